// Round 1
// baseline (7060.128 us; speedup 1.0000x reference)
//
#include <hip/hip_runtime.h>
#include <hip/hip_fp16.h>

#define D 128
#define E_PER 500000

typedef _Float16 f16;
typedef _Float16 f16x8 __attribute__((ext_vector_type(8)));
typedef _Float16 f16x4 __attribute__((ext_vector_type(4)));
typedef float f32x4 __attribute__((ext_vector_type(4)));

// XOR swizzle for the A tile in LDS: row stride is 256B (128 f16) -> without
// swizzle, lanes reading the same k across 16 rows hit the same bank group.
__device__ __forceinline__ unsigned a_swz(int row, int byteoff) {
    return (unsigned)(row * 256 + byteoff) ^ (unsigned)((row & 7) << 4);
}

// ---------------------------------------------------------------- precast W^T
// Wth layout: [layer][s][c][k] f16, i.e. transposed weights so the MFMA B
// fragment (8 consecutive k for a fixed col) is one contiguous 16B read.
__global__ void precast(const float* __restrict__ W1,
                        const float* __restrict__ W2,
                        f16* __restrict__ Wth) {
    int i = blockIdx.x * 256 + threadIdx.x;
    if (i >= 2 * 3 * 128 * 128) return;
    int layer = i / 49152;
    int rem = i - layer * 49152;
    int s = rem / 16384;
    int r2 = rem & 16383;
    int kk = r2 >> 7;
    int c  = r2 & 127;
    const float* W = layer ? W2 : W1;
    Wth[(((size_t)layer * 3 + s) * 128 + c) * 128 + kk] = (f16)W[((size_t)s * 128 + kk) * 128 + c];
}

// ---------------------------------------------------------------- scatter-add
// One wave per edge; lane handles 2 channels (float2 gather + 2 f32 atomics).
__global__ __launch_bounds__(256) void scatter(const float* __restrict__ xs,
                                               const int* __restrict__ srcp,
                                               const int* __restrict__ dstp,
                                               float* __restrict__ agg, int nE) {
    int gw   = (blockIdx.x * 256 + threadIdx.x) >> 6;
    int lane = threadIdx.x & 63;
    int nw   = (gridDim.x * 256) >> 6;
    int c = lane * 2;
    for (int e = gw; e < nE; e += nw) {
        int s = srcp[e];
        int d = dstp[e];
        const float2 v = *(const float2*)(xs + (size_t)s * D + c);
        float* a = agg + (size_t)d * D + c;
        unsafeAtomicAdd(a, v.x);
        unsafeAtomicAdd(a + 1, v.y);
    }
}

// ------------------------------------------------------------------- GEMM+BN
// mode 1: in = (1+eps[kidx])*xt + buf(agg);      writes z into buf (in-place)
// mode 2: in = relu(buf(z1)*affa + affc);        writes z into buf (in-place)
// Epilogue: z += bias, store, accumulate per-column sum/sumsq via atomics.
__global__ __launch_bounds__(256) void gemm_bn(const float* __restrict__ xt,
                                               float* __restrict__ buf,
                                               const f16* __restrict__ Wt,
                                               const float* __restrict__ bias,
                                               const float* __restrict__ affa,
                                               const float* __restrict__ affc,
                                               const float* __restrict__ eps9, int kidx,
                                               float* __restrict__ ssum,
                                               float* __restrict__ ssq,
                                               int N, int mode) {
    __shared__ alignas(16) char lds[64 * 128 * 2];  // 64x128 f16 A tile
    const int tid  = threadIdx.x;
    const int lane = tid & 63;
    const int w    = tid >> 6;
    const int row0 = blockIdx.x * 64;

    float epsv = 0.f;
    if (mode == 1) epsv = 1.0f + eps9[kidx];

    // ---- stage A tile (64 rows x 128 cols) as f16, swizzled
    #pragma unroll
    for (int it = 0; it < 8; ++it) {
        int flat = it * 256 + tid;      // 0..2047 float4 slots
        int r  = flat >> 5;             // local row 0..63
        int c4 = flat & 31;             // float4 index within row
        int row = row0 + r;
        f32x4 v = {0.f, 0.f, 0.f, 0.f};
        if (row < N) {
            v = *((const f32x4*)(buf + (size_t)row * D) + c4);
            if (mode == 1) {
                f32x4 xv = *((const f32x4*)(xt + (size_t)row * D) + c4);
                #pragma unroll
                for (int j = 0; j < 4; ++j) v[j] = xv[j] * epsv + v[j];
            } else {
                f32x4 a = ((const f32x4*)affa)[c4];
                f32x4 c = ((const f32x4*)affc)[c4];
                #pragma unroll
                for (int j = 0; j < 4; ++j) {
                    float t = v[j] * a[j] + c[j];
                    v[j] = t > 0.f ? t : 0.f;
                }
            }
        }
        f16x4 h;
        #pragma unroll
        for (int j = 0; j < 4; ++j) h[j] = (f16)v[j];
        *(f16x4*)(lds + a_swz(r, c4 * 8)) = h;
    }
    __syncthreads();

    // ---- compute: wave w owns rows [w*16, w*16+16), all 128 cols
    f32x4 acc[8];
    #pragma unroll
    for (int ct = 0; ct < 8; ++ct) acc[ct] = (f32x4){0.f, 0.f, 0.f, 0.f};

    const int arow = (w << 4) + (lane & 15);   // local row in tile
    const int kq   = (lane >> 4) * 8;          // k sub-offset per lane group

    #pragma unroll
    for (int ks = 0; ks < 4; ++ks) {
        f16x8 af = *(const f16x8*)(lds + a_swz(arow, (ks * 32 + kq) * 2));
        #pragma unroll
        for (int ct = 0; ct < 8; ++ct) {
            f16x8 bf = *(const f16x8*)(Wt + (size_t)(ct * 16 + (lane & 15)) * D + ks * 32 + kq);
            acc[ct] = __builtin_amdgcn_mfma_f32_16x16x32_f16(af, bf, acc[ct], 0, 0, 0);
        }
    }

    // ---- epilogue: bias, store, column stats
    const int col_lo = lane & 15;
    const int rbase  = row0 + (w << 4) + ((lane >> 4) << 2);
    #pragma unroll
    for (int ct = 0; ct < 8; ++ct) {
        int col = ct * 16 + col_lo;
        float bv = bias[col];
        float s = 0.f, q = 0.f;
        #pragma unroll
        for (int r = 0; r < 4; ++r) {
            int row = rbase + r;
            float val = acc[ct][r] + bv;
            if (row < N) {
                buf[(size_t)row * D + col] = val;
                s += val;
                q += val * val;
            }
        }
        s += __shfl_xor(s, 16); q += __shfl_xor(q, 16);
        s += __shfl_xor(s, 32); q += __shfl_xor(q, 32);
        if (lane < 16) {
            unsafeAtomicAdd(&ssum[col], s);
            unsafeAtomicAdd(&ssq[col], q);
        }
    }
}

// ----------------------------------------------------------------- BN params
__global__ void bn_params(const float* __restrict__ ssum, const float* __restrict__ ssq,
                          const float* __restrict__ g, const float* __restrict__ be,
                          float* __restrict__ affa, float* __restrict__ affc, int N) {
    int c = threadIdx.x;
    float n = (float)N;
    float mean = ssum[c] / n;
    float var  = ssq[c] / n - mean * mean;
    float a = g[c] * rsqrtf(var + 1e-5f);
    affa[c] = a;
    affc[c] = be[c] - mean * a;
}

// ------------------------------------------------------------------- accum
__global__ __launch_bounds__(256) void accum(const float* __restrict__ buf,
                                             const float* __restrict__ affa,
                                             const float* __restrict__ affc,
                                             float* __restrict__ outp,
                                             int N, int first) {
    int n4 = N * 32;
    for (int i = blockIdx.x * 256 + threadIdx.x; i < n4; i += gridDim.x * 256) {
        int c4 = i & 31;
        f32x4 v = ((const f32x4*)buf)[i];
        f32x4 a = ((const f32x4*)affa)[c4];
        f32x4 c = ((const f32x4*)affc)[c4];
        f32x4 r;
        #pragma unroll
        for (int j = 0; j < 4; ++j) {
            float t = v[j] * a[j] + c[j];
            r[j] = t > 0.f ? t : 0.f;
        }
        f32x4* o = (f32x4*)outp + i;
        if (first) *o = r;
        else       { f32x4 p = *o; *o = p + r; }
    }
}

extern "C" void kernel_launch(void* const* d_in, const int* in_sizes, int n_in,
                              void* d_out, int out_size, void* d_ws, size_t ws_size,
                              hipStream_t stream) {
    const float* x0  = (const float*)d_in[0];
    const float* x1  = (const float*)d_in[1];
    const float* x2  = (const float*)d_in[2];
    const int*   ei  = (const int*)d_in[3];
    const float* W1  = (const float*)d_in[4];
    const float* b1  = (const float*)d_in[5];
    const float* g1  = (const float*)d_in[6];
    const float* be1 = (const float*)d_in[7];
    const float* W2  = (const float*)d_in[8];
    const float* b2  = (const float*)d_in[9];
    const float* g2  = (const float*)d_in[10];
    const float* be2 = (const float*)d_in[11];
    const float* eps9 = (const float*)d_in[12];
    float* outp = (float*)d_out;

    const int NC[3] = {200000, 3000, 20000};
    const size_t OUT_OFF[3] = {0, (size_t)200000 * D, (size_t)203000 * D};
    const float* xs[3] = {x0, x1, x2};

    char* ws = (char*)d_ws;
    float* buf = (float*)ws;
    size_t off = (size_t)200000 * D * sizeof(float);
    float* ssum1 = (float*)(ws + off); off += 512;
    float* ssq1  = (float*)(ws + off); off += 512;
    float* ssum2 = (float*)(ws + off); off += 512;
    float* ssq2  = (float*)(ws + off); off += 512;
    float* aff1a = (float*)(ws + off); off += 512;
    float* aff1c = (float*)(ws + off); off += 512;
    float* aff2a = (float*)(ws + off); off += 512;
    float* aff2c = (float*)(ws + off); off += 512;
    f16* Wth = (f16*)(ws + off); off += (size_t)2 * 3 * 128 * 128 * sizeof(f16);

    precast<<<(98304 + 255) / 256, 256, 0, stream>>>(W1, W2, Wth);

    for (int k = 0; k < 9; ++k) {
        int s = k / 3, t = k % 3;
        int N = NC[t];
        hipMemsetAsync(buf, 0, (size_t)N * D * sizeof(float), stream);
        hipMemsetAsync(ssum1, 0, 4 * 512, stream);  // ssum1,ssq1,ssum2,ssq2 contiguous

        const int* srcp = ei + (size_t)k * 2 * E_PER;
        const int* dstp = srcp + E_PER;
        scatter<<<4096, 256, 0, stream>>>(xs[s], srcp, dstp, buf, E_PER);

        int gtiles = (N + 63) / 64;
        gemm_bn<<<gtiles, 256, 0, stream>>>(xs[t], buf, Wth + (size_t)s * 16384,
                                            b1 + s * D, nullptr, nullptr,
                                            eps9, k, ssum1, ssq1, N, 1);
        bn_params<<<1, 128, 0, stream>>>(ssum1, ssq1, g1 + s * D, be1 + s * D, aff1a, aff1c, N);

        gemm_bn<<<gtiles, 256, 0, stream>>>(nullptr, buf, Wth + (size_t)(3 + s) * 16384,
                                            b2 + s * D, aff1a, aff1c,
                                            eps9, k, ssum2, ssq2, N, 2);
        bn_params<<<1, 128, 0, stream>>>(ssum2, ssq2, g2 + s * D, be2 + s * D, aff2a, aff2c, N);

        int nblk = (N * 32 + 255) / 256;
        if (nblk > 2048) nblk = 2048;
        accum<<<nblk, 256, 0, stream>>>(buf, aff2a, aff2c, outp + OUT_OFF[t], N, (s == 0) ? 1 : 0);
    }
}

// Round 2
// 4842.760 us; speedup vs baseline: 1.4579x; 1.4579x over previous
//
#include <hip/hip_runtime.h>
#include <hip/hip_fp16.h>

#define D 128
#define E_PER 500000
#define NRED 32

typedef _Float16 f16;
typedef _Float16 f16x8 __attribute__((ext_vector_type(8)));
typedef _Float16 f16x4 __attribute__((ext_vector_type(4)));
typedef float f32x4 __attribute__((ext_vector_type(4)));

// XOR swizzle for the A tile in LDS (row stride 256B f16).
__device__ __forceinline__ unsigned a_swz(int row, int byteoff) {
    return (unsigned)(row * 256 + byteoff) ^ (unsigned)((row & 7) << 4);
}

// ---------------------------------------------------------------- precast W^T
// Wth layout: [layer][s][c][k] f16 (transposed) so B fragment is 16B contiguous.
__global__ void precast(const float* __restrict__ W1,
                        const float* __restrict__ W2,
                        f16* __restrict__ Wth) {
    int i = blockIdx.x * 256 + threadIdx.x;
    if (i >= 2 * 3 * 128 * 128) return;
    int layer = i / 49152;
    int rem = i - layer * 49152;
    int s = rem / 16384;
    int r2 = rem & 16383;
    int kk = r2 >> 7;
    int c  = r2 & 127;
    const float* W = layer ? W2 : W1;
    Wth[(((size_t)layer * 3 + s) * 128 + c) * 128 + kk] = (f16)W[((size_t)s * 128 + kk) * 128 + c];
}

// ---------------------------------------------------------------- scatter-add
__global__ __launch_bounds__(256) void scatter(const float* __restrict__ xs,
                                               const int* __restrict__ srcp,
                                               const int* __restrict__ dstp,
                                               float* __restrict__ agg, int nE) {
    int gw   = (blockIdx.x * 256 + threadIdx.x) >> 6;
    int lane = threadIdx.x & 63;
    int nw   = (gridDim.x * 256) >> 6;
    int c = lane * 2;
    for (int e = gw; e < nE; e += nw) {
        int s = srcp[e];
        int d = dstp[e];
        const float2 v = *(const float2*)(xs + (size_t)s * D + c);
        float* a = agg + (size_t)d * D + c;
        unsafeAtomicAdd(a, v.x);
        unsafeAtomicAdd(a + 1, v.y);
    }
}

// ------------------------------------------------------------------- GEMM+BN
// Row slab layout: row r occupies bytes [r*512, r*512+512) of bufb.
//   agg (mode1 input): full 512B as 128 f32
//   z1  (mode1 output / mode2 input): bytes [r*512, +256) as 128 f16
//   z2  (mode2 output): bytes [r*512+256, +512) as 128 f16
// mode 1: in = (1+eps)*xt + agg;  mode 2: in = relu(z1*affa+affc)
// Epilogue: z += bias, store f16, per-block column sum/sumsq -> partials (no atomics).
__global__ __launch_bounds__(256) void gemm_bn(const float* __restrict__ xt,
                                               char* __restrict__ bufb,
                                               const f16* __restrict__ Wt,
                                               const float* __restrict__ bias,
                                               const float* __restrict__ affa,
                                               const float* __restrict__ affc,
                                               const float* __restrict__ eps9, int kidx,
                                               float* __restrict__ partials,
                                               int N, int mode) {
    __shared__ alignas(16) char lds[64 * 256];   // 64 rows x 128 f16
    __shared__ float wstats[4][256];
    const int tid  = threadIdx.x;
    const int lane = tid & 63;
    const int w    = tid >> 6;
    const int row0 = blockIdx.x * 64;

    if (mode == 1) {
        float epsv = 1.0f + eps9[kidx];
        #pragma unroll
        for (int it = 0; it < 8; ++it) {
            int flat = it * 256 + tid;      // 2048 f32x4 slots
            int r  = flat >> 5;
            int c4 = flat & 31;
            int row = row0 + r;
            f16x4 h = {0, 0, 0, 0};
            if (row < N) {
                f32x4 v  = ((const f32x4*)(bufb + (size_t)row * 512))[c4];
                f32x4 xv = ((const f32x4*)(xt + (size_t)row * D))[c4];
                #pragma unroll
                for (int j = 0; j < 4; ++j) h[j] = (f16)(xv[j] * epsv + v[j]);
            }
            *(f16x4*)(lds + a_swz(r, c4 * 8)) = h;
        }
    } else {
        #pragma unroll
        for (int it = 0; it < 4; ++it) {
            int flat = it * 256 + tid;      // 1024 f16x8 slots
            int r  = flat >> 4;
            int c8 = flat & 15;
            int row = row0 + r;
            f16x8 h = {0, 0, 0, 0, 0, 0, 0, 0};
            if (row < N) {
                f16x8 zv = ((const f16x8*)(bufb + (size_t)row * 512))[c8];
                f32x4 a0 = ((const f32x4*)affa)[c8 * 2];
                f32x4 a1 = ((const f32x4*)affa)[c8 * 2 + 1];
                f32x4 c0 = ((const f32x4*)affc)[c8 * 2];
                f32x4 c1 = ((const f32x4*)affc)[c8 * 2 + 1];
                #pragma unroll
                for (int j = 0; j < 4; ++j) {
                    float t0 = (float)zv[j] * a0[j] + c0[j];
                    float t1 = (float)zv[4 + j] * a1[j] + c1[j];
                    h[j]     = (f16)(t0 > 0.f ? t0 : 0.f);
                    h[4 + j] = (f16)(t1 > 0.f ? t1 : 0.f);
                }
            }
            *(f16x8*)(lds + a_swz(r, c8 * 16)) = h;
        }
    }
    __syncthreads();

    // ---- compute: wave w owns rows [w*16, w*16+16), all 128 cols
    f32x4 acc[8];
    #pragma unroll
    for (int ct = 0; ct < 8; ++ct) acc[ct] = (f32x4){0.f, 0.f, 0.f, 0.f};

    const int arow = (w << 4) + (lane & 15);
    const int kq   = (lane >> 4) * 8;

    #pragma unroll
    for (int ks = 0; ks < 4; ++ks) {
        f16x8 af = *(const f16x8*)(lds + a_swz(arow, (ks * 32 + kq) * 2));
        #pragma unroll
        for (int ct = 0; ct < 8; ++ct) {
            f16x8 bf = *(const f16x8*)(Wt + (size_t)(ct * 16 + (lane & 15)) * D + ks * 32 + kq);
            acc[ct] = __builtin_amdgcn_mfma_f32_16x16x32_f16(af, bf, acc[ct], 0, 0, 0);
        }
    }

    // ---- epilogue: bias, store f16, block-level column stats (no atomics)
    const int col_lo = lane & 15;
    const int lrbase = (w << 4) + ((lane >> 4) << 2);
    const int zoff   = (mode == 1) ? 0 : 256;
    #pragma unroll
    for (int ct = 0; ct < 8; ++ct) {
        int col = ct * 16 + col_lo;
        float bv = bias[col];
        float s = 0.f, q = 0.f;
        #pragma unroll
        for (int r = 0; r < 4; ++r) {
            int row = row0 + lrbase + r;
            float val = acc[ct][r] + bv;
            if (row < N) {
                *(f16*)(bufb + (size_t)row * 512 + zoff + col * 2) = (f16)val;
                s += val;
                q += val * val;
            }
        }
        s += __shfl_xor(s, 16); q += __shfl_xor(q, 16);
        s += __shfl_xor(s, 32); q += __shfl_xor(q, 32);
        if (lane < 16) {
            wstats[w][col] = s;
            wstats[w][128 + col] = q;
        }
    }
    __syncthreads();
    float p = wstats[0][tid] + wstats[1][tid] + wstats[2][tid] + wstats[3][tid];
    partials[(size_t)blockIdx.x * 256 + tid] = p;
}

// ----------------------------------------------------------- stats reduction
__global__ void bn_reduce(const float* __restrict__ partials,
                          float* __restrict__ partial2, int nblk) {
    int tid = threadIdx.x;
    float s = 0.f;
    for (int r = blockIdx.x; r < nblk; r += NRED)
        s += partials[(size_t)r * 256 + tid];
    partial2[blockIdx.x * 256 + tid] = s;
}

__global__ void bn_params(const float* __restrict__ partial2,
                          const float* __restrict__ g, const float* __restrict__ be,
                          float* __restrict__ affa, float* __restrict__ affc, int N) {
    int c = threadIdx.x;  // 128
    float s = 0.f, q = 0.f;
    #pragma unroll
    for (int b = 0; b < NRED; ++b) {
        s += partial2[b * 256 + c];
        q += partial2[b * 256 + 128 + c];
    }
    float n = (float)N;
    float mean = s / n;
    float var  = q / n - mean * mean;
    float a = g[c] * rsqrtf(var + 1e-5f);
    affa[c] = a;
    affc[c] = be[c] - mean * a;
}

// ------------------------------------------------------------------- accum
__global__ __launch_bounds__(256) void accum(const char* __restrict__ bufb,
                                             const float* __restrict__ affa,
                                             const float* __restrict__ affc,
                                             float* __restrict__ outp,
                                             int N, int first) {
    int total = N * 16;
    for (int i = blockIdx.x * 256 + threadIdx.x; i < total; i += gridDim.x * 256) {
        int row = i >> 4;
        int c8  = i & 15;
        f16x8 z = *((const f16x8*)(bufb + (size_t)row * 512 + 256) + c8);
        f32x4 a0 = ((const f32x4*)affa)[c8 * 2];
        f32x4 a1 = ((const f32x4*)affa)[c8 * 2 + 1];
        f32x4 c0 = ((const f32x4*)affc)[c8 * 2];
        f32x4 c1 = ((const f32x4*)affc)[c8 * 2 + 1];
        f32x4 r0, r1;
        #pragma unroll
        for (int j = 0; j < 4; ++j) {
            float t0 = (float)z[j] * a0[j] + c0[j];
            float t1 = (float)z[4 + j] * a1[j] + c1[j];
            r0[j] = t0 > 0.f ? t0 : 0.f;
            r1[j] = t1 > 0.f ? t1 : 0.f;
        }
        f32x4* o = (f32x4*)(outp + (size_t)row * 128) + c8 * 2;
        if (first) { o[0] = r0; o[1] = r1; }
        else       { f32x4 p0 = o[0], p1 = o[1]; o[0] = p0 + r0; o[1] = p1 + r1; }
    }
}

extern "C" void kernel_launch(void* const* d_in, const int* in_sizes, int n_in,
                              void* d_out, int out_size, void* d_ws, size_t ws_size,
                              hipStream_t stream) {
    const float* x0  = (const float*)d_in[0];
    const float* x1  = (const float*)d_in[1];
    const float* x2  = (const float*)d_in[2];
    const int*   ei  = (const int*)d_in[3];
    const float* W1  = (const float*)d_in[4];
    const float* b1  = (const float*)d_in[5];
    const float* g1  = (const float*)d_in[6];
    const float* be1 = (const float*)d_in[7];
    const float* W2  = (const float*)d_in[8];
    const float* b2  = (const float*)d_in[9];
    const float* g2  = (const float*)d_in[10];
    const float* be2 = (const float*)d_in[11];
    const float* eps9 = (const float*)d_in[12];
    float* outp = (float*)d_out;

    const int NC[3] = {200000, 3000, 20000};
    const size_t OUT_OFF[3] = {0, (size_t)200000 * D, (size_t)203000 * D};
    const float* xs[3] = {x0, x1, x2};

    char* ws = (char*)d_ws;
    char* bufb = ws;                                     // 200000*512 B row slabs
    size_t off = (size_t)200000 * 512;
    float* partials = (float*)(ws + off); off += (size_t)3125 * 256 * 4;
    float* partial2 = (float*)(ws + off); off += NRED * 256 * 4;
    float* aff1a = (float*)(ws + off); off += 512;
    float* aff1c = (float*)(ws + off); off += 512;
    float* aff2a = (float*)(ws + off); off += 512;
    float* aff2c = (float*)(ws + off); off += 512;
    f16* Wth = (f16*)(ws + off); off += (size_t)2 * 3 * 128 * 128 * sizeof(f16);

    precast<<<(98304 + 255) / 256, 256, 0, stream>>>(W1, W2, Wth);

    for (int k = 0; k < 9; ++k) {
        int s = k / 3, t = k % 3;
        int N = NC[t];
        hipMemsetAsync(bufb, 0, (size_t)N * 512, stream);

        const int* srcp = ei + (size_t)k * 2 * E_PER;
        const int* dstp = srcp + E_PER;
        scatter<<<4096, 256, 0, stream>>>(xs[s], srcp, dstp, (float*)bufb, E_PER);

        int gtiles = (N + 63) / 64;
        gemm_bn<<<gtiles, 256, 0, stream>>>(xs[t], bufb, Wth + (size_t)s * 16384,
                                            b1 + s * D, nullptr, nullptr,
                                            eps9, k, partials, N, 1);
        bn_reduce<<<NRED, 256, 0, stream>>>(partials, partial2, gtiles);
        bn_params<<<1, 128, 0, stream>>>(partial2, g1 + s * D, be1 + s * D, aff1a, aff1c, N);

        gemm_bn<<<gtiles, 256, 0, stream>>>(nullptr, bufb, Wth + (size_t)(3 + s) * 16384,
                                            b2 + s * D, aff1a, aff1c,
                                            eps9, k, partials, N, 2);
        bn_reduce<<<NRED, 256, 0, stream>>>(partials, partial2, gtiles);
        bn_params<<<1, 128, 0, stream>>>(partial2, g2 + s * D, be2 + s * D, aff2a, aff2c, N);

        int nblk = (N * 16 + 255) / 256;
        if (nblk > 2048) nblk = 2048;
        accum<<<nblk, 256, 0, stream>>>(bufb, aff2a, aff2c, outp + OUT_OFF[t], N, (s == 0) ? 1 : 0);
    }
}

// Round 3
// 2128.674 us; speedup vs baseline: 3.3167x; 2.2750x over previous
//
#include <hip/hip_runtime.h>
#include <hip/hip_fp16.h>

#define D 128
#define E_PER 500000
#define NRED 32

typedef _Float16 f16;
typedef _Float16 f16x8 __attribute__((ext_vector_type(8)));
typedef _Float16 f16x4 __attribute__((ext_vector_type(4)));
typedef _Float16 f16x2 __attribute__((ext_vector_type(2)));
typedef float f32x4 __attribute__((ext_vector_type(4)));

// XOR swizzle for the A tile in LDS (row stride 256B f16).
__device__ __forceinline__ unsigned a_swz(int row, int byteoff) {
    return (unsigned)(row * 256 + byteoff) ^ (unsigned)((row & 7) << 4);
}

// ---------------------------------------------------------------- precast W^T
__global__ void precast(const float* __restrict__ W1,
                        const float* __restrict__ W2,
                        f16* __restrict__ Wth) {
    int i = blockIdx.x * 256 + threadIdx.x;
    if (i >= 2 * 3 * 128 * 128) return;
    int layer = i / 49152;
    int rem = i - layer * 49152;
    int s = rem / 16384;
    int r2 = rem & 16383;
    int kk = r2 >> 7;
    int c  = r2 & 127;
    const float* W = layer ? W2 : W1;
    Wth[(((size_t)layer * 3 + s) * 128 + c) * 128 + kk] = (f16)W[((size_t)s * 128 + kk) * 128 + c];
}

// ------------------------------------------------------------------ x0 -> f16
__global__ void cast16(const float* __restrict__ x, f16* __restrict__ y, int n4) {
    for (int i = blockIdx.x * 256 + threadIdx.x; i < n4; i += gridDim.x * 256) {
        f32x4 v = ((const f32x4*)x)[i];
        f16x4 h;
        #pragma unroll
        for (int j = 0; j < 4; ++j) h[j] = (f16)v[j];
        ((f16x4*)y)[i] = h;
    }
}

// ------------------------------------------------------------------ CSR build
__global__ void deg_count(const int* __restrict__ dstp, int* __restrict__ deg, int nE) {
    for (int i = blockIdx.x * 256 + threadIdx.x; i < nE; i += gridDim.x * 256)
        atomicAdd(&deg[dstp[i]], 1);
}

__global__ void scan1(const int* __restrict__ deg, int* __restrict__ bsum, int N, int C) {
    __shared__ int red[256];
    int b = blockIdx.x, t = threadIdx.x;
    int lo = b * C, hi = min(lo + C, N);
    int s = 0;
    for (int i = lo + t; i < hi; i += 256) s += deg[i];
    red[t] = s; __syncthreads();
    for (int off = 128; off > 0; off >>= 1) {
        if (t < off) red[t] += red[t + off];
        __syncthreads();
    }
    if (t == 0) bsum[b] = red[0];
}

__global__ void scan2(int* __restrict__ bsum) {
    __shared__ int sb[256];
    int t = threadIdx.x;
    int v = bsum[t];
    sb[t] = v; __syncthreads();
    for (int off = 1; off < 256; off <<= 1) {
        int u = (t >= off) ? sb[t - off] : 0;
        __syncthreads();
        sb[t] += u;
        __syncthreads();
    }
    bsum[t] = sb[t] - v;   // exclusive
}

__global__ void scan3(const int* __restrict__ deg, const int* __restrict__ bsum,
                      int* __restrict__ rowstart, int* __restrict__ cursor,
                      int N, int C, int c2) {
    __shared__ int sb[256];
    int b = blockIdx.x, t = threadIdx.x;
    int cap = min(b * C + C, N);
    int lo = b * C + t * c2;
    int hi = min(lo + c2, cap);
    int s = 0;
    for (int i = lo; i < hi; ++i) s += deg[i];
    sb[t] = s; __syncthreads();
    int v = s;
    for (int off = 1; off < 256; off <<= 1) {
        int u = (t >= off) ? sb[t - off] : 0;
        __syncthreads();
        sb[t] += u;
        __syncthreads();
    }
    int pre = bsum[b] + sb[t] - v;
    for (int i = lo; i < hi; ++i) {
        rowstart[i] = pre;
        cursor[i]   = pre;
        pre += deg[i];
        if (i == N - 1) rowstart[N] = pre;
    }
}

__global__ void fill_csr(const int* __restrict__ srcp, const int* __restrict__ dstp,
                         int* __restrict__ cursor, int* __restrict__ ssrc, int nE) {
    for (int i = blockIdx.x * 256 + threadIdx.x; i < nE; i += gridDim.x * 256) {
        int d = dstp[i];
        int pos = atomicAdd(&cursor[d], 1);
        ssrc[pos] = srcp[i];
    }
}

// ------------------------------------------------------------------ aggregate
// Gather-based segment sum: wave per row (wpr4=0) or 4 waves per row (wpr4=1).
// Lane holds channels [2*lane, 2*lane+1]. Output f16 row (256 B) into bufb.
__global__ __launch_bounds__(256) void aggregate(const void* __restrict__ xsrc, int xf16,
                                                 const int* __restrict__ rowstart,
                                                 const int* __restrict__ ssrc,
                                                 char* __restrict__ bufb, int N, int wpr4) {
    __shared__ float part[4][130];
    int lane = threadIdx.x & 63;
    int w    = threadIdx.x >> 6;
    int row, sub, wpr;
    if (wpr4) { row = blockIdx.x; sub = w; wpr = 4; }
    else      { row = (blockIdx.x << 2) + w; sub = 0; wpr = 1; }
    float r0 = 0.f, r1 = 0.f;
    if (row < N) {
        int rs = rowstart[row], re = rowstart[row + 1];
        float a0=0,a1=0,b0=0,b1=0,c0=0,c1=0,d0=0,d1=0;
        int e = rs + sub;
        if (xf16) {
            const f16* xt = (const f16*)xsrc;
            for (; e + 3 * wpr < re; e += 4 * wpr) {
                int s0 = ssrc[e], s1 = ssrc[e + wpr], s2 = ssrc[e + 2 * wpr], s3 = ssrc[e + 3 * wpr];
                f16x2 v0 = *(const f16x2*)(xt + (size_t)s0 * D + lane * 2);
                f16x2 v1 = *(const f16x2*)(xt + (size_t)s1 * D + lane * 2);
                f16x2 v2 = *(const f16x2*)(xt + (size_t)s2 * D + lane * 2);
                f16x2 v3 = *(const f16x2*)(xt + (size_t)s3 * D + lane * 2);
                a0 += (float)v0[0]; a1 += (float)v0[1];
                b0 += (float)v1[0]; b1 += (float)v1[1];
                c0 += (float)v2[0]; c1 += (float)v2[1];
                d0 += (float)v3[0]; d1 += (float)v3[1];
            }
            for (; e < re; e += wpr) {
                int s0 = ssrc[e];
                f16x2 v0 = *(const f16x2*)(xt + (size_t)s0 * D + lane * 2);
                a0 += (float)v0[0]; a1 += (float)v0[1];
            }
        } else {
            const float* xt = (const float*)xsrc;
            for (; e + 3 * wpr < re; e += 4 * wpr) {
                int s0 = ssrc[e], s1 = ssrc[e + wpr], s2 = ssrc[e + 2 * wpr], s3 = ssrc[e + 3 * wpr];
                float2 v0 = *(const float2*)(xt + (size_t)s0 * D + lane * 2);
                float2 v1 = *(const float2*)(xt + (size_t)s1 * D + lane * 2);
                float2 v2 = *(const float2*)(xt + (size_t)s2 * D + lane * 2);
                float2 v3 = *(const float2*)(xt + (size_t)s3 * D + lane * 2);
                a0 += v0.x; a1 += v0.y;
                b0 += v1.x; b1 += v1.y;
                c0 += v2.x; c1 += v2.y;
                d0 += v3.x; d1 += v3.y;
            }
            for (; e < re; e += wpr) {
                int s0 = ssrc[e];
                float2 v0 = *(const float2*)(xt + (size_t)s0 * D + lane * 2);
                a0 += v0.x; a1 += v0.y;
            }
        }
        r0 = (a0 + b0) + (c0 + d0);
        r1 = (a1 + b1) + (c1 + d1);
    }
    if (wpr4) {
        part[w][lane * 2] = r0; part[w][lane * 2 + 1] = r1;
        __syncthreads();
        if (w == 0 && row < N) {
            float s0 = part[0][lane*2] + part[1][lane*2] + part[2][lane*2] + part[3][lane*2];
            float s1 = part[0][lane*2+1] + part[1][lane*2+1] + part[2][lane*2+1] + part[3][lane*2+1];
            f16x2 h; h[0] = (f16)s0; h[1] = (f16)s1;
            *(f16x2*)(bufb + (size_t)row * 256 + lane * 4) = h;
        }
    } else if (row < N) {
        f16x2 h; h[0] = (f16)r0; h[1] = (f16)r1;
        *(f16x2*)(bufb + (size_t)row * 256 + lane * 4) = h;
    }
}

// ------------------------------------------------------------------- GEMM+BN
// Row slab: 256 B per row in bufb, processed in-place (block-local rows).
// mode 1: in = (1+eps)*xt + agg(f16);  mode 2: in = relu(z1*affa + affc)
__global__ __launch_bounds__(256) void gemm_bn(const float* __restrict__ xtf,
                                               const f16* __restrict__ xth,
                                               char* __restrict__ bufb,
                                               const f16* __restrict__ Wt,
                                               const float* __restrict__ bias,
                                               const float* __restrict__ affa,
                                               const float* __restrict__ affc,
                                               const float* __restrict__ eps9, int kidx,
                                               float* __restrict__ partials,
                                               int N, int mode) {
    __shared__ alignas(16) char lds[64 * 256];
    __shared__ float wstats[4][256];
    const int tid  = threadIdx.x;
    const int lane = tid & 63;
    const int w    = tid >> 6;
    const int row0 = blockIdx.x * 64;

    if (mode == 1) {
        float epsv = 1.0f + eps9[kidx];
        #pragma unroll
        for (int it = 0; it < 4; ++it) {
            int flat = it * 256 + tid;
            int r  = flat >> 4;
            int c8 = flat & 15;
            int row = row0 + r;
            f16x8 h = {0, 0, 0, 0, 0, 0, 0, 0};
            if (row < N) {
                f16x8 ag = ((const f16x8*)(bufb + (size_t)row * 256))[c8];
                if (xth) {
                    f16x8 xv = ((const f16x8*)(xth + (size_t)row * D))[c8];
                    #pragma unroll
                    for (int j = 0; j < 8; ++j) h[j] = (f16)((float)xv[j] * epsv + (float)ag[j]);
                } else {
                    f32x4 x0 = ((const f32x4*)(xtf + (size_t)row * D))[c8 * 2];
                    f32x4 x1 = ((const f32x4*)(xtf + (size_t)row * D))[c8 * 2 + 1];
                    #pragma unroll
                    for (int j = 0; j < 4; ++j) {
                        h[j]     = (f16)(x0[j] * epsv + (float)ag[j]);
                        h[4 + j] = (f16)(x1[j] * epsv + (float)ag[4 + j]);
                    }
                }
            }
            *(f16x8*)(lds + a_swz(r, c8 * 16)) = h;
        }
    } else {
        #pragma unroll
        for (int it = 0; it < 4; ++it) {
            int flat = it * 256 + tid;
            int r  = flat >> 4;
            int c8 = flat & 15;
            int row = row0 + r;
            f16x8 h = {0, 0, 0, 0, 0, 0, 0, 0};
            if (row < N) {
                f16x8 zv = ((const f16x8*)(bufb + (size_t)row * 256))[c8];
                f32x4 a0 = ((const f32x4*)affa)[c8 * 2];
                f32x4 a1 = ((const f32x4*)affa)[c8 * 2 + 1];
                f32x4 c0 = ((const f32x4*)affc)[c8 * 2];
                f32x4 c1 = ((const f32x4*)affc)[c8 * 2 + 1];
                #pragma unroll
                for (int j = 0; j < 4; ++j) {
                    float t0 = (float)zv[j] * a0[j] + c0[j];
                    float t1 = (float)zv[4 + j] * a1[j] + c1[j];
                    h[j]     = (f16)(t0 > 0.f ? t0 : 0.f);
                    h[4 + j] = (f16)(t1 > 0.f ? t1 : 0.f);
                }
            }
            *(f16x8*)(lds + a_swz(r, c8 * 16)) = h;
        }
    }
    __syncthreads();

    f32x4 acc[8];
    #pragma unroll
    for (int ct = 0; ct < 8; ++ct) acc[ct] = (f32x4){0.f, 0.f, 0.f, 0.f};

    const int arow = (w << 4) + (lane & 15);
    const int kq   = (lane >> 4) * 8;

    #pragma unroll
    for (int ks = 0; ks < 4; ++ks) {
        f16x8 af = *(const f16x8*)(lds + a_swz(arow, (ks * 32 + kq) * 2));
        #pragma unroll
        for (int ct = 0; ct < 8; ++ct) {
            f16x8 bf = *(const f16x8*)(Wt + (size_t)(ct * 16 + (lane & 15)) * D + ks * 32 + kq);
            acc[ct] = __builtin_amdgcn_mfma_f32_16x16x32_f16(af, bf, acc[ct], 0, 0, 0);
        }
    }

    const int col_lo = lane & 15;
    const int lrbase = (w << 4) + ((lane >> 4) << 2);
    #pragma unroll
    for (int ct = 0; ct < 8; ++ct) {
        int col = ct * 16 + col_lo;
        float bv = bias[col];
        float s = 0.f, q = 0.f;
        #pragma unroll
        for (int r = 0; r < 4; ++r) {
            int row = row0 + lrbase + r;
            float val = acc[ct][r] + bv;
            if (row < N) {
                *(f16*)(bufb + (size_t)row * 256 + col * 2) = (f16)val;
                s += val;
                q += val * val;
            }
        }
        s += __shfl_xor(s, 16); q += __shfl_xor(q, 16);
        s += __shfl_xor(s, 32); q += __shfl_xor(q, 32);
        if (lane < 16) {
            wstats[w][col] = s;
            wstats[w][128 + col] = q;
        }
    }
    __syncthreads();
    float p = wstats[0][tid] + wstats[1][tid] + wstats[2][tid] + wstats[3][tid];
    partials[(size_t)blockIdx.x * 256 + tid] = p;
}

// ----------------------------------------------------------- stats reduction
__global__ void bn_reduce(const float* __restrict__ partials,
                          float* __restrict__ partial2, int nblk) {
    int tid = threadIdx.x;
    float s = 0.f;
    for (int r = blockIdx.x; r < nblk; r += NRED)
        s += partials[(size_t)r * 256 + tid];
    partial2[blockIdx.x * 256 + tid] = s;
}

__global__ void bn_params(const float* __restrict__ partial2,
                          const float* __restrict__ g, const float* __restrict__ be,
                          float* __restrict__ affa, float* __restrict__ affc, int N) {
    int c = threadIdx.x;  // 128
    float s = 0.f, q = 0.f;
    #pragma unroll
    for (int b = 0; b < NRED; ++b) {
        s += partial2[b * 256 + c];
        q += partial2[b * 256 + 128 + c];
    }
    float n = (float)N;
    float mean = s / n;
    float var  = q / n - mean * mean;
    float a = g[c] * rsqrtf(var + 1e-5f);
    affa[c] = a;
    affc[c] = be[c] - mean * a;
}

// ------------------------------------------------------------------- accum
__global__ __launch_bounds__(256) void accum(const char* __restrict__ bufb,
                                             const float* __restrict__ affa,
                                             const float* __restrict__ affc,
                                             float* __restrict__ outp,
                                             int N, int first) {
    int total = N * 16;
    for (int i = blockIdx.x * 256 + threadIdx.x; i < total; i += gridDim.x * 256) {
        int row = i >> 4;
        int c8  = i & 15;
        f16x8 z = ((const f16x8*)(bufb + (size_t)row * 256))[c8];
        f32x4 a0 = ((const f32x4*)affa)[c8 * 2];
        f32x4 a1 = ((const f32x4*)affa)[c8 * 2 + 1];
        f32x4 c0 = ((const f32x4*)affc)[c8 * 2];
        f32x4 c1 = ((const f32x4*)affc)[c8 * 2 + 1];
        f32x4 r0, r1;
        #pragma unroll
        for (int j = 0; j < 4; ++j) {
            float t0 = (float)z[j] * a0[j] + c0[j];
            float t1 = (float)z[4 + j] * a1[j] + c1[j];
            r0[j] = t0 > 0.f ? t0 : 0.f;
            r1[j] = t1 > 0.f ? t1 : 0.f;
        }
        f32x4* o = (f32x4*)(outp + (size_t)row * 128) + c8 * 2;
        if (first) { o[0] = r0; o[1] = r1; }
        else       { f32x4 p0 = o[0], p1 = o[1]; o[0] = p0 + r0; o[1] = p1 + r1; }
    }
}

extern "C" void kernel_launch(void* const* d_in, const int* in_sizes, int n_in,
                              void* d_out, int out_size, void* d_ws, size_t ws_size,
                              hipStream_t stream) {
    const float* x0  = (const float*)d_in[0];
    const float* x1  = (const float*)d_in[1];
    const float* x2  = (const float*)d_in[2];
    const int*   ei  = (const int*)d_in[3];
    const float* W1  = (const float*)d_in[4];
    const float* b1  = (const float*)d_in[5];
    const float* g1  = (const float*)d_in[6];
    const float* be1 = (const float*)d_in[7];
    const float* W2  = (const float*)d_in[8];
    const float* b2  = (const float*)d_in[9];
    const float* g2  = (const float*)d_in[10];
    const float* be2 = (const float*)d_in[11];
    const float* eps9 = (const float*)d_in[12];
    float* outp = (float*)d_out;

    const int NC[3] = {200000, 3000, 20000};
    const size_t OUT_OFF[3] = {0, (size_t)200000 * D, (size_t)203000 * D};
    const float* xs[3] = {x0, x1, x2};

    char* ws = (char*)d_ws;
    char* bufb = ws;                                      // 200000*256 B row slabs
    size_t off = (size_t)200000 * 256;
    f16* x16_0 = (f16*)(ws + off); off += (size_t)200000 * 256;   // f16 shadow of x0
    int* deg      = (int*)(ws + off); off += (size_t)200001 * 4;
    int* rowstart = (int*)(ws + off); off += (size_t)200001 * 4;
    int* cursor   = (int*)(ws + off); off += (size_t)200000 * 4;
    int* ssrc     = (int*)(ws + off); off += (size_t)E_PER * 4;
    int* bsum     = (int*)(ws + off); off += 256 * 4;
    float* partials = (float*)(ws + off); off += (size_t)3125 * 256 * 4;
    float* partial2 = (float*)(ws + off); off += NRED * 256 * 4;
    float* aff1a = (float*)(ws + off); off += 512;
    float* aff1c = (float*)(ws + off); off += 512;
    float* aff2a = (float*)(ws + off); off += 512;
    float* aff2c = (float*)(ws + off); off += 512;
    f16* Wth = (f16*)(ws + off); off += (size_t)2 * 3 * 128 * 128 * sizeof(f16);

    precast<<<(98304 + 255) / 256, 256, 0, stream>>>(W1, W2, Wth);
    cast16<<<2048, 256, 0, stream>>>(x0, x16_0, 200000 * 32);

    for (int k = 0; k < 9; ++k) {
        int s = k / 3, t = k % 3;
        int N = NC[t];
        const int* srcp = ei + (size_t)k * 2 * E_PER;
        const int* dstp = srcp + E_PER;

        // ---- CSR build
        hipMemsetAsync(deg, 0, (size_t)N * 4, stream);
        deg_count<<<1024, 256, 0, stream>>>(dstp, deg, E_PER);
        int C  = (N + 255) / 256;
        int c2 = (C + 255) / 256;
        scan1<<<256, 256, 0, stream>>>(deg, bsum, N, C);
        scan2<<<1, 256, 0, stream>>>(bsum);
        scan3<<<256, 256, 0, stream>>>(deg, bsum, rowstart, cursor, N, C, c2);
        fill_csr<<<1024, 256, 0, stream>>>(srcp, dstp, cursor, ssrc, E_PER);

        // ---- aggregate (gather, no atomics)
        int wpr4 = (N <= 4000) ? 1 : 0;
        int agrid = wpr4 ? N : (N + 3) / 4;
        const void* xsrc = (s == 0) ? (const void*)x16_0 : (const void*)xs[s];
        aggregate<<<agrid, 256, 0, stream>>>(xsrc, (s == 0) ? 1 : 0, rowstart, ssrc, bufb, N, wpr4);

        // ---- MLP
        int gtiles = (N + 63) / 64;
        const float* xtf = (t == 0) ? nullptr : xs[t];
        const f16*   xth = (t == 0) ? x16_0 : nullptr;
        gemm_bn<<<gtiles, 256, 0, stream>>>(xtf, xth, bufb, Wth + (size_t)s * 16384,
                                            b1 + s * D, nullptr, nullptr,
                                            eps9, k, partials, N, 1);
        bn_reduce<<<NRED, 256, 0, stream>>>(partials, partial2, gtiles);
        bn_params<<<1, 128, 0, stream>>>(partial2, g1 + s * D, be1 + s * D, aff1a, aff1c, N);

        gemm_bn<<<gtiles, 256, 0, stream>>>(nullptr, nullptr, bufb, Wth + (size_t)(3 + s) * 16384,
                                            b2 + s * D, aff1a, aff1c,
                                            eps9, k, partials, N, 2);
        bn_reduce<<<NRED, 256, 0, stream>>>(partials, partial2, gtiles);
        bn_params<<<1, 128, 0, stream>>>(partial2, g2 + s * D, be2 + s * D, aff2a, aff2c, N);

        int nblk = (N * 16 + 255) / 256;
        if (nblk > 2048) nblk = 2048;
        accum<<<nblk, 256, 0, stream>>>(bufb, aff2a, aff2c, outp + OUT_OFF[t], N, (s == 0) ? 1 : 0);
    }
}

// Round 4
// 1666.441 us; speedup vs baseline: 4.2367x; 1.2774x over previous
//
#include <hip/hip_runtime.h>
#include <hip/hip_fp16.h>

#define D 128
#define E_PER 500000
#define NRED 32
#define TOT_ROWS 669000

typedef _Float16 f16;
typedef _Float16 f16x8 __attribute__((ext_vector_type(8)));
typedef _Float16 f16x4 __attribute__((ext_vector_type(4)));
typedef _Float16 f16x2 __attribute__((ext_vector_type(2)));
typedef float f32x4 __attribute__((ext_vector_type(4)));

// Per-edge-type row-segment bases in the concatenated CSR arrays (k = s*3 + t).
__device__ const int d_SEGB[9] = {0, 200000, 203000, 223000, 423000, 426000,
                                  446000, 646000, 649000};
// Row base of each node type inside the concatenated f16 feature table.
__device__ const int d_XB[3] = {0, 200000, 203000};

// XOR swizzle for the A tile in LDS (row stride 256B f16).
__device__ __forceinline__ unsigned a_swz(int row, int byteoff) {
    return (unsigned)(row * 256 + byteoff) ^ (unsigned)((row & 7) << 4);
}

// ---------------------------------------------------------------- precast W^T
__global__ void precast(const float* __restrict__ W1,
                        const float* __restrict__ W2,
                        f16* __restrict__ Wth) {
    int i = blockIdx.x * 256 + threadIdx.x;
    if (i >= 2 * 3 * 128 * 128) return;
    int layer = i / 49152;
    int rem = i - layer * 49152;
    int s = rem / 16384;
    int r2 = rem & 16383;
    int kk = r2 >> 7;
    int c  = r2 & 127;
    const float* W = layer ? W2 : W1;
    Wth[(((size_t)layer * 3 + s) * 128 + c) * 128 + kk] = (f16)W[((size_t)s * 128 + kk) * 128 + c];
}

// ------------------------------------------------------- all x -> f16 table
__global__ void cast16_all(const float* __restrict__ x0,
                           const float* __restrict__ x1,
                           const float* __restrict__ x2,
                           f16* __restrict__ y) {
    const int total = 223000 * 16;
    for (int i = blockIdx.x * 256 + threadIdx.x; i < total; i += gridDim.x * 256) {
        int row = i >> 4, c8 = i & 15;
        const float* src;
        if (row < 200000)      src = x0 + (size_t)row * D;
        else if (row < 203000) src = x1 + (size_t)(row - 200000) * D;
        else                   src = x2 + (size_t)(row - 203000) * D;
        f32x4 v0 = ((const f32x4*)src)[c8 * 2];
        f32x4 v1 = ((const f32x4*)src)[c8 * 2 + 1];
        f16x8 h;
        #pragma unroll
        for (int j = 0; j < 4; ++j) { h[j] = (f16)v0[j]; h[4 + j] = (f16)v1[j]; }
        ((f16x8*)(y + (size_t)row * D))[c8] = h;
    }
}

// ------------------------------------------------------------ batched CSR
__global__ void deg_count_all(const int* __restrict__ ei, int* __restrict__ deg) {
    int k = blockIdx.y;
    const int* dstp = ei + (size_t)k * 2 * E_PER + E_PER;
    int base = d_SEGB[k];
    int i = blockIdx.x * 256 + threadIdx.x;
    if (i < E_PER) atomicAdd(&deg[base + dstp[i]], 1);
}

__global__ void scan1(const int* __restrict__ deg, int* __restrict__ bsum, int N, int C) {
    __shared__ int red[256];
    int b = blockIdx.x, t = threadIdx.x;
    int lo = b * C, hi = min(lo + C, N);
    int s = 0;
    for (int i = lo + t; i < hi; i += 256) s += deg[i];
    red[t] = s; __syncthreads();
    for (int off = 128; off > 0; off >>= 1) {
        if (t < off) red[t] += red[t + off];
        __syncthreads();
    }
    if (t == 0) bsum[b] = red[0];
}

__global__ void scan2(int* __restrict__ bsum) {
    __shared__ int sb[256];
    int t = threadIdx.x;
    int v = bsum[t];
    sb[t] = v; __syncthreads();
    for (int off = 1; off < 256; off <<= 1) {
        int u = (t >= off) ? sb[t - off] : 0;
        __syncthreads();
        sb[t] += u;
        __syncthreads();
    }
    bsum[t] = sb[t] - v;   // exclusive
}

__global__ void scan3(const int* __restrict__ deg, const int* __restrict__ bsum,
                      int* __restrict__ rowstart, int* __restrict__ cursor,
                      int N, int C, int c2) {
    __shared__ int sb[256];
    int b = blockIdx.x, t = threadIdx.x;
    int cap = min(b * C + C, N);
    int lo = b * C + t * c2;
    int hi = min(lo + c2, cap);
    int s = 0;
    for (int i = lo; i < hi; ++i) s += deg[i];
    sb[t] = s; __syncthreads();
    int v = s;
    for (int off = 1; off < 256; off <<= 1) {
        int u = (t >= off) ? sb[t - off] : 0;
        __syncthreads();
        sb[t] += u;
        __syncthreads();
    }
    int pre = bsum[b] + sb[t] - v;
    for (int i = lo; i < hi; ++i) {
        rowstart[i] = pre;
        cursor[i]   = pre;
        pre += deg[i];
        if (i == N - 1) rowstart[N] = pre;
    }
}

__global__ void fill_all(const int* __restrict__ ei, int* __restrict__ cursor,
                         int* __restrict__ ssrc) {
    int k = blockIdx.y;
    const int* srcp = ei + (size_t)k * 2 * E_PER;
    const int* dstp = srcp + E_PER;
    int base = d_SEGB[k];
    int i = blockIdx.x * 256 + threadIdx.x;
    if (i < E_PER) {
        int pos = atomicAdd(&cursor[base + dstp[i]], 1);
        ssrc[pos] = srcp[i];
    }
}

// --------------------------------------------- standalone aggregate (t=1,2)
// blockIdx.y = s. Gather segment-sum into f16 slab rows (256 B).
__global__ __launch_bounds__(256) void aggregate_b(const f16* __restrict__ x16,
                                                   const int* __restrict__ rowstart,
                                                   const int* __restrict__ ssrc,
                                                   char* __restrict__ slabs, size_t slabN,
                                                   int t, int N, int wpr4) {
    __shared__ float part[4][130];
    int s = blockIdx.y;
    int k = s * 3 + t;
    const int* rs = rowstart + d_SEGB[k];
    const f16* xsrc = x16 + (size_t)d_XB[s] * D;
    char* slab = slabs + (size_t)s * slabN;
    int lane = threadIdx.x & 63;
    int w    = threadIdx.x >> 6;
    int row, sub, wpr;
    if (wpr4) { row = blockIdx.x; sub = w; wpr = 4; }
    else      { row = (blockIdx.x << 2) + w; sub = 0; wpr = 1; }
    float r0 = 0.f, r1 = 0.f;
    if (row < N) {
        int e0 = rs[row], e1 = rs[row + 1];
        float a0=0,a1=0,b0=0,b1=0,c0=0,c1=0,d0=0,d1=0;
        int e = e0 + sub;
        for (; e + 3 * wpr < e1; e += 4 * wpr) {
            int s0 = ssrc[e], s1 = ssrc[e + wpr], s2 = ssrc[e + 2 * wpr], s3 = ssrc[e + 3 * wpr];
            f16x2 v0 = *(const f16x2*)(xsrc + (size_t)s0 * D + lane * 2);
            f16x2 v1 = *(const f16x2*)(xsrc + (size_t)s1 * D + lane * 2);
            f16x2 v2 = *(const f16x2*)(xsrc + (size_t)s2 * D + lane * 2);
            f16x2 v3 = *(const f16x2*)(xsrc + (size_t)s3 * D + lane * 2);
            a0 += (float)v0[0]; a1 += (float)v0[1];
            b0 += (float)v1[0]; b1 += (float)v1[1];
            c0 += (float)v2[0]; c1 += (float)v2[1];
            d0 += (float)v3[0]; d1 += (float)v3[1];
        }
        for (; e < e1; e += wpr) {
            int s0 = ssrc[e];
            f16x2 v0 = *(const f16x2*)(xsrc + (size_t)s0 * D + lane * 2);
            a0 += (float)v0[0]; a1 += (float)v0[1];
        }
        r0 = (a0 + b0) + (c0 + d0);
        r1 = (a1 + b1) + (c1 + d1);
    }
    if (wpr4) {
        part[w][lane * 2] = r0; part[w][lane * 2 + 1] = r1;
        __syncthreads();
        if (w == 0 && row < N) {
            float s0 = part[0][lane*2] + part[1][lane*2] + part[2][lane*2] + part[3][lane*2];
            float s1 = part[0][lane*2+1] + part[1][lane*2+1] + part[2][lane*2+1] + part[3][lane*2+1];
            f16x2 h; h[0] = (f16)s0; h[1] = (f16)s1;
            *(f16x2*)(slab + (size_t)row * 256 + lane * 4) = h;
        }
    } else if (row < N) {
        f16x2 h; h[0] = (f16)r0; h[1] = (f16)r1;
        *(f16x2*)(slab + (size_t)row * 256 + lane * 4) = h;
    }
}

// -------------------------------------------------- layer-1 GEMM, 3 s fused
// 128 rows/block; per s: stage A = (1+eps_k)*x_t + agg_s (gather from CSR when
// gather=1, else read slab), MFMA vs W1_s, epilogue: +bias, store z1 f16 into
// slab_s, per-block column stats -> partials[block][s][256].
__global__ __launch_bounds__(256) void gemm13(const f16* __restrict__ x16,
                                              const int* __restrict__ rowstart,
                                              const int* __restrict__ ssrc,
                                              char* __restrict__ slabs, size_t slabN,
                                              const f16* __restrict__ Wth,
                                              const float* __restrict__ b1,
                                              const float* __restrict__ eps9,
                                              float* __restrict__ partials,
                                              int N, int t, int gather) {
    __shared__ alignas(16) char atile[128 * 256];
    __shared__ float wst[4][256];
    const int tid  = threadIdx.x;
    const int lane = tid & 63;
    const int w    = tid >> 6;
    const int row0 = blockIdx.x * 128;
    const f16* xt = x16 + (size_t)d_XB[t] * D;

    for (int s = 0; s < 3; ++s) {
        const int k = s * 3 + t;
        const float epsv = 1.0f + eps9[k];
        char* slab = slabs + (size_t)s * slabN;

        if (gather) {
            const f16* xsrc = x16 + (size_t)d_XB[s] * D;
            const int* rs = rowstart + d_SEGB[k];
            for (int p = 0; p < 8; ++p) {
                int rp = p * 16 + (tid >> 4);
                int c8 = tid & 15;
                int row = row0 + rp;
                f16x8 hv = {0, 0, 0, 0, 0, 0, 0, 0};
                if (row < N) {
                    f16x8 xv = ((const f16x8*)(xt + (size_t)row * D))[c8];
                    float sum[8];
                    #pragma unroll
                    for (int j = 0; j < 8; ++j) sum[j] = epsv * (float)xv[j];
                    int e1 = rs[row + 1];
                    for (int e = rs[row]; e < e1; ++e) {
                        f16x8 v = ((const f16x8*)(xsrc + (size_t)ssrc[e] * D))[c8];
                        #pragma unroll
                        for (int j = 0; j < 8; ++j) sum[j] += (float)v[j];
                    }
                    #pragma unroll
                    for (int j = 0; j < 8; ++j) hv[j] = (f16)sum[j];
                }
                *(f16x8*)(atile + a_swz(rp, c8 * 16)) = hv;
            }
        } else {
            #pragma unroll
            for (int p = 0; p < 8; ++p) {
                int rp = p * 16 + (tid >> 4);
                int c8 = tid & 15;
                int row = row0 + rp;
                f16x8 hv = {0, 0, 0, 0, 0, 0, 0, 0};
                if (row < N) {
                    f16x8 ag = ((const f16x8*)(slab + (size_t)row * 256))[c8];
                    f16x8 xv = ((const f16x8*)(xt + (size_t)row * D))[c8];
                    #pragma unroll
                    for (int j = 0; j < 8; ++j) hv[j] = (f16)(epsv * (float)xv[j] + (float)ag[j]);
                }
                *(f16x8*)(atile + a_swz(rp, c8 * 16)) = hv;
            }
        }
        __syncthreads();

        const f16* Wt = Wth + (size_t)s * 16384;
        f32x4 acc0[8], acc1[8];
        #pragma unroll
        for (int ct = 0; ct < 8; ++ct) {
            acc0[ct] = (f32x4){0.f, 0.f, 0.f, 0.f};
            acc1[ct] = (f32x4){0.f, 0.f, 0.f, 0.f};
        }
        const int arow0 = (w << 5) + (lane & 15);
        const int arow1 = arow0 + 16;
        const int kq = (lane >> 4) * 8;
        #pragma unroll
        for (int ks = 0; ks < 4; ++ks) {
            f16x8 af0 = *(const f16x8*)(atile + a_swz(arow0, (ks * 32 + kq) * 2));
            f16x8 af1 = *(const f16x8*)(atile + a_swz(arow1, (ks * 32 + kq) * 2));
            #pragma unroll
            for (int ct = 0; ct < 8; ++ct) {
                f16x8 bf = *(const f16x8*)(Wt + (size_t)(ct * 16 + (lane & 15)) * D + ks * 32 + kq);
                acc0[ct] = __builtin_amdgcn_mfma_f32_16x16x32_f16(af0, bf, acc0[ct], 0, 0, 0);
                acc1[ct] = __builtin_amdgcn_mfma_f32_16x16x32_f16(af1, bf, acc1[ct], 0, 0, 0);
            }
        }

        const int col_lo = lane & 15;
        const int rb0 = row0 + (w << 5) + ((lane >> 4) << 2);
        const int rb1 = rb0 + 16;
        #pragma unroll
        for (int ct = 0; ct < 8; ++ct) {
            int col = ct * 16 + col_lo;
            float bv = b1[s * D + col];
            float s_ = 0.f, q_ = 0.f;
            #pragma unroll
            for (int r = 0; r < 4; ++r) {
                int row = rb0 + r;
                float val = acc0[ct][r] + bv;
                if (row < N) {
                    *(f16*)(slab + (size_t)row * 256 + col * 2) = (f16)val;
                    s_ += val; q_ += val * val;
                }
            }
            #pragma unroll
            for (int r = 0; r < 4; ++r) {
                int row = rb1 + r;
                float val = acc1[ct][r] + bv;
                if (row < N) {
                    *(f16*)(slab + (size_t)row * 256 + col * 2) = (f16)val;
                    s_ += val; q_ += val * val;
                }
            }
            s_ += __shfl_xor(s_, 16); q_ += __shfl_xor(q_, 16);
            s_ += __shfl_xor(s_, 32); q_ += __shfl_xor(q_, 32);
            if (lane < 16) { wst[w][col] = s_; wst[w][128 + col] = q_; }
        }
        __syncthreads();
        float p = wst[0][tid] + wst[1][tid] + wst[2][tid] + wst[3][tid];
        partials[((size_t)blockIdx.x * 3 + s) * 256 + tid] = p;
    }
}

// -------------------------------------------------- layer-2 GEMM, 3 s fused
__global__ __launch_bounds__(256) void gemm23(char* __restrict__ slabs, size_t slabN,
                                              const f16* __restrict__ Wth2,
                                              const float* __restrict__ b2,
                                              const float* __restrict__ affa,
                                              const float* __restrict__ affc,
                                              float* __restrict__ partials, int N) {
    __shared__ alignas(16) char atile[128 * 256];
    __shared__ float wst[4][256];
    __shared__ alignas(16) float afa[384];
    __shared__ alignas(16) float afc[384];
    const int tid  = threadIdx.x;
    const int lane = tid & 63;
    const int w    = tid >> 6;
    const int row0 = blockIdx.x * 128;

    for (int i = tid; i < 384; i += 256) { afa[i] = affa[i]; afc[i] = affc[i]; }
    __syncthreads();

    for (int s = 0; s < 3; ++s) {
        char* slab = slabs + (size_t)s * slabN;
        #pragma unroll
        for (int p = 0; p < 8; ++p) {
            int rp = p * 16 + (tid >> 4);
            int c8 = tid & 15;
            int row = row0 + rp;
            f16x8 hv = {0, 0, 0, 0, 0, 0, 0, 0};
            if (row < N) {
                f16x8 zv = ((const f16x8*)(slab + (size_t)row * 256))[c8];
                f32x4 a0 = *(const f32x4*)(afa + s * 128 + c8 * 8);
                f32x4 a1 = *(const f32x4*)(afa + s * 128 + c8 * 8 + 4);
                f32x4 c0 = *(const f32x4*)(afc + s * 128 + c8 * 8);
                f32x4 c1 = *(const f32x4*)(afc + s * 128 + c8 * 8 + 4);
                #pragma unroll
                for (int j = 0; j < 4; ++j) {
                    float t0 = (float)zv[j] * a0[j] + c0[j];
                    float t1 = (float)zv[4 + j] * a1[j] + c1[j];
                    hv[j]     = (f16)(t0 > 0.f ? t0 : 0.f);
                    hv[4 + j] = (f16)(t1 > 0.f ? t1 : 0.f);
                }
            }
            *(f16x8*)(atile + a_swz(rp, c8 * 16)) = hv;
        }
        __syncthreads();

        const f16* Wt = Wth2 + (size_t)s * 16384;
        f32x4 acc0[8], acc1[8];
        #pragma unroll
        for (int ct = 0; ct < 8; ++ct) {
            acc0[ct] = (f32x4){0.f, 0.f, 0.f, 0.f};
            acc1[ct] = (f32x4){0.f, 0.f, 0.f, 0.f};
        }
        const int arow0 = (w << 5) + (lane & 15);
        const int arow1 = arow0 + 16;
        const int kq = (lane >> 4) * 8;
        #pragma unroll
        for (int ks = 0; ks < 4; ++ks) {
            f16x8 af0 = *(const f16x8*)(atile + a_swz(arow0, (ks * 32 + kq) * 2));
            f16x8 af1 = *(const f16x8*)(atile + a_swz(arow1, (ks * 32 + kq) * 2));
            #pragma unroll
            for (int ct = 0; ct < 8; ++ct) {
                f16x8 bf = *(const f16x8*)(Wt + (size_t)(ct * 16 + (lane & 15)) * D + ks * 32 + kq);
                acc0[ct] = __builtin_amdgcn_mfma_f32_16x16x32_f16(af0, bf, acc0[ct], 0, 0, 0);
                acc1[ct] = __builtin_amdgcn_mfma_f32_16x16x32_f16(af1, bf, acc1[ct], 0, 0, 0);
            }
        }

        const int col_lo = lane & 15;
        const int rb0 = row0 + (w << 5) + ((lane >> 4) << 2);
        const int rb1 = rb0 + 16;
        #pragma unroll
        for (int ct = 0; ct < 8; ++ct) {
            int col = ct * 16 + col_lo;
            float bv = b2[s * D + col];
            float s_ = 0.f, q_ = 0.f;
            #pragma unroll
            for (int r = 0; r < 4; ++r) {
                int row = rb0 + r;
                float val = acc0[ct][r] + bv;
                if (row < N) {
                    *(f16*)(slab + (size_t)row * 256 + col * 2) = (f16)val;
                    s_ += val; q_ += val * val;
                }
            }
            #pragma unroll
            for (int r = 0; r < 4; ++r) {
                int row = rb1 + r;
                float val = acc1[ct][r] + bv;
                if (row < N) {
                    *(f16*)(slab + (size_t)row * 256 + col * 2) = (f16)val;
                    s_ += val; q_ += val * val;
                }
            }
            s_ += __shfl_xor(s_, 16); q_ += __shfl_xor(q_, 16);
            s_ += __shfl_xor(s_, 32); q_ += __shfl_xor(q_, 32);
            if (lane < 16) { wst[w][col] = s_; wst[w][128 + col] = q_; }
        }
        __syncthreads();
        float p = wst[0][tid] + wst[1][tid] + wst[2][tid] + wst[3][tid];
        partials[((size_t)blockIdx.x * 3 + s) * 256 + tid] = p;
    }
}

// ----------------------------------------------------------- stats reduction
__global__ void bn_reduce3(const float* __restrict__ partials,
                           float* __restrict__ partial2, int nblk) {
    int s = blockIdx.y, tid = threadIdx.x;
    float v = 0.f;
    for (int b = blockIdx.x; b < nblk; b += NRED)
        v += partials[((size_t)b * 3 + s) * 256 + tid];
    partial2[((size_t)s * NRED + blockIdx.x) * 256 + tid] = v;
}

__global__ void bn_params3(const float* __restrict__ partial2,
                           const float* __restrict__ g, const float* __restrict__ be,
                           float* __restrict__ affa, float* __restrict__ affc, int N) {
    int s = blockIdx.x, c = threadIdx.x;  // 128 threads
    float sm = 0.f, q = 0.f;
    #pragma unroll
    for (int b = 0; b < NRED; ++b) {
        sm += partial2[((size_t)s * NRED + b) * 256 + c];
        q  += partial2[((size_t)s * NRED + b) * 256 + 128 + c];
    }
    float n = (float)N;
    float mean = sm / n;
    float var  = q / n - mean * mean;
    float a = g[s * D + c] * rsqrtf(var + 1e-5f);
    affa[s * 128 + c] = a;
    affc[s * 128 + c] = be[s * D + c] - mean * a;
}

// ----------------------------------------------------- final accum (3 s sum)
__global__ __launch_bounds__(256) void accum3(const char* __restrict__ slabs, size_t slabN,
                                              const float* __restrict__ affa,
                                              const float* __restrict__ affc,
                                              float* __restrict__ outp, int N) {
    int total = N * 16;
    for (int i = blockIdx.x * 256 + threadIdx.x; i < total; i += gridDim.x * 256) {
        int row = i >> 4;
        int c8  = i & 15;
        f32x4 o0 = {0.f, 0.f, 0.f, 0.f}, o1 = {0.f, 0.f, 0.f, 0.f};
        #pragma unroll
        for (int s = 0; s < 3; ++s) {
            f16x8 z = ((const f16x8*)(slabs + (size_t)s * slabN + (size_t)row * 256))[c8];
            f32x4 a0 = ((const f32x4*)(affa + s * 128))[c8 * 2];
            f32x4 a1 = ((const f32x4*)(affa + s * 128))[c8 * 2 + 1];
            f32x4 c0 = ((const f32x4*)(affc + s * 128))[c8 * 2];
            f32x4 c1 = ((const f32x4*)(affc + s * 128))[c8 * 2 + 1];
            #pragma unroll
            for (int j = 0; j < 4; ++j) {
                float t0 = (float)z[j] * a0[j] + c0[j];
                float t1 = (float)z[4 + j] * a1[j] + c1[j];
                o0[j] += t0 > 0.f ? t0 : 0.f;
                o1[j] += t1 > 0.f ? t1 : 0.f;
            }
        }
        ((f32x4*)(outp + (size_t)row * D))[c8 * 2]     = o0;
        ((f32x4*)(outp + (size_t)row * D))[c8 * 2 + 1] = o1;
    }
}

extern "C" void kernel_launch(void* const* d_in, const int* in_sizes, int n_in,
                              void* d_out, int out_size, void* d_ws, size_t ws_size,
                              hipStream_t stream) {
    const float* x0  = (const float*)d_in[0];
    const float* x1  = (const float*)d_in[1];
    const float* x2  = (const float*)d_in[2];
    const int*   ei  = (const int*)d_in[3];
    const float* W1  = (const float*)d_in[4];
    const float* b1  = (const float*)d_in[5];
    const float* g1  = (const float*)d_in[6];
    const float* be1 = (const float*)d_in[7];
    const float* W2  = (const float*)d_in[8];
    const float* b2  = (const float*)d_in[9];
    const float* g2  = (const float*)d_in[10];
    const float* be2 = (const float*)d_in[11];
    const float* eps9 = (const float*)d_in[12];
    float* outp = (float*)d_out;

    const int NC[3] = {200000, 3000, 20000};
    const size_t OUT_OFF[3] = {0, (size_t)200000 * D, (size_t)203000 * D};

    char* ws = (char*)d_ws;
    size_t off = 0;
    char* slabs = ws;                 off += (size_t)3 * 200000 * 256;     // 153.6 MB
    f16* x16    = (f16*)(ws + off);   off += (size_t)223000 * 256;         // 57.1 MB
    int* ssrc   = (int*)(ws + off);   off += (size_t)9 * E_PER * 4;        // 18 MB
    int* rowstart = (int*)(ws + off); off += (size_t)(TOT_ROWS + 2) * 4;
    off = (off + 255) & ~(size_t)255;
    int* cursor = (int*)(ws + off);   off += (size_t)TOT_ROWS * 4;
    off = (off + 255) & ~(size_t)255;
    int* deg    = (int*)(ws + off);   off += (size_t)TOT_ROWS * 4;
    off = (off + 255) & ~(size_t)255;
    int* bsum   = (int*)(ws + off);   off += 1024;
    float* partials = (float*)(ws + off); off += (size_t)1563 * 3 * 256 * 4;
    float* partial2 = (float*)(ws + off); off += (size_t)3 * NRED * 256 * 4;
    float* aff1a = (float*)(ws + off); off += 1536;
    float* aff1c = (float*)(ws + off); off += 1536;
    float* aff2a = (float*)(ws + off); off += 1536;
    float* aff2c = (float*)(ws + off); off += 1536;
    f16* Wth = (f16*)(ws + off); off += (size_t)2 * 3 * 128 * 128 * sizeof(f16);

    // ---- setup
    precast<<<384, 256, 0, stream>>>(W1, W2, Wth);
    cast16_all<<<2048, 256, 0, stream>>>(x0, x1, x2, x16);

    // ---- batched CSR over all 9 edge types
    hipMemsetAsync(deg, 0, (size_t)TOT_ROWS * 4, stream);
    int eblk = (E_PER + 255) / 256;
    deg_count_all<<<dim3(eblk, 9), 256, 0, stream>>>(ei, deg);
    int C  = (TOT_ROWS + 255) / 256;   // 2614
    int c2 = (C + 255) / 256;          // 11
    scan1<<<256, 256, 0, stream>>>(deg, bsum, TOT_ROWS, C);
    scan2<<<1, 256, 0, stream>>>(bsum);
    scan3<<<256, 256, 0, stream>>>(deg, bsum, rowstart, cursor, TOT_ROWS, C, c2);
    fill_all<<<dim3(eblk, 9), 256, 0, stream>>>(ei, cursor, ssrc);

    // ---- per target type
    for (int t = 0; t < 3; ++t) {
        int N = NC[t];
        size_t slabN = (size_t)N * 256;
        int gtiles = (N + 127) / 128;

        if (t == 1) {
            aggregate_b<<<dim3(N, 3), 256, 0, stream>>>(x16, rowstart, ssrc, slabs, slabN, t, N, 1);
        } else if (t == 2) {
            aggregate_b<<<dim3((N + 3) / 4, 3), 256, 0, stream>>>(x16, rowstart, ssrc, slabs, slabN, t, N, 0);
        }

        gemm13<<<gtiles, 256, 0, stream>>>(x16, rowstart, ssrc, slabs, slabN,
                                           Wth, b1, eps9, partials, N, t, (t == 0) ? 1 : 0);
        bn_reduce3<<<dim3(NRED, 3), 256, 0, stream>>>(partials, partial2, gtiles);
        bn_params3<<<3, 128, 0, stream>>>(partial2, g1, be1, aff1a, aff1c, N);

        gemm23<<<gtiles, 256, 0, stream>>>(slabs, slabN, Wth + 3 * 16384, b2,
                                           aff1a, aff1c, partials, N);
        bn_reduce3<<<dim3(NRED, 3), 256, 0, stream>>>(partials, partial2, gtiles);
        bn_params3<<<3, 128, 0, stream>>>(partial2, g2, be2, aff2a, aff2c, N);

        int nblk = (N * 16 + 255) / 256;
        if (nblk > 2048) nblk = 2048;
        accum3<<<nblk, 256, 0, stream>>>(slabs, slabN, aff2a, aff2c, outp + OUT_OFF[t], N);
    }
}

// Round 5
// 1638.507 us; speedup vs baseline: 4.3089x; 1.0170x over previous
//
#include <hip/hip_runtime.h>
#include <hip/hip_fp16.h>

#define D 128
#define E_PER 500000
#define NRED 32
#define TOT_ROWS 669000

typedef _Float16 f16;
typedef _Float16 f16x8 __attribute__((ext_vector_type(8)));
typedef _Float16 f16x4 __attribute__((ext_vector_type(4)));
typedef _Float16 f16x2 __attribute__((ext_vector_type(2)));
typedef float f32x4 __attribute__((ext_vector_type(4)));

// Per-edge-type row-segment bases in the concatenated CSR arrays (k = s*3 + t).
__device__ const int d_SEGB[9] = {0, 200000, 203000, 223000, 423000, 426000,
                                  446000, 646000, 649000};
// Row base of each node type inside the concatenated f16 feature table.
__device__ const int d_XB[3] = {0, 200000, 203000};

// XOR swizzle for the A tile in LDS (row stride 256B f16).
__device__ __forceinline__ unsigned a_swz(int row, int byteoff) {
    return (unsigned)(row * 256 + byteoff) ^ (unsigned)((row & 7) << 4);
}

// ---------------------------------------------------------------- precast W^T
__global__ void precast(const float* __restrict__ W1,
                        const float* __restrict__ W2,
                        f16* __restrict__ Wth) {
    int i = blockIdx.x * 256 + threadIdx.x;
    if (i >= 2 * 3 * 128 * 128) return;
    int layer = i / 49152;
    int rem = i - layer * 49152;
    int s = rem / 16384;
    int r2 = rem & 16383;
    int kk = r2 >> 7;
    int c  = r2 & 127;
    const float* W = layer ? W2 : W1;
    Wth[(((size_t)layer * 3 + s) * 128 + c) * 128 + kk] = (f16)W[((size_t)s * 128 + kk) * 128 + c];
}

// ------------------------------------------------------- all x -> f16 table
__global__ void cast16_all(const float* __restrict__ x0,
                           const float* __restrict__ x1,
                           const float* __restrict__ x2,
                           f16* __restrict__ y) {
    const int total = 223000 * 16;
    for (int i = blockIdx.x * 256 + threadIdx.x; i < total; i += gridDim.x * 256) {
        int row = i >> 4, c8 = i & 15;
        const float* src;
        if (row < 200000)      src = x0 + (size_t)row * D;
        else if (row < 203000) src = x1 + (size_t)(row - 200000) * D;
        else                   src = x2 + (size_t)(row - 203000) * D;
        f32x4 v0 = ((const f32x4*)src)[c8 * 2];
        f32x4 v1 = ((const f32x4*)src)[c8 * 2 + 1];
        f16x8 h;
        #pragma unroll
        for (int j = 0; j < 4; ++j) { h[j] = (f16)v0[j]; h[4 + j] = (f16)v1[j]; }
        ((f16x8*)(y + (size_t)row * D))[c8] = h;
    }
}

// ------------------------------------------------------------ batched CSR
__global__ void deg_count_all(const int* __restrict__ ei, int* __restrict__ deg) {
    int k = blockIdx.y;
    const int* dstp = ei + (size_t)k * 2 * E_PER + E_PER;
    int base = d_SEGB[k];
    int i = blockIdx.x * 256 + threadIdx.x;
    if (i < E_PER) atomicAdd(&deg[base + dstp[i]], 1);
}

__global__ void scan1(const int* __restrict__ deg, int* __restrict__ bsum, int N, int C) {
    __shared__ int red[256];
    int b = blockIdx.x, t = threadIdx.x;
    int lo = b * C, hi = min(lo + C, N);
    int s = 0;
    for (int i = lo + t; i < hi; i += 256) s += deg[i];
    red[t] = s; __syncthreads();
    for (int off = 128; off > 0; off >>= 1) {
        if (t < off) red[t] += red[t + off];
        __syncthreads();
    }
    if (t == 0) bsum[b] = red[0];
}

__global__ void scan2(int* __restrict__ bsum) {
    __shared__ int sb[256];
    int t = threadIdx.x;
    int v = bsum[t];
    sb[t] = v; __syncthreads();
    for (int off = 1; off < 256; off <<= 1) {
        int u = (t >= off) ? sb[t - off] : 0;
        __syncthreads();
        sb[t] += u;
        __syncthreads();
    }
    bsum[t] = sb[t] - v;   // exclusive
}

__global__ void scan3(const int* __restrict__ deg, const int* __restrict__ bsum,
                      int* __restrict__ rowstart, int* __restrict__ cursor,
                      int N, int C, int c2) {
    __shared__ int sb[256];
    int b = blockIdx.x, t = threadIdx.x;
    int cap = min(b * C + C, N);
    int lo = b * C + t * c2;
    int hi = min(lo + c2, cap);
    int s = 0;
    for (int i = lo; i < hi; ++i) s += deg[i];
    sb[t] = s; __syncthreads();
    int v = s;
    for (int off = 1; off < 256; off <<= 1) {
        int u = (t >= off) ? sb[t - off] : 0;
        __syncthreads();
        sb[t] += u;
        __syncthreads();
    }
    int pre = bsum[b] + sb[t] - v;
    for (int i = lo; i < hi; ++i) {
        rowstart[i] = pre;
        cursor[i]   = pre;
        pre += deg[i];
        if (i == N - 1) rowstart[N] = pre;
    }
}

__global__ void fill_all(const int* __restrict__ ei, int* __restrict__ cursor,
                         int* __restrict__ ssrc) {
    int k = blockIdx.y;
    const int* srcp = ei + (size_t)k * 2 * E_PER;
    const int* dstp = srcp + E_PER;
    int base = d_SEGB[k];
    int i = blockIdx.x * 256 + threadIdx.x;
    if (i < E_PER) {
        int pos = atomicAdd(&cursor[base + dstp[i]], 1);
        ssrc[pos] = srcp[i];
    }
}

// ---------------------------------------------------------------- aggregate
// blockIdx.y = s. slab_s[row] = (1+eps_k)*x_t[row] + sum_{e in row} x_s[src[e]],
// stored f16 (256 B/row). wpr4=1: 4 waves/row (high degree); else wave/row.
__global__ __launch_bounds__(256) void aggregate_b(const f16* __restrict__ x16,
                                                   const int* __restrict__ rowstart,
                                                   const int* __restrict__ ssrc,
                                                   char* __restrict__ slabs, size_t slabN,
                                                   const float* __restrict__ eps9,
                                                   int t, int N, int wpr4) {
    __shared__ float part[4][130];
    int s = blockIdx.y;
    int k = s * 3 + t;
    const int* rs = rowstart + d_SEGB[k];
    const f16* xsrc = x16 + (size_t)d_XB[s] * D;
    const f16* xt   = x16 + (size_t)d_XB[t] * D;
    char* slab = slabs + (size_t)s * slabN;
    float epsv = 1.0f + eps9[k];
    int lane = threadIdx.x & 63;
    int w    = threadIdx.x >> 6;
    int row, sub, wpr;
    if (wpr4) { row = blockIdx.x; sub = w; wpr = 4; }
    else      { row = (blockIdx.x << 2) + w; sub = 0; wpr = 1; }
    float r0 = 0.f, r1 = 0.f;
    if (row < N) {
        if (sub == 0) {
            f16x2 xv = *(const f16x2*)(xt + (size_t)row * D + lane * 2);
            r0 = epsv * (float)xv[0];
            r1 = epsv * (float)xv[1];
        }
        int e1 = rs[row + 1];
        int e  = rs[row] + sub;
        float a0=0,a1=0,b0=0,b1=0,c0=0,c1=0,d0=0,d1=0;
        // 4-way
        for (; e + 3 * wpr < e1; e += 4 * wpr) {
            int s0 = ssrc[e], s1 = ssrc[e + wpr], s2 = ssrc[e + 2 * wpr], s3 = ssrc[e + 3 * wpr];
            f16x2 v0 = *(const f16x2*)(xsrc + (size_t)s0 * D + lane * 2);
            f16x2 v1 = *(const f16x2*)(xsrc + (size_t)s1 * D + lane * 2);
            f16x2 v2 = *(const f16x2*)(xsrc + (size_t)s2 * D + lane * 2);
            f16x2 v3 = *(const f16x2*)(xsrc + (size_t)s3 * D + lane * 2);
            a0 += (float)v0[0]; a1 += (float)v0[1];
            b0 += (float)v1[0]; b1 += (float)v1[1];
            c0 += (float)v2[0]; c1 += (float)v2[1];
            d0 += (float)v3[0]; d1 += (float)v3[1];
        }
        // 2-way
        if (e + wpr < e1) {
            int s0 = ssrc[e], s1 = ssrc[e + wpr];
            f16x2 v0 = *(const f16x2*)(xsrc + (size_t)s0 * D + lane * 2);
            f16x2 v1 = *(const f16x2*)(xsrc + (size_t)s1 * D + lane * 2);
            a0 += (float)v0[0]; a1 += (float)v0[1];
            b0 += (float)v1[0]; b1 += (float)v1[1];
            e += 2 * wpr;
        }
        // 1-way tail
        if (e < e1) {
            int s0 = ssrc[e];
            f16x2 v0 = *(const f16x2*)(xsrc + (size_t)s0 * D + lane * 2);
            a0 += (float)v0[0]; a1 += (float)v0[1];
        }
        r0 += (a0 + b0) + (c0 + d0);
        r1 += (a1 + b1) + (c1 + d1);
    }
    if (wpr4) {
        part[w][lane * 2] = r0; part[w][lane * 2 + 1] = r1;
        __syncthreads();
        if (w == 0 && row < N) {
            float s0 = part[0][lane*2] + part[1][lane*2] + part[2][lane*2] + part[3][lane*2];
            float s1 = part[0][lane*2+1] + part[1][lane*2+1] + part[2][lane*2+1] + part[3][lane*2+1];
            f16x2 h; h[0] = (f16)s0; h[1] = (f16)s1;
            *(f16x2*)(slab + (size_t)row * 256 + lane * 4) = h;
        }
    } else if (row < N) {
        f16x2 h; h[0] = (f16)r0; h[1] = (f16)r1;
        *(f16x2*)(slab + (size_t)row * 256 + lane * 4) = h;
    }
}

// ---------------------------------------------------- GEMM (both layers), 3 s fused
// affa==nullptr: layer 1 — A = slab (already (1+eps)x+agg, f16 copy).
// affa!=nullptr: layer 2 — A = relu(slab*affa + affc).
// Epilogue: z = A@W_s + bias_s stored f16 into slab_s; block column stats -> partials.
__global__ __launch_bounds__(256) void gemm3(char* __restrict__ slabs, size_t slabN,
                                             const f16* __restrict__ Wth,
                                             const float* __restrict__ bias,
                                             const float* __restrict__ affa,
                                             const float* __restrict__ affc,
                                             float* __restrict__ partials, int N) {
    __shared__ alignas(16) char atile[128 * 256];
    __shared__ float wst[4][256];
    __shared__ alignas(16) float afa[384];
    __shared__ alignas(16) float afc[384];
    const int tid  = threadIdx.x;
    const int lane = tid & 63;
    const int w    = tid >> 6;
    const int row0 = blockIdx.x * 128;

    if (affa) {
        for (int i = tid; i < 384; i += 256) { afa[i] = affa[i]; afc[i] = affc[i]; }
    }
    __syncthreads();

    for (int s = 0; s < 3; ++s) {
        char* slab = slabs + (size_t)s * slabN;
        #pragma unroll
        for (int p = 0; p < 8; ++p) {
            int rp = p * 16 + (tid >> 4);
            int c8 = tid & 15;
            int row = row0 + rp;
            f16x8 hv = {0, 0, 0, 0, 0, 0, 0, 0};
            if (row < N) {
                hv = ((const f16x8*)(slab + (size_t)row * 256))[c8];
                if (affa) {
                    f32x4 a0 = *(const f32x4*)(afa + s * 128 + c8 * 8);
                    f32x4 a1 = *(const f32x4*)(afa + s * 128 + c8 * 8 + 4);
                    f32x4 c0 = *(const f32x4*)(afc + s * 128 + c8 * 8);
                    f32x4 c1 = *(const f32x4*)(afc + s * 128 + c8 * 8 + 4);
                    #pragma unroll
                    for (int j = 0; j < 4; ++j) {
                        float t0 = (float)hv[j] * a0[j] + c0[j];
                        float t1 = (float)hv[4 + j] * a1[j] + c1[j];
                        hv[j]     = (f16)(t0 > 0.f ? t0 : 0.f);
                        hv[4 + j] = (f16)(t1 > 0.f ? t1 : 0.f);
                    }
                }
            }
            *(f16x8*)(atile + a_swz(rp, c8 * 16)) = hv;
        }
        __syncthreads();

        const f16* Wt = Wth + (size_t)s * 16384;
        f32x4 acc0[8], acc1[8];
        #pragma unroll
        for (int ct = 0; ct < 8; ++ct) {
            acc0[ct] = (f32x4){0.f, 0.f, 0.f, 0.f};
            acc1[ct] = (f32x4){0.f, 0.f, 0.f, 0.f};
        }
        const int arow0 = (w << 5) + (lane & 15);
        const int arow1 = arow0 + 16;
        const int kq = (lane >> 4) * 8;
        #pragma unroll
        for (int ks = 0; ks < 4; ++ks) {
            f16x8 af0 = *(const f16x8*)(atile + a_swz(arow0, (ks * 32 + kq) * 2));
            f16x8 af1 = *(const f16x8*)(atile + a_swz(arow1, (ks * 32 + kq) * 2));
            #pragma unroll
            for (int ct = 0; ct < 8; ++ct) {
                f16x8 bf = *(const f16x8*)(Wt + (size_t)(ct * 16 + (lane & 15)) * D + ks * 32 + kq);
                acc0[ct] = __builtin_amdgcn_mfma_f32_16x16x32_f16(af0, bf, acc0[ct], 0, 0, 0);
                acc1[ct] = __builtin_amdgcn_mfma_f32_16x16x32_f16(af1, bf, acc1[ct], 0, 0, 0);
            }
        }

        const int col_lo = lane & 15;
        const int rb0 = row0 + (w << 5) + ((lane >> 4) << 2);
        const int rb1 = rb0 + 16;
        #pragma unroll
        for (int ct = 0; ct < 8; ++ct) {
            int col = ct * 16 + col_lo;
            float bv = bias[s * D + col];
            float s_ = 0.f, q_ = 0.f;
            #pragma unroll
            for (int r = 0; r < 4; ++r) {
                int row = rb0 + r;
                float val = acc0[ct][r] + bv;
                if (row < N) {
                    *(f16*)(slab + (size_t)row * 256 + col * 2) = (f16)val;
                    s_ += val; q_ += val * val;
                }
            }
            #pragma unroll
            for (int r = 0; r < 4; ++r) {
                int row = rb1 + r;
                float val = acc1[ct][r] + bv;
                if (row < N) {
                    *(f16*)(slab + (size_t)row * 256 + col * 2) = (f16)val;
                    s_ += val; q_ += val * val;
                }
            }
            s_ += __shfl_xor(s_, 16); q_ += __shfl_xor(q_, 16);
            s_ += __shfl_xor(s_, 32); q_ += __shfl_xor(q_, 32);
            if (lane < 16) { wst[w][col] = s_; wst[w][128 + col] = q_; }
        }
        __syncthreads();
        float p = wst[0][tid] + wst[1][tid] + wst[2][tid] + wst[3][tid];
        partials[((size_t)blockIdx.x * 3 + s) * 256 + tid] = p;
    }
}

// ----------------------------------------------------------- stats reduction
__global__ void bn_reduce3(const float* __restrict__ partials,
                           float* __restrict__ partial2, int nblk) {
    int s = blockIdx.y, tid = threadIdx.x;
    float v = 0.f;
    for (int b = blockIdx.x; b < nblk; b += NRED)
        v += partials[((size_t)b * 3 + s) * 256 + tid];
    partial2[((size_t)s * NRED + blockIdx.x) * 256 + tid] = v;
}

__global__ void bn_params3(const float* __restrict__ partial2,
                           const float* __restrict__ g, const float* __restrict__ be,
                           float* __restrict__ affa, float* __restrict__ affc, int N) {
    int s = blockIdx.x, c = threadIdx.x;  // 128 threads
    float sm = 0.f, q = 0.f;
    #pragma unroll
    for (int b = 0; b < NRED; ++b) {
        sm += partial2[((size_t)s * NRED + b) * 256 + c];
        q  += partial2[((size_t)s * NRED + b) * 256 + 128 + c];
    }
    float n = (float)N;
    float mean = sm / n;
    float var  = q / n - mean * mean;
    float a = g[s * D + c] * rsqrtf(var + 1e-5f);
    affa[s * 128 + c] = a;
    affc[s * 128 + c] = be[s * D + c] - mean * a;
}

// ----------------------------------------------------- final accum (3 s sum)
__global__ __launch_bounds__(256) void accum3(const char* __restrict__ slabs, size_t slabN,
                                              const float* __restrict__ affa,
                                              const float* __restrict__ affc,
                                              float* __restrict__ outp, int N) {
    int total = N * 16;
    for (int i = blockIdx.x * 256 + threadIdx.x; i < total; i += gridDim.x * 256) {
        int row = i >> 4;
        int c8  = i & 15;
        f32x4 o0 = {0.f, 0.f, 0.f, 0.f}, o1 = {0.f, 0.f, 0.f, 0.f};
        #pragma unroll
        for (int s = 0; s < 3; ++s) {
            f16x8 z = ((const f16x8*)(slabs + (size_t)s * slabN + (size_t)row * 256))[c8];
            f32x4 a0 = ((const f32x4*)(affa + s * 128))[c8 * 2];
            f32x4 a1 = ((const f32x4*)(affa + s * 128))[c8 * 2 + 1];
            f32x4 c0 = ((const f32x4*)(affc + s * 128))[c8 * 2];
            f32x4 c1 = ((const f32x4*)(affc + s * 128))[c8 * 2 + 1];
            #pragma unroll
            for (int j = 0; j < 4; ++j) {
                float t0 = (float)z[j] * a0[j] + c0[j];
                float t1 = (float)z[4 + j] * a1[j] + c1[j];
                o0[j] += t0 > 0.f ? t0 : 0.f;
                o1[j] += t1 > 0.f ? t1 : 0.f;
            }
        }
        ((f32x4*)(outp + (size_t)row * D))[c8 * 2]     = o0;
        ((f32x4*)(outp + (size_t)row * D))[c8 * 2 + 1] = o1;
    }
}

extern "C" void kernel_launch(void* const* d_in, const int* in_sizes, int n_in,
                              void* d_out, int out_size, void* d_ws, size_t ws_size,
                              hipStream_t stream) {
    const float* x0  = (const float*)d_in[0];
    const float* x1  = (const float*)d_in[1];
    const float* x2  = (const float*)d_in[2];
    const int*   ei  = (const int*)d_in[3];
    const float* W1  = (const float*)d_in[4];
    const float* b1  = (const float*)d_in[5];
    const float* g1  = (const float*)d_in[6];
    const float* be1 = (const float*)d_in[7];
    const float* W2  = (const float*)d_in[8];
    const float* b2  = (const float*)d_in[9];
    const float* g2  = (const float*)d_in[10];
    const float* be2 = (const float*)d_in[11];
    const float* eps9 = (const float*)d_in[12];
    float* outp = (float*)d_out;

    const int NC[3] = {200000, 3000, 20000};
    const size_t OUT_OFF[3] = {0, (size_t)200000 * D, (size_t)203000 * D};

    char* ws = (char*)d_ws;
    size_t off = 0;
    char* slabs = ws;                 off += (size_t)3 * 200000 * 256;     // 153.6 MB
    f16* x16    = (f16*)(ws + off);   off += (size_t)223000 * 256;         // 57.1 MB
    int* ssrc   = (int*)(ws + off);   off += (size_t)9 * E_PER * 4;        // 18 MB
    int* rowstart = (int*)(ws + off); off += (size_t)(TOT_ROWS + 2) * 4;
    off = (off + 255) & ~(size_t)255;
    int* cursor = (int*)(ws + off);   off += (size_t)TOT_ROWS * 4;
    off = (off + 255) & ~(size_t)255;
    int* deg    = (int*)(ws + off);   off += (size_t)TOT_ROWS * 4;
    off = (off + 255) & ~(size_t)255;
    int* bsum   = (int*)(ws + off);   off += 1024;
    float* partials = (float*)(ws + off); off += (size_t)1563 * 3 * 256 * 4;
    float* partial2 = (float*)(ws + off); off += (size_t)3 * NRED * 256 * 4;
    float* aff1a = (float*)(ws + off); off += 1536;
    float* aff1c = (float*)(ws + off); off += 1536;
    float* aff2a = (float*)(ws + off); off += 1536;
    float* aff2c = (float*)(ws + off); off += 1536;
    f16* Wth = (f16*)(ws + off); off += (size_t)2 * 3 * 128 * 128 * sizeof(f16);

    // ---- setup
    precast<<<384, 256, 0, stream>>>(W1, W2, Wth);
    cast16_all<<<2048, 256, 0, stream>>>(x0, x1, x2, x16);

    // ---- batched CSR over all 9 edge types
    hipMemsetAsync(deg, 0, (size_t)TOT_ROWS * 4, stream);
    int eblk = (E_PER + 255) / 256;
    deg_count_all<<<dim3(eblk, 9), 256, 0, stream>>>(ei, deg);
    int C  = (TOT_ROWS + 255) / 256;   // 2614
    int c2 = (C + 255) / 256;          // 11
    scan1<<<256, 256, 0, stream>>>(deg, bsum, TOT_ROWS, C);
    scan2<<<1, 256, 0, stream>>>(bsum);
    scan3<<<256, 256, 0, stream>>>(deg, bsum, rowstart, cursor, TOT_ROWS, C, c2);
    fill_all<<<dim3(eblk, 9), 256, 0, stream>>>(ei, cursor, ssrc);

    // ---- per target type
    for (int t = 0; t < 3; ++t) {
        int N = NC[t];
        size_t slabN = (size_t)N * 256;
        int gtiles = (N + 127) / 128;

        if (t == 1) {
            aggregate_b<<<dim3(N, 3), 256, 0, stream>>>(x16, rowstart, ssrc, slabs, slabN,
                                                        eps9, t, N, 1);
        } else {
            aggregate_b<<<dim3((N + 3) / 4, 3), 256, 0, stream>>>(x16, rowstart, ssrc, slabs, slabN,
                                                                  eps9, t, N, 0);
        }

        gemm3<<<gtiles, 256, 0, stream>>>(slabs, slabN, Wth, b1,
                                          nullptr, nullptr, partials, N);
        bn_reduce3<<<dim3(NRED, 3), 256, 0, stream>>>(partials, partial2, gtiles);
        bn_params3<<<3, 128, 0, stream>>>(partial2, g1, be1, aff1a, aff1c, N);

        gemm3<<<gtiles, 256, 0, stream>>>(slabs, slabN, Wth + 3 * 16384, b2,
                                          aff1a, aff1c, partials, N);
        bn_reduce3<<<dim3(NRED, 3), 256, 0, stream>>>(partials, partial2, gtiles);
        bn_params3<<<3, 128, 0, stream>>>(partial2, g2, be2, aff2a, aff2c, N);

        int nblk = (N * 16 + 255) / 256;
        if (nblk > 2048) nblk = 2048;
        accum3<<<nblk, 256, 0, stream>>>(slabs, slabN, aff2a, aff2c, outp + OUT_OFF[t], N);
    }
}

// Round 6
// 1238.591 us; speedup vs baseline: 5.7001x; 1.3229x over previous
//
#include <hip/hip_runtime.h>
#include <hip/hip_fp16.h>

#define D 128
#define E_PER 500000
#define NRED 32
#define TOT_ROWS 669000
#define CH 4096

typedef _Float16 f16;
typedef _Float16 f16x8 __attribute__((ext_vector_type(8)));
typedef _Float16 f16x4 __attribute__((ext_vector_type(4)));
typedef _Float16 f16x2 __attribute__((ext_vector_type(2)));
typedef float f32x4 __attribute__((ext_vector_type(4)));

// Per-edge-type row-segment bases in the concatenated CSR arrays (k = s*3 + t).
__device__ const int d_SEGB[9] = {0, 200000, 203000, 223000, 423000, 426000,
                                  446000, 646000, 649000};
// Row base of each node type inside the concatenated f16 feature table.
__device__ const int d_XB[3] = {0, 200000, 203000};
__device__ const int d_NC[3] = {200000, 3000, 20000};

// XOR swizzle for the A tile in LDS (row stride 256B f16).
__device__ __forceinline__ unsigned a_swz(int row, int byteoff) {
    return (unsigned)(row * 256 + byteoff) ^ (unsigned)((row & 7) << 4);
}

// ---------------------------------------------------------------- precast W^T
__global__ void precast(const float* __restrict__ W1,
                        const float* __restrict__ W2,
                        f16* __restrict__ Wth) {
    int i = blockIdx.x * 256 + threadIdx.x;
    if (i >= 2 * 3 * 128 * 128) return;
    int layer = i / 49152;
    int rem = i - layer * 49152;
    int s = rem / 16384;
    int r2 = rem & 16383;
    int kk = r2 >> 7;
    int c  = r2 & 127;
    const float* W = layer ? W2 : W1;
    Wth[(((size_t)layer * 3 + s) * 128 + c) * 128 + kk] = (f16)W[((size_t)s * 128 + kk) * 128 + c];
}

// ------------------------------------------------------- all x -> f16 table
__global__ void cast16_all(const float* __restrict__ x0,
                           const float* __restrict__ x1,
                           const float* __restrict__ x2,
                           f16* __restrict__ y) {
    const int total = 223000 * 16;
    for (int i = blockIdx.x * 256 + threadIdx.x; i < total; i += gridDim.x * 256) {
        int row = i >> 4, c8 = i & 15;
        const float* src;
        if (row < 200000)      src = x0 + (size_t)row * D;
        else if (row < 203000) src = x1 + (size_t)(row - 200000) * D;
        else                   src = x2 + (size_t)(row - 203000) * D;
        f32x4 v0 = ((const f32x4*)src)[c8 * 2];
        f32x4 v1 = ((const f32x4*)src)[c8 * 2 + 1];
        f16x8 h;
        #pragma unroll
        for (int j = 0; j < 4; ++j) { h[j] = (f16)v0[j]; h[4 + j] = (f16)v1[j]; }
        ((f16x8*)(y + (size_t)row * D))[c8] = h;
    }
}

// ============================================================ CSR via 2-pass
// bucket of dst: b = dst*256/Nt (monotonic). Rows of bucket b:
// [ceil(b*Nt/256), ceil((b+1)*Nt/256)).

__global__ __launch_bounds__(256) void bucket_count(const int* __restrict__ ei,
                                                    int* __restrict__ bcnt) {
    __shared__ int hist[256];
    int k = blockIdx.y, tid = threadIdx.x;
    const int* dstp = ei + (size_t)k * 2 * E_PER + E_PER;
    unsigned Nt = (unsigned)d_NC[k % 3];
    int base = blockIdx.x * CH;
    int hi = min(base + CH, E_PER);
    hist[tid] = 0;
    __syncthreads();
    for (int i = base + tid; i < hi; i += 256) {
        unsigned b = ((unsigned)dstp[i] << 8) / Nt;
        atomicAdd(&hist[b], 1);
    }
    __syncthreads();
    if (hist[tid]) atomicAdd(&bcnt[k * 256 + tid], hist[tid]);
}

__global__ void bucket_scan(const int* __restrict__ bcnt,
                            int* __restrict__ bbase, int* __restrict__ bcursor) {
    __shared__ int sb[256];
    int t = threadIdx.x;
    int loc[9];
    int s = 0;
    #pragma unroll
    for (int j = 0; j < 9; ++j) { loc[j] = bcnt[t * 9 + j]; s += loc[j]; }
    sb[t] = s; __syncthreads();
    int v = s;
    for (int off = 1; off < 256; off <<= 1) {
        int u = (t >= off) ? sb[t - off] : 0;
        __syncthreads();
        sb[t] += u;
        __syncthreads();
    }
    int pre = sb[t] - v;
    #pragma unroll
    for (int j = 0; j < 9; ++j) {
        bbase[t * 9 + j] = pre;
        bcursor[t * 9 + j] = pre;
        pre += loc[j];
    }
    if (t == 255) bbase[2304] = pre;
}

__global__ __launch_bounds__(256) void bin_scatter(const int* __restrict__ ei,
                                                   int* __restrict__ bcursor,
                                                   int2* __restrict__ binned) {
    __shared__ int hist[256], gb[256], cur[256];
    int k = blockIdx.y, tid = threadIdx.x;
    const int* srcp = ei + (size_t)k * 2 * E_PER;
    const int* dstp = srcp + E_PER;
    unsigned Nt = (unsigned)d_NC[k % 3];
    int base = blockIdx.x * CH;
    int hi = min(base + CH, E_PER);
    hist[tid] = 0;
    __syncthreads();
    for (int i = base + tid; i < hi; i += 256) {
        unsigned b = ((unsigned)dstp[i] << 8) / Nt;
        atomicAdd(&hist[b], 1);
    }
    __syncthreads();
    gb[tid] = hist[tid] ? atomicAdd(&bcursor[k * 256 + tid], hist[tid]) : 0;
    cur[tid] = 0;
    __syncthreads();
    for (int i = base + tid; i < hi; i += 256) {
        int src = srcp[i], dst = dstp[i];
        unsigned b = ((unsigned)dst << 8) / Nt;
        int r = atomicAdd(&cur[b], 1);
        binned[(size_t)gb[b] + r] = make_int2(src, dst);
    }
}

// One block per (bucket, k): per-row counts + scan in LDS, write rowstart,
// fill ssrc within the bucket's ~8KB region (cache-resident -> no write amp).
__global__ __launch_bounds__(256) void fine_fill(const int2* __restrict__ binned,
                                                 const int* __restrict__ bbase,
                                                 int* __restrict__ rowstart,
                                                 int* __restrict__ ssrc) {
    __shared__ int rcnt[784];
    __shared__ int excl[784];
    __shared__ int scur[784];
    __shared__ int sb[256];
    int k = blockIdx.y, b = blockIdx.x, tid = threadIdx.x;
    int Nt = d_NC[k % 3];
    int segb = d_SEGB[k];
    int row_lo = (b * Nt + 255) >> 8;
    int row_hi = ((b + 1) * Nt + 255) >> 8;
    int nrows = row_hi - row_lo;
    int ebase = bbase[k * 256 + b];
    int eend  = bbase[k * 256 + b + 1];
    for (int i = tid; i < nrows; i += 256) rcnt[i] = 0;
    __syncthreads();
    for (int e = ebase + tid; e < eend; e += 256)
        atomicAdd(&rcnt[binned[e].y - row_lo], 1);
    __syncthreads();
    int stride = (nrows + 255) >> 8;
    int lo = tid * stride;
    int hi2 = min(lo + stride, nrows);
    int s = 0;
    for (int i = lo; i < hi2; ++i) s += rcnt[i];
    sb[tid] = s; __syncthreads();
    int v = s;
    for (int off = 1; off < 256; off <<= 1) {
        int u = (tid >= off) ? sb[tid - off] : 0;
        __syncthreads();
        sb[tid] += u;
        __syncthreads();
    }
    int pre = sb[tid] - v;
    for (int i = lo; i < hi2; ++i) {
        excl[i] = pre;
        scur[i] = pre;
        pre += rcnt[i];
    }
    __syncthreads();
    for (int i = tid; i < nrows; i += 256)
        rowstart[segb + row_lo + i] = ebase + excl[i];
    if (k == 8 && b == 255 && tid == 0) rowstart[TOT_ROWS] = eend;
    for (int e = ebase + tid; e < eend; e += 256) {
        int2 ed = binned[e];
        int r = atomicAdd(&scur[ed.y - row_lo], 1);
        ssrc[ebase + r] = ed.x;
    }
}

// ---------------------------------------------------------------- aggregate
// blockIdx.y = s. slab_s[row] = (1+eps_k)*x_t[row] + sum_{e in row} x_s[src[e]],
// stored f16 (256 B/row). wpr4=1: 4 waves/row (high degree); else wave/row.
__global__ __launch_bounds__(256) void aggregate_b(const f16* __restrict__ x16,
                                                   const int* __restrict__ rowstart,
                                                   const int* __restrict__ ssrc,
                                                   char* __restrict__ slabs, size_t slabN,
                                                   const float* __restrict__ eps9,
                                                   int t, int N, int wpr4) {
    __shared__ float part[4][130];
    int s = blockIdx.y;
    int k = s * 3 + t;
    const int* rs = rowstart + d_SEGB[k];
    const f16* xsrc = x16 + (size_t)d_XB[s] * D;
    const f16* xt   = x16 + (size_t)d_XB[t] * D;
    char* slab = slabs + (size_t)s * slabN;
    float epsv = 1.0f + eps9[k];
    int lane = threadIdx.x & 63;
    int w    = threadIdx.x >> 6;
    int row, sub, wpr;
    if (wpr4) { row = blockIdx.x; sub = w; wpr = 4; }
    else      { row = (blockIdx.x << 2) + w; sub = 0; wpr = 1; }
    float r0 = 0.f, r1 = 0.f;
    if (row < N) {
        if (sub == 0) {
            f16x2 xv = *(const f16x2*)(xt + (size_t)row * D + lane * 2);
            r0 = epsv * (float)xv[0];
            r1 = epsv * (float)xv[1];
        }
        int e1 = rs[row + 1];
        int e  = rs[row] + sub;
        float a0=0,a1=0,b0=0,b1=0,c0=0,c1=0,d0=0,d1=0;
        for (; e + 3 * wpr < e1; e += 4 * wpr) {
            int s0 = ssrc[e], s1 = ssrc[e + wpr], s2 = ssrc[e + 2 * wpr], s3 = ssrc[e + 3 * wpr];
            f16x2 v0 = *(const f16x2*)(xsrc + (size_t)s0 * D + lane * 2);
            f16x2 v1 = *(const f16x2*)(xsrc + (size_t)s1 * D + lane * 2);
            f16x2 v2 = *(const f16x2*)(xsrc + (size_t)s2 * D + lane * 2);
            f16x2 v3 = *(const f16x2*)(xsrc + (size_t)s3 * D + lane * 2);
            a0 += (float)v0[0]; a1 += (float)v0[1];
            b0 += (float)v1[0]; b1 += (float)v1[1];
            c0 += (float)v2[0]; c1 += (float)v2[1];
            d0 += (float)v3[0]; d1 += (float)v3[1];
        }
        if (e + wpr < e1) {
            int s0 = ssrc[e], s1 = ssrc[e + wpr];
            f16x2 v0 = *(const f16x2*)(xsrc + (size_t)s0 * D + lane * 2);
            f16x2 v1 = *(const f16x2*)(xsrc + (size_t)s1 * D + lane * 2);
            a0 += (float)v0[0]; a1 += (float)v0[1];
            b0 += (float)v1[0]; b1 += (float)v1[1];
            e += 2 * wpr;
        }
        if (e < e1) {
            int s0 = ssrc[e];
            f16x2 v0 = *(const f16x2*)(xsrc + (size_t)s0 * D + lane * 2);
            a0 += (float)v0[0]; a1 += (float)v0[1];
        }
        r0 += (a0 + b0) + (c0 + d0);
        r1 += (a1 + b1) + (c1 + d1);
    }
    if (wpr4) {
        part[w][lane * 2] = r0; part[w][lane * 2 + 1] = r1;
        __syncthreads();
        if (w == 0 && row < N) {
            float s0 = part[0][lane*2] + part[1][lane*2] + part[2][lane*2] + part[3][lane*2];
            float s1 = part[0][lane*2+1] + part[1][lane*2+1] + part[2][lane*2+1] + part[3][lane*2+1];
            f16x2 h; h[0] = (f16)s0; h[1] = (f16)s1;
            *(f16x2*)(slab + (size_t)row * 256 + lane * 4) = h;
        }
    } else if (row < N) {
        f16x2 h; h[0] = (f16)r0; h[1] = (f16)r1;
        *(f16x2*)(slab + (size_t)row * 256 + lane * 4) = h;
    }
}

// ---------------------------------------------------- GEMM (both layers), 3 s fused
__global__ __launch_bounds__(256) void gemm3(char* __restrict__ slabs, size_t slabN,
                                             const f16* __restrict__ Wth,
                                             const float* __restrict__ bias,
                                             const float* __restrict__ affa,
                                             const float* __restrict__ affc,
                                             float* __restrict__ partials, int N) {
    __shared__ alignas(16) char atile[128 * 256];
    __shared__ float wst[4][256];
    __shared__ alignas(16) float afa[384];
    __shared__ alignas(16) float afc[384];
    const int tid  = threadIdx.x;
    const int lane = tid & 63;
    const int w    = tid >> 6;
    const int row0 = blockIdx.x * 128;

    if (affa) {
        for (int i = tid; i < 384; i += 256) { afa[i] = affa[i]; afc[i] = affc[i]; }
    }
    __syncthreads();

    for (int s = 0; s < 3; ++s) {
        char* slab = slabs + (size_t)s * slabN;
        #pragma unroll
        for (int p = 0; p < 8; ++p) {
            int rp = p * 16 + (tid >> 4);
            int c8 = tid & 15;
            int row = row0 + rp;
            f16x8 hv = {0, 0, 0, 0, 0, 0, 0, 0};
            if (row < N) {
                hv = ((const f16x8*)(slab + (size_t)row * 256))[c8];
                if (affa) {
                    f32x4 a0 = *(const f32x4*)(afa + s * 128 + c8 * 8);
                    f32x4 a1 = *(const f32x4*)(afa + s * 128 + c8 * 8 + 4);
                    f32x4 c0 = *(const f32x4*)(afc + s * 128 + c8 * 8);
                    f32x4 c1 = *(const f32x4*)(afc + s * 128 + c8 * 8 + 4);
                    #pragma unroll
                    for (int j = 0; j < 4; ++j) {
                        float t0 = (float)hv[j] * a0[j] + c0[j];
                        float t1 = (float)hv[4 + j] * a1[j] + c1[j];
                        hv[j]     = (f16)(t0 > 0.f ? t0 : 0.f);
                        hv[4 + j] = (f16)(t1 > 0.f ? t1 : 0.f);
                    }
                }
            }
            *(f16x8*)(atile + a_swz(rp, c8 * 16)) = hv;
        }
        __syncthreads();

        const f16* Wt = Wth + (size_t)s * 16384;
        f32x4 acc0[8], acc1[8];
        #pragma unroll
        for (int ct = 0; ct < 8; ++ct) {
            acc0[ct] = (f32x4){0.f, 0.f, 0.f, 0.f};
            acc1[ct] = (f32x4){0.f, 0.f, 0.f, 0.f};
        }
        const int arow0 = (w << 5) + (lane & 15);
        const int arow1 = arow0 + 16;
        const int kq = (lane >> 4) * 8;
        #pragma unroll
        for (int ks = 0; ks < 4; ++ks) {
            f16x8 af0 = *(const f16x8*)(atile + a_swz(arow0, (ks * 32 + kq) * 2));
            f16x8 af1 = *(const f16x8*)(atile + a_swz(arow1, (ks * 32 + kq) * 2));
            #pragma unroll
            for (int ct = 0; ct < 8; ++ct) {
                f16x8 bf = *(const f16x8*)(Wt + (size_t)(ct * 16 + (lane & 15)) * D + ks * 32 + kq);
                acc0[ct] = __builtin_amdgcn_mfma_f32_16x16x32_f16(af0, bf, acc0[ct], 0, 0, 0);
                acc1[ct] = __builtin_amdgcn_mfma_f32_16x16x32_f16(af1, bf, acc1[ct], 0, 0, 0);
            }
        }

        const int col_lo = lane & 15;
        const int rb0 = row0 + (w << 5) + ((lane >> 4) << 2);
        const int rb1 = rb0 + 16;
        #pragma unroll
        for (int ct = 0; ct < 8; ++ct) {
            int col = ct * 16 + col_lo;
            float bv = bias[s * D + col];
            float s_ = 0.f, q_ = 0.f;
            #pragma unroll
            for (int r = 0; r < 4; ++r) {
                int row = rb0 + r;
                float val = acc0[ct][r] + bv;
                if (row < N) {
                    *(f16*)(slab + (size_t)row * 256 + col * 2) = (f16)val;
                    s_ += val; q_ += val * val;
                }
            }
            #pragma unroll
            for (int r = 0; r < 4; ++r) {
                int row = rb1 + r;
                float val = acc1[ct][r] + bv;
                if (row < N) {
                    *(f16*)(slab + (size_t)row * 256 + col * 2) = (f16)val;
                    s_ += val; q_ += val * val;
                }
            }
            s_ += __shfl_xor(s_, 16); q_ += __shfl_xor(q_, 16);
            s_ += __shfl_xor(s_, 32); q_ += __shfl_xor(q_, 32);
            if (lane < 16) { wst[w][col] = s_; wst[w][128 + col] = q_; }
        }
        __syncthreads();
        float p = wst[0][tid] + wst[1][tid] + wst[2][tid] + wst[3][tid];
        partials[((size_t)blockIdx.x * 3 + s) * 256 + tid] = p;
    }
}

// ----------------------------------------------------------- stats reduction
__global__ void bn_reduce3(const float* __restrict__ partials,
                           float* __restrict__ partial2, int nblk) {
    int s = blockIdx.y, tid = threadIdx.x;
    float v = 0.f;
    for (int b = blockIdx.x; b < nblk; b += NRED)
        v += partials[((size_t)b * 3 + s) * 256 + tid];
    partial2[((size_t)s * NRED + blockIdx.x) * 256 + tid] = v;
}

__global__ void bn_params3(const float* __restrict__ partial2,
                           const float* __restrict__ g, const float* __restrict__ be,
                           float* __restrict__ affa, float* __restrict__ affc, int N) {
    int s = blockIdx.x, c = threadIdx.x;  // 128 threads
    float sm = 0.f, q = 0.f;
    #pragma unroll
    for (int b = 0; b < NRED; ++b) {
        sm += partial2[((size_t)s * NRED + b) * 256 + c];
        q  += partial2[((size_t)s * NRED + b) * 256 + 128 + c];
    }
    float n = (float)N;
    float mean = sm / n;
    float var  = q / n - mean * mean;
    float a = g[s * D + c] * rsqrtf(var + 1e-5f);
    affa[s * 128 + c] = a;
    affc[s * 128 + c] = be[s * D + c] - mean * a;
}

// ----------------------------------------------------- final accum (3 s sum)
__global__ __launch_bounds__(256) void accum3(const char* __restrict__ slabs, size_t slabN,
                                              const float* __restrict__ affa,
                                              const float* __restrict__ affc,
                                              float* __restrict__ outp, int N) {
    int total = N * 16;
    for (int i = blockIdx.x * 256 + threadIdx.x; i < total; i += gridDim.x * 256) {
        int row = i >> 4;
        int c8  = i & 15;
        f32x4 o0 = {0.f, 0.f, 0.f, 0.f}, o1 = {0.f, 0.f, 0.f, 0.f};
        #pragma unroll
        for (int s = 0; s < 3; ++s) {
            f16x8 z = ((const f16x8*)(slabs + (size_t)s * slabN + (size_t)row * 256))[c8];
            f32x4 a0 = ((const f32x4*)(affa + s * 128))[c8 * 2];
            f32x4 a1 = ((const f32x4*)(affa + s * 128))[c8 * 2 + 1];
            f32x4 c0 = ((const f32x4*)(affc + s * 128))[c8 * 2];
            f32x4 c1 = ((const f32x4*)(affc + s * 128))[c8 * 2 + 1];
            #pragma unroll
            for (int j = 0; j < 4; ++j) {
                float t0 = (float)z[j] * a0[j] + c0[j];
                float t1 = (float)z[4 + j] * a1[j] + c1[j];
                o0[j] += t0 > 0.f ? t0 : 0.f;
                o1[j] += t1 > 0.f ? t1 : 0.f;
            }
        }
        ((f32x4*)(outp + (size_t)row * D))[c8 * 2]     = o0;
        ((f32x4*)(outp + (size_t)row * D))[c8 * 2 + 1] = o1;
    }
}

extern "C" void kernel_launch(void* const* d_in, const int* in_sizes, int n_in,
                              void* d_out, int out_size, void* d_ws, size_t ws_size,
                              hipStream_t stream) {
    const float* x0  = (const float*)d_in[0];
    const float* x1  = (const float*)d_in[1];
    const float* x2  = (const float*)d_in[2];
    const int*   ei  = (const int*)d_in[3];
    const float* W1  = (const float*)d_in[4];
    const float* b1  = (const float*)d_in[5];
    const float* g1  = (const float*)d_in[6];
    const float* be1 = (const float*)d_in[7];
    const float* W2  = (const float*)d_in[8];
    const float* b2  = (const float*)d_in[9];
    const float* g2  = (const float*)d_in[10];
    const float* be2 = (const float*)d_in[11];
    const float* eps9 = (const float*)d_in[12];
    float* outp = (float*)d_out;

    const int NC[3] = {200000, 3000, 20000};
    const size_t OUT_OFF[3] = {0, (size_t)200000 * D, (size_t)203000 * D};

    char* ws = (char*)d_ws;
    size_t off = 0;
    char* slabs = ws;                 off += (size_t)3 * 200000 * 256;     // 153.6 MB
    int2* binned = (int2*)slabs;      // 36 MB alias, consumed before slabs written
    f16* x16    = (f16*)(ws + off);   off += (size_t)223000 * 256;         // 57.1 MB
    int* ssrc   = (int*)(ws + off);   off += (size_t)9 * E_PER * 4;        // 18 MB
    int* rowstart = (int*)(ws + off); off += (size_t)(TOT_ROWS + 2) * 4;
    off = (off + 255) & ~(size_t)255;
    int* bcnt   = (int*)(ws + off);   off += 2308 * 4;
    int* bbase  = (int*)(ws + off);   off += 2308 * 4;
    int* bcursor= (int*)(ws + off);   off += 2308 * 4;
    off = (off + 255) & ~(size_t)255;
    float* partials = (float*)(ws + off); off += (size_t)1563 * 3 * 256 * 4;
    float* partial2 = (float*)(ws + off); off += (size_t)3 * NRED * 256 * 4;
    float* aff1a = (float*)(ws + off); off += 1536;
    float* aff1c = (float*)(ws + off); off += 1536;
    float* aff2a = (float*)(ws + off); off += 1536;
    float* aff2c = (float*)(ws + off); off += 1536;
    f16* Wth = (f16*)(ws + off); off += (size_t)2 * 3 * 128 * 128 * sizeof(f16);

    // ---- setup
    precast<<<384, 256, 0, stream>>>(W1, W2, Wth);
    cast16_all<<<2048, 256, 0, stream>>>(x0, x1, x2, x16);

    // ---- CSR build via LDS-binned counting sort (all 9 types)
    hipMemsetAsync(bcnt, 0, 2308 * 4, stream);
    int nchunk = (E_PER + CH - 1) / CH;   // 123
    bucket_count<<<dim3(nchunk, 9), 256, 0, stream>>>(ei, bcnt);
    bucket_scan<<<1, 256, 0, stream>>>(bcnt, bbase, bcursor);
    bin_scatter<<<dim3(nchunk, 9), 256, 0, stream>>>(ei, bcursor, binned);
    fine_fill<<<dim3(256, 9), 256, 0, stream>>>(binned, bbase, rowstart, ssrc);

    // ---- per target type
    for (int t = 0; t < 3; ++t) {
        int N = NC[t];
        size_t slabN = (size_t)N * 256;
        int gtiles = (N + 127) / 128;

        if (t == 1) {
            aggregate_b<<<dim3(N, 3), 256, 0, stream>>>(x16, rowstart, ssrc, slabs, slabN,
                                                        eps9, t, N, 1);
        } else {
            aggregate_b<<<dim3((N + 3) / 4, 3), 256, 0, stream>>>(x16, rowstart, ssrc, slabs, slabN,
                                                                  eps9, t, N, 0);
        }

        gemm3<<<gtiles, 256, 0, stream>>>(slabs, slabN, Wth, b1,
                                          nullptr, nullptr, partials, N);
        bn_reduce3<<<dim3(NRED, 3), 256, 0, stream>>>(partials, partial2, gtiles);
        bn_params3<<<3, 128, 0, stream>>>(partial2, g1, be1, aff1a, aff1c, N);

        gemm3<<<gtiles, 256, 0, stream>>>(slabs, slabN, Wth + 3 * 16384, b2,
                                          aff1a, aff1c, partials, N);
        bn_reduce3<<<dim3(NRED, 3), 256, 0, stream>>>(partials, partial2, gtiles);
        bn_params3<<<3, 128, 0, stream>>>(partial2, g2, be2, aff2a, aff2c, N);

        int nblk = (N * 16 + 255) / 256;
        if (nblk > 2048) nblk = 2048;
        accum3<<<nblk, 256, 0, stream>>>(slabs, slabN, aff2a, aff2c, outp + OUT_OFF[t], N);
    }
}

// Round 7
// 1193.409 us; speedup vs baseline: 5.9159x; 1.0379x over previous
//
#include <hip/hip_runtime.h>
#include <hip/hip_fp16.h>

#define D 128
#define E_PER 500000
#define TOT_ROWS 669000
#define CH 4096

typedef _Float16 f16;
typedef _Float16 f16x8 __attribute__((ext_vector_type(8)));
typedef _Float16 f16x4 __attribute__((ext_vector_type(4)));
typedef _Float16 f16x2 __attribute__((ext_vector_type(2)));
typedef float f32x4 __attribute__((ext_vector_type(4)));

// Per-edge-type row-segment bases in the concatenated CSR arrays (k = s*3 + t).
__device__ const int d_SEGB[9] = {0, 200000, 203000, 223000, 423000, 426000,
                                  446000, 646000, 649000};
// Row base of each node type inside the concatenated f16 feature table.
__device__ const int d_XB[3] = {0, 200000, 203000};
__device__ const int d_NC[3] = {200000, 3000, 20000};

// XOR swizzle for the A tile in LDS (row stride 256B f16).
__device__ __forceinline__ unsigned a_swz(int row, int byteoff) {
    return (unsigned)(row * 256 + byteoff) ^ (unsigned)((row & 7) << 4);
}

// ---------------------------------------------------------------- precast W^T
__global__ void precast(const float* __restrict__ W1,
                        const float* __restrict__ W2,
                        f16* __restrict__ Wth) {
    int i = blockIdx.x * 256 + threadIdx.x;
    if (i >= 2 * 3 * 128 * 128) return;
    int layer = i / 49152;
    int rem = i - layer * 49152;
    int s = rem / 16384;
    int r2 = rem & 16383;
    int kk = r2 >> 7;
    int c  = r2 & 127;
    const float* W = layer ? W2 : W1;
    Wth[(((size_t)layer * 3 + s) * 128 + c) * 128 + kk] = (f16)W[((size_t)s * 128 + kk) * 128 + c];
}

// ------------------------------------------------------- all x -> f16 table
__global__ void cast16_all(const float* __restrict__ x0,
                           const float* __restrict__ x1,
                           const float* __restrict__ x2,
                           f16* __restrict__ y) {
    const int total = 223000 * 16;
    for (int i = blockIdx.x * 256 + threadIdx.x; i < total; i += gridDim.x * 256) {
        int row = i >> 4, c8 = i & 15;
        const float* src;
        if (row < 200000)      src = x0 + (size_t)row * D;
        else if (row < 203000) src = x1 + (size_t)(row - 200000) * D;
        else                   src = x2 + (size_t)(row - 203000) * D;
        f32x4 v0 = ((const f32x4*)src)[c8 * 2];
        f32x4 v1 = ((const f32x4*)src)[c8 * 2 + 1];
        f16x8 h;
        #pragma unroll
        for (int j = 0; j < 4; ++j) { h[j] = (f16)v0[j]; h[4 + j] = (f16)v1[j]; }
        ((f16x8*)(y + (size_t)row * D))[c8] = h;
    }
}

// ============================================================ CSR via 2-pass
__global__ __launch_bounds__(256) void bucket_count(const int* __restrict__ ei,
                                                    int* __restrict__ bcnt) {
    __shared__ int hist[256];
    int k = blockIdx.y, tid = threadIdx.x;
    const int* dstp = ei + (size_t)k * 2 * E_PER + E_PER;
    unsigned Nt = (unsigned)d_NC[k % 3];
    int base = blockIdx.x * CH;
    int hi = min(base + CH, E_PER);
    hist[tid] = 0;
    __syncthreads();
    for (int i = base + tid; i < hi; i += 256) {
        unsigned b = ((unsigned)dstp[i] << 8) / Nt;
        atomicAdd(&hist[b], 1);
    }
    __syncthreads();
    if (hist[tid]) atomicAdd(&bcnt[k * 256 + tid], hist[tid]);
}

__global__ void bucket_scan(const int* __restrict__ bcnt,
                            int* __restrict__ bbase, int* __restrict__ bcursor) {
    __shared__ int sb[256];
    int t = threadIdx.x;
    int loc[9];
    int s = 0;
    #pragma unroll
    for (int j = 0; j < 9; ++j) { loc[j] = bcnt[t * 9 + j]; s += loc[j]; }
    sb[t] = s; __syncthreads();
    int v = s;
    for (int off = 1; off < 256; off <<= 1) {
        int u = (t >= off) ? sb[t - off] : 0;
        __syncthreads();
        sb[t] += u;
        __syncthreads();
    }
    int pre = sb[t] - v;
    #pragma unroll
    for (int j = 0; j < 9; ++j) {
        bbase[t * 9 + j] = pre;
        bcursor[t * 9 + j] = pre;
        pre += loc[j];
    }
    if (t == 255) bbase[2304] = pre;
}

__global__ __launch_bounds__(256) void bin_scatter(const int* __restrict__ ei,
                                                   int* __restrict__ bcursor,
                                                   int2* __restrict__ binned) {
    __shared__ int hist[256], gb[256], cur[256];
    int k = blockIdx.y, tid = threadIdx.x;
    const int* srcp = ei + (size_t)k * 2 * E_PER;
    const int* dstp = srcp + E_PER;
    unsigned Nt = (unsigned)d_NC[k % 3];
    int base = blockIdx.x * CH;
    int hi = min(base + CH, E_PER);
    hist[tid] = 0;
    __syncthreads();
    for (int i = base + tid; i < hi; i += 256) {
        unsigned b = ((unsigned)dstp[i] << 8) / Nt;
        atomicAdd(&hist[b], 1);
    }
    __syncthreads();
    gb[tid] = hist[tid] ? atomicAdd(&bcursor[k * 256 + tid], hist[tid]) : 0;
    cur[tid] = 0;
    __syncthreads();
    for (int i = base + tid; i < hi; i += 256) {
        int src = srcp[i], dst = dstp[i];
        unsigned b = ((unsigned)dst << 8) / Nt;
        int r = atomicAdd(&cur[b], 1);
        binned[(size_t)gb[b] + r] = make_int2(src, dst);
    }
}

__global__ __launch_bounds__(256) void fine_fill(const int2* __restrict__ binned,
                                                 const int* __restrict__ bbase,
                                                 int* __restrict__ rowstart,
                                                 int* __restrict__ ssrc) {
    __shared__ int rcnt[784];
    __shared__ int excl[784];
    __shared__ int scur[784];
    __shared__ int sb[256];
    int k = blockIdx.y, b = blockIdx.x, tid = threadIdx.x;
    int Nt = d_NC[k % 3];
    int segb = d_SEGB[k];
    int row_lo = (b * Nt + 255) >> 8;
    int row_hi = ((b + 1) * Nt + 255) >> 8;
    int nrows = row_hi - row_lo;
    int ebase = bbase[k * 256 + b];
    int eend  = bbase[k * 256 + b + 1];
    for (int i = tid; i < nrows; i += 256) rcnt[i] = 0;
    __syncthreads();
    for (int e = ebase + tid; e < eend; e += 256)
        atomicAdd(&rcnt[binned[e].y - row_lo], 1);
    __syncthreads();
    int stride = (nrows + 255) >> 8;
    int lo = tid * stride;
    int hi2 = min(lo + stride, nrows);
    int s = 0;
    for (int i = lo; i < hi2; ++i) s += rcnt[i];
    sb[tid] = s; __syncthreads();
    int v = s;
    for (int off = 1; off < 256; off <<= 1) {
        int u = (tid >= off) ? sb[tid - off] : 0;
        __syncthreads();
        sb[tid] += u;
        __syncthreads();
    }
    int pre = sb[tid] - v;
    for (int i = lo; i < hi2; ++i) {
        excl[i] = pre;
        scur[i] = pre;
        pre += rcnt[i];
    }
    __syncthreads();
    for (int i = tid; i < nrows; i += 256)
        rowstart[segb + row_lo + i] = ebase + excl[i];
    if (k == 8 && b == 255 && tid == 0) rowstart[TOT_ROWS] = eend;
    for (int e = ebase + tid; e < eend; e += 256) {
        int2 ed = binned[e];
        int r = atomicAdd(&scur[ed.y - row_lo], 1);
        ssrc[ebase + r] = ed.x;
    }
}

// ---------------------------------------------------------------- aggregate
__global__ __launch_bounds__(256) void aggregate_b(const f16* __restrict__ x16,
                                                   const int* __restrict__ rowstart,
                                                   const int* __restrict__ ssrc,
                                                   char* __restrict__ slabs, size_t slabN,
                                                   const float* __restrict__ eps9,
                                                   int t, int N, int wpr4) {
    __shared__ float part[4][130];
    int s = blockIdx.y;
    int k = s * 3 + t;
    const int* rs = rowstart + d_SEGB[k];
    const f16* xsrc = x16 + (size_t)d_XB[s] * D;
    const f16* xt   = x16 + (size_t)d_XB[t] * D;
    char* slab = slabs + (size_t)s * slabN;
    float epsv = 1.0f + eps9[k];
    int lane = threadIdx.x & 63;
    int w    = threadIdx.x >> 6;
    int row, sub, wpr;
    if (wpr4) { row = blockIdx.x; sub = w; wpr = 4; }
    else      { row = (blockIdx.x << 2) + w; sub = 0; wpr = 1; }
    float r0 = 0.f, r1 = 0.f;
    if (row < N) {
        if (sub == 0) {
            f16x2 xv = *(const f16x2*)(xt + (size_t)row * D + lane * 2);
            r0 = epsv * (float)xv[0];
            r1 = epsv * (float)xv[1];
        }
        int e1 = rs[row + 1];
        int e  = rs[row] + sub;
        float a0=0,a1=0,b0=0,b1=0,c0=0,c1=0,d0=0,d1=0;
        for (; e + 3 * wpr < e1; e += 4 * wpr) {
            int s0 = ssrc[e], s1 = ssrc[e + wpr], s2 = ssrc[e + 2 * wpr], s3 = ssrc[e + 3 * wpr];
            f16x2 v0 = *(const f16x2*)(xsrc + (size_t)s0 * D + lane * 2);
            f16x2 v1 = *(const f16x2*)(xsrc + (size_t)s1 * D + lane * 2);
            f16x2 v2 = *(const f16x2*)(xsrc + (size_t)s2 * D + lane * 2);
            f16x2 v3 = *(const f16x2*)(xsrc + (size_t)s3 * D + lane * 2);
            a0 += (float)v0[0]; a1 += (float)v0[1];
            b0 += (float)v1[0]; b1 += (float)v1[1];
            c0 += (float)v2[0]; c1 += (float)v2[1];
            d0 += (float)v3[0]; d1 += (float)v3[1];
        }
        if (e + wpr < e1) {
            int s0 = ssrc[e], s1 = ssrc[e + wpr];
            f16x2 v0 = *(const f16x2*)(xsrc + (size_t)s0 * D + lane * 2);
            f16x2 v1 = *(const f16x2*)(xsrc + (size_t)s1 * D + lane * 2);
            a0 += (float)v0[0]; a1 += (float)v0[1];
            b0 += (float)v1[0]; b1 += (float)v1[1];
            e += 2 * wpr;
        }
        if (e < e1) {
            int s0 = ssrc[e];
            f16x2 v0 = *(const f16x2*)(xsrc + (size_t)s0 * D + lane * 2);
            a0 += (float)v0[0]; a1 += (float)v0[1];
        }
        r0 += (a0 + b0) + (c0 + d0);
        r1 += (a1 + b1) + (c1 + d1);
    }
    if (wpr4) {
        part[w][lane * 2] = r0; part[w][lane * 2 + 1] = r1;
        __syncthreads();
        if (w == 0 && row < N) {
            float s0 = part[0][lane*2] + part[1][lane*2] + part[2][lane*2] + part[3][lane*2];
            float s1 = part[0][lane*2+1] + part[1][lane*2+1] + part[2][lane*2+1] + part[3][lane*2+1];
            f16x2 h; h[0] = (f16)s0; h[1] = (f16)s1;
            *(f16x2*)(slab + (size_t)row * 256 + lane * 4) = h;
        }
    } else if (row < N) {
        f16x2 h; h[0] = (f16)r0; h[1] = (f16)r1;
        *(f16x2*)(slab + (size_t)row * 256 + lane * 4) = h;
    }
}

// -------------------------------------------------------------- layer-1 GEMM
// grid (tiles, s). Stage A = slab rows via global_load_lds with PRE-SWIZZLED
// source offsets (slab row stride == LDS row stride == 256B, so the XOR
// swizzle commutes to the source address; LDS dest stays linear).
__global__ __launch_bounds__(256) void gemm_l1(char* __restrict__ slabs, size_t slabN,
                                               const f16* __restrict__ Wth,
                                               const float* __restrict__ bias,
                                               float* __restrict__ partials, int N) {
    __shared__ alignas(16) char atile[128 * 256];
    __shared__ float wst[4][256];
    const int tid  = threadIdx.x;
    const int lane = tid & 63;
    const int w    = tid >> 6;
    const int s    = blockIdx.y;
    const int row0 = blockIdx.x * 128;
    char* slab = slabs + (size_t)s * slabN;

    #pragma unroll
    for (int p = 0; p < 8; ++p) {
        int r  = p * 16 + (tid >> 4);
        int c8 = tid & 15;
        int row = row0 + r;
        if (row >= N) row = N - 1;   // clamp: garbage rows masked in epilogue
        const char* src = slab + (size_t)row * 256 + (unsigned)((c8 * 16) ^ ((r & 7) << 4));
        __builtin_amdgcn_global_load_lds(
            (const __attribute__((address_space(1))) void*)src,
            (__attribute__((address_space(3))) void*)(atile + p * 4096 + w * 1024),
            16, 0, 0);
    }
    __syncthreads();

    const f16* Wt = Wth + (size_t)s * 16384;
    f32x4 acc0[8], acc1[8];
    #pragma unroll
    for (int ct = 0; ct < 8; ++ct) {
        acc0[ct] = (f32x4){0.f, 0.f, 0.f, 0.f};
        acc1[ct] = (f32x4){0.f, 0.f, 0.f, 0.f};
    }
    const int arow0 = (w << 5) + (lane & 15);
    const int arow1 = arow0 + 16;
    const int kq = (lane >> 4) * 8;
    #pragma unroll
    for (int ks = 0; ks < 4; ++ks) {
        f16x8 af0 = *(const f16x8*)(atile + a_swz(arow0, (ks * 32 + kq) * 2));
        f16x8 af1 = *(const f16x8*)(atile + a_swz(arow1, (ks * 32 + kq) * 2));
        #pragma unroll
        for (int ct = 0; ct < 8; ++ct) {
            f16x8 bf = *(const f16x8*)(Wt + (size_t)(ct * 16 + (lane & 15)) * D + ks * 32 + kq);
            acc0[ct] = __builtin_amdgcn_mfma_f32_16x16x32_f16(af0, bf, acc0[ct], 0, 0, 0);
            acc1[ct] = __builtin_amdgcn_mfma_f32_16x16x32_f16(af1, bf, acc1[ct], 0, 0, 0);
        }
    }

    const int col_lo = lane & 15;
    const int rb0 = row0 + (w << 5) + ((lane >> 4) << 2);
    const int rb1 = rb0 + 16;
    #pragma unroll
    for (int ct = 0; ct < 8; ++ct) {
        int col = ct * 16 + col_lo;
        float bv = bias[s * D + col];
        float s_ = 0.f, q_ = 0.f;
        #pragma unroll
        for (int r = 0; r < 4; ++r) {
            int row = rb0 + r;
            float val = acc0[ct][r] + bv;
            if (row < N) {
                *(f16*)(slab + (size_t)row * 256 + col * 2) = (f16)val;
                s_ += val; q_ += val * val;
            }
        }
        #pragma unroll
        for (int r = 0; r < 4; ++r) {
            int row = rb1 + r;
            float val = acc1[ct][r] + bv;
            if (row < N) {
                *(f16*)(slab + (size_t)row * 256 + col * 2) = (f16)val;
                s_ += val; q_ += val * val;
            }
        }
        s_ += __shfl_xor(s_, 16); q_ += __shfl_xor(q_, 16);
        s_ += __shfl_xor(s_, 32); q_ += __shfl_xor(q_, 32);
        if (lane < 16) { wst[w][col] = s_; wst[w][128 + col] = q_; }
    }
    __syncthreads();
    float p = wst[0][tid] + wst[1][tid] + wst[2][tid] + wst[3][tid];
    partials[((size_t)blockIdx.x * 3 + s) * 256 + tid] = p;
}

// -------------------------------------------------------------- layer-2 GEMM
// grid (tiles, s). A = relu(z1*affa + affc), reg-staged (transform needed).
__global__ __launch_bounds__(256) void gemm_l2(char* __restrict__ slabs, size_t slabN,
                                               const f16* __restrict__ Wth2,
                                               const float* __restrict__ bias,
                                               const float* __restrict__ affa,
                                               const float* __restrict__ affc,
                                               float* __restrict__ partials, int N) {
    __shared__ alignas(16) char atile[128 * 256];
    __shared__ float wst[4][256];
    const int tid  = threadIdx.x;
    const int lane = tid & 63;
    const int w    = tid >> 6;
    const int s    = blockIdx.y;
    const int row0 = blockIdx.x * 128;
    char* slab = slabs + (size_t)s * slabN;
    const int c8 = tid & 15;

    // hoisted per-thread affine params (c8 loop-invariant)
    f32x4 a0 = ((const f32x4*)(affa + s * 128))[c8 * 2];
    f32x4 a1 = ((const f32x4*)(affa + s * 128))[c8 * 2 + 1];
    f32x4 c0 = ((const f32x4*)(affc + s * 128))[c8 * 2];
    f32x4 c1 = ((const f32x4*)(affc + s * 128))[c8 * 2 + 1];

    #pragma unroll
    for (int p = 0; p < 8; ++p) {
        int r = p * 16 + (tid >> 4);
        int row = row0 + r;
        f16x8 hv = {0, 0, 0, 0, 0, 0, 0, 0};
        if (row < N) {
            f16x8 zv = ((const f16x8*)(slab + (size_t)row * 256))[c8];
            #pragma unroll
            for (int j = 0; j < 4; ++j) {
                float t0 = (float)zv[j] * a0[j] + c0[j];
                float t1 = (float)zv[4 + j] * a1[j] + c1[j];
                hv[j]     = (f16)(t0 > 0.f ? t0 : 0.f);
                hv[4 + j] = (f16)(t1 > 0.f ? t1 : 0.f);
            }
        }
        *(f16x8*)(atile + a_swz(r, c8 * 16)) = hv;
    }
    __syncthreads();

    const f16* Wt = Wth2 + (size_t)s * 16384;
    f32x4 acc0[8], acc1[8];
    #pragma unroll
    for (int ct = 0; ct < 8; ++ct) {
        acc0[ct] = (f32x4){0.f, 0.f, 0.f, 0.f};
        acc1[ct] = (f32x4){0.f, 0.f, 0.f, 0.f};
    }
    const int arow0 = (w << 5) + (lane & 15);
    const int arow1 = arow0 + 16;
    const int kq = (lane >> 4) * 8;
    #pragma unroll
    for (int ks = 0; ks < 4; ++ks) {
        f16x8 af0 = *(const f16x8*)(atile + a_swz(arow0, (ks * 32 + kq) * 2));
        f16x8 af1 = *(const f16x8*)(atile + a_swz(arow1, (ks * 32 + kq) * 2));
        #pragma unroll
        for (int ct = 0; ct < 8; ++ct) {
            f16x8 bf = *(const f16x8*)(Wt + (size_t)(ct * 16 + (lane & 15)) * D + ks * 32 + kq);
            acc0[ct] = __builtin_amdgcn_mfma_f32_16x16x32_f16(af0, bf, acc0[ct], 0, 0, 0);
            acc1[ct] = __builtin_amdgcn_mfma_f32_16x16x32_f16(af1, bf, acc1[ct], 0, 0, 0);
        }
    }

    const int col_lo = lane & 15;
    const int rb0 = row0 + (w << 5) + ((lane >> 4) << 2);
    const int rb1 = rb0 + 16;
    #pragma unroll
    for (int ct = 0; ct < 8; ++ct) {
        int col = ct * 16 + col_lo;
        float bv = bias[s * D + col];
        float s_ = 0.f, q_ = 0.f;
        #pragma unroll
        for (int r = 0; r < 4; ++r) {
            int row = rb0 + r;
            float val = acc0[ct][r] + bv;
            if (row < N) {
                *(f16*)(slab + (size_t)row * 256 + col * 2) = (f16)val;
                s_ += val; q_ += val * val;
            }
        }
        #pragma unroll
        for (int r = 0; r < 4; ++r) {
            int row = rb1 + r;
            float val = acc1[ct][r] + bv;
            if (row < N) {
                *(f16*)(slab + (size_t)row * 256 + col * 2) = (f16)val;
                s_ += val; q_ += val * val;
            }
        }
        s_ += __shfl_xor(s_, 16); q_ += __shfl_xor(q_, 16);
        s_ += __shfl_xor(s_, 32); q_ += __shfl_xor(q_, 32);
        if (lane < 16) { wst[w][col] = s_; wst[w][128 + col] = q_; }
    }
    __syncthreads();
    float p = wst[0][tid] + wst[1][tid] + wst[2][tid] + wst[3][tid];
    partials[((size_t)blockIdx.x * 3 + s) * 256 + tid] = p;
}

// ------------------------------------------------- fused stats -> BN affine
__global__ void bn_fuse(const float* __restrict__ partials,
                        const float* __restrict__ g, const float* __restrict__ be,
                        float* __restrict__ affa, float* __restrict__ affc,
                        int N, int nblk) {
    __shared__ float red[256];
    int s = blockIdx.x, tid = threadIdx.x;
    float v = 0.f;
    #pragma unroll 4
    for (int b = 0; b < nblk; ++b)
        v += partials[((size_t)b * 3 + s) * 256 + tid];
    red[tid] = v;
    __syncthreads();
    if (tid < 128) {
        float sm = red[tid], q = red[128 + tid];
        float n = (float)N;
        float mean = sm / n;
        float var  = q / n - mean * mean;
        float a = g[s * D + tid] * rsqrtf(var + 1e-5f);
        affa[s * 128 + tid] = a;
        affc[s * 128 + tid] = be[s * D + tid] - mean * a;
    }
}

// ----------------------------------------------------- final accum (3 s sum)
__global__ __launch_bounds__(256) void accum3(const char* __restrict__ slabs, size_t slabN,
                                              const float* __restrict__ affa,
                                              const float* __restrict__ affc,
                                              float* __restrict__ outp, int N) {
    int total = N * 16;
    for (int i = blockIdx.x * 256 + threadIdx.x; i < total; i += gridDim.x * 256) {
        int row = i >> 4;
        int c8  = i & 15;
        f32x4 o0 = {0.f, 0.f, 0.f, 0.f}, o1 = {0.f, 0.f, 0.f, 0.f};
        #pragma unroll
        for (int s = 0; s < 3; ++s) {
            f16x8 z = ((const f16x8*)(slabs + (size_t)s * slabN + (size_t)row * 256))[c8];
            f32x4 a0 = ((const f32x4*)(affa + s * 128))[c8 * 2];
            f32x4 a1 = ((const f32x4*)(affa + s * 128))[c8 * 2 + 1];
            f32x4 c0 = ((const f32x4*)(affc + s * 128))[c8 * 2];
            f32x4 c1 = ((const f32x4*)(affc + s * 128))[c8 * 2 + 1];
            #pragma unroll
            for (int j = 0; j < 4; ++j) {
                float t0 = (float)z[j] * a0[j] + c0[j];
                float t1 = (float)z[4 + j] * a1[j] + c1[j];
                o0[j] += t0 > 0.f ? t0 : 0.f;
                o1[j] += t1 > 0.f ? t1 : 0.f;
            }
        }
        ((f32x4*)(outp + (size_t)row * D))[c8 * 2]     = o0;
        ((f32x4*)(outp + (size_t)row * D))[c8 * 2 + 1] = o1;
    }
}

extern "C" void kernel_launch(void* const* d_in, const int* in_sizes, int n_in,
                              void* d_out, int out_size, void* d_ws, size_t ws_size,
                              hipStream_t stream) {
    const float* x0  = (const float*)d_in[0];
    const float* x1  = (const float*)d_in[1];
    const float* x2  = (const float*)d_in[2];
    const int*   ei  = (const int*)d_in[3];
    const float* W1  = (const float*)d_in[4];
    const float* b1  = (const float*)d_in[5];
    const float* g1  = (const float*)d_in[6];
    const float* be1 = (const float*)d_in[7];
    const float* W2  = (const float*)d_in[8];
    const float* b2  = (const float*)d_in[9];
    const float* g2  = (const float*)d_in[10];
    const float* be2 = (const float*)d_in[11];
    const float* eps9 = (const float*)d_in[12];
    float* outp = (float*)d_out;

    const int NC[3] = {200000, 3000, 20000};
    const size_t OUT_OFF[3] = {0, (size_t)200000 * D, (size_t)203000 * D};

    char* ws = (char*)d_ws;
    size_t off = 0;
    char* slabs = ws;                 off += (size_t)3 * 200000 * 256;     // 153.6 MB
    int2* binned = (int2*)slabs;      // 36 MB alias, consumed before slabs written
    f16* x16    = (f16*)(ws + off);   off += (size_t)223000 * 256;         // 57.1 MB
    int* ssrc   = (int*)(ws + off);   off += (size_t)9 * E_PER * 4;        // 18 MB
    int* rowstart = (int*)(ws + off); off += (size_t)(TOT_ROWS + 2) * 4;
    off = (off + 255) & ~(size_t)255;
    int* bcnt   = (int*)(ws + off);   off += 2308 * 4;
    int* bbase  = (int*)(ws + off);   off += 2308 * 4;
    int* bcursor= (int*)(ws + off);   off += 2308 * 4;
    off = (off + 255) & ~(size_t)255;
    float* partials = (float*)(ws + off); off += (size_t)1563 * 3 * 256 * 4;
    float* aff1a = (float*)(ws + off); off += 1536;
    float* aff1c = (float*)(ws + off); off += 1536;
    float* aff2a = (float*)(ws + off); off += 1536;
    float* aff2c = (float*)(ws + off); off += 1536;
    f16* Wth = (f16*)(ws + off); off += (size_t)2 * 3 * 128 * 128 * sizeof(f16);

    // ---- setup
    precast<<<384, 256, 0, stream>>>(W1, W2, Wth);
    cast16_all<<<2048, 256, 0, stream>>>(x0, x1, x2, x16);

    // ---- CSR build via LDS-binned counting sort (all 9 types)
    hipMemsetAsync(bcnt, 0, 2308 * 4, stream);
    int nchunk = (E_PER + CH - 1) / CH;   // 123
    bucket_count<<<dim3(nchunk, 9), 256, 0, stream>>>(ei, bcnt);
    bucket_scan<<<1, 256, 0, stream>>>(bcnt, bbase, bcursor);
    bin_scatter<<<dim3(nchunk, 9), 256, 0, stream>>>(ei, bcursor, binned);
    fine_fill<<<dim3(256, 9), 256, 0, stream>>>(binned, bbase, rowstart, ssrc);

    // ---- per target type
    for (int t = 0; t < 3; ++t) {
        int N = NC[t];
        size_t slabN = (size_t)N * 256;
        int gtiles = (N + 127) / 128;

        if (t == 1) {
            aggregate_b<<<dim3(N, 3), 256, 0, stream>>>(x16, rowstart, ssrc, slabs, slabN,
                                                        eps9, t, N, 1);
        } else {
            aggregate_b<<<dim3((N + 3) / 4, 3), 256, 0, stream>>>(x16, rowstart, ssrc, slabs, slabN,
                                                                  eps9, t, N, 0);
        }

        gemm_l1<<<dim3(gtiles, 3), 256, 0, stream>>>(slabs, slabN, Wth, b1, partials, N);
        bn_fuse<<<3, 256, 0, stream>>>(partials, g1, be1, aff1a, aff1c, N, gtiles);

        gemm_l2<<<dim3(gtiles, 3), 256, 0, stream>>>(slabs, slabN, Wth + 3 * 16384, b2,
                                                     aff1a, aff1c, partials, N);
        bn_fuse<<<3, 256, 0, stream>>>(partials, g2, be2, aff2a, aff2c, N, gtiles);

        int nblk = (N * 16 + 255) / 256;
        if (nblk > 2048) nblk = 2048;
        accum3<<<nblk, 256, 0, stream>>>(slabs, slabN, aff2a, aff2c, outp + OUT_OFF[t], N);
    }
}

// Round 8
// 971.698 us; speedup vs baseline: 7.2658x; 1.2282x over previous
//
#include <hip/hip_runtime.h>
#include <hip/hip_fp16.h>

#define D 128
#define E_PER 500000
#define TOT_ROWS 669000
#define CH 4096
#define SLABSZ ((size_t)223000 * 256)

typedef _Float16 f16;
typedef _Float16 f16x8 __attribute__((ext_vector_type(8)));
typedef _Float16 f16x4 __attribute__((ext_vector_type(4)));
typedef _Float16 f16x2 __attribute__((ext_vector_type(2)));
typedef float f32x4 __attribute__((ext_vector_type(4)));

// Per-edge-type row-segment bases in the concatenated CSR arrays (k = s*3 + t).
__device__ const int d_SEGB[9] = {0, 200000, 203000, 223000, 423000, 426000,
                                  446000, 646000, 649000};
__device__ const int d_XB[3] = {0, 200000, 203000};
__device__ const int d_NC[3] = {200000, 3000, 20000};
// gemm tile ranges per t (128-row tiles): t0 1563, t1 24, t2 157
__device__ const int d_TLO[3] = {0, 1563, 1587};
__device__ const int d_THI[3] = {1563, 1587, 1744};
// aggregate block offsets per k (t0/t2: 4 rows/block; t1: 1 row/block 4-wave)
__device__ const int d_AOFF[10] = {0, 50000, 53000, 58000, 108000, 111000,
                                   116000, 166000, 169000, 174000};

// XOR swizzle for the A tile in LDS (row stride 256B f16).
__device__ __forceinline__ unsigned a_swz(int row, int byteoff) {
    return (unsigned)(row * 256 + byteoff) ^ (unsigned)((row & 7) << 4);
}

// map global gemm tile -> (t, local tile)
__device__ __forceinline__ void tile_map(int g, int& t, int& tl) {
    if (g < 1563)      { t = 0; tl = g; }
    else if (g < 1587) { t = 1; tl = g - 1563; }
    else               { t = 2; tl = g - 1587; }
}

// ---------------------------------------------------------------- precast W^T
__global__ void precast(const float* __restrict__ W1,
                        const float* __restrict__ W2,
                        f16* __restrict__ Wth) {
    int i = blockIdx.x * 256 + threadIdx.x;
    if (i >= 2 * 3 * 128 * 128) return;
    int layer = i / 49152;
    int rem = i - layer * 49152;
    int s = rem / 16384;
    int r2 = rem & 16383;
    int kk = r2 >> 7;
    int c  = r2 & 127;
    const float* W = layer ? W2 : W1;
    Wth[(((size_t)layer * 3 + s) * 128 + c) * 128 + kk] = (f16)W[((size_t)s * 128 + kk) * 128 + c];
}

// ------------------------------------------------------- all x -> f16 table
__global__ void cast16_all(const float* __restrict__ x0,
                           const float* __restrict__ x1,
                           const float* __restrict__ x2,
                           f16* __restrict__ y) {
    const int total = 223000 * 16;
    for (int i = blockIdx.x * 256 + threadIdx.x; i < total; i += gridDim.x * 256) {
        int row = i >> 4, c8 = i & 15;
        const float* src;
        if (row < 200000)      src = x0 + (size_t)row * D;
        else if (row < 203000) src = x1 + (size_t)(row - 200000) * D;
        else                   src = x2 + (size_t)(row - 203000) * D;
        f32x4 v0 = ((const f32x4*)src)[c8 * 2];
        f32x4 v1 = ((const f32x4*)src)[c8 * 2 + 1];
        f16x8 h;
        #pragma unroll
        for (int j = 0; j < 4; ++j) { h[j] = (f16)v0[j]; h[4 + j] = (f16)v1[j]; }
        ((f16x8*)(y + (size_t)row * D))[c8] = h;
    }
}

// ============================================================ CSR via 2-pass
__global__ __launch_bounds__(256) void bucket_count(const int* __restrict__ ei,
                                                    int* __restrict__ bcnt) {
    __shared__ int hist[256];
    int k = blockIdx.y, tid = threadIdx.x;
    const int* dstp = ei + (size_t)k * 2 * E_PER + E_PER;
    unsigned Nt = (unsigned)d_NC[k % 3];
    int base = blockIdx.x * CH;
    int hi = min(base + CH, E_PER);
    hist[tid] = 0;
    __syncthreads();
    for (int i = base + tid; i < hi; i += 256) {
        unsigned b = ((unsigned)dstp[i] << 8) / Nt;
        atomicAdd(&hist[b], 1);
    }
    __syncthreads();
    if (hist[tid]) atomicAdd(&bcnt[k * 256 + tid], hist[tid]);
}

__global__ void bucket_scan(const int* __restrict__ bcnt,
                            int* __restrict__ bbase, int* __restrict__ bcursor) {
    __shared__ int sb[256];
    int t = threadIdx.x;
    int loc[9];
    int s = 0;
    #pragma unroll
    for (int j = 0; j < 9; ++j) { loc[j] = bcnt[t * 9 + j]; s += loc[j]; }
    sb[t] = s; __syncthreads();
    int v = s;
    for (int off = 1; off < 256; off <<= 1) {
        int u = (t >= off) ? sb[t - off] : 0;
        __syncthreads();
        sb[t] += u;
        __syncthreads();
    }
    int pre = sb[t] - v;
    #pragma unroll
    for (int j = 0; j < 9; ++j) {
        bbase[t * 9 + j] = pre;
        bcursor[t * 9 + j] = pre;
        pre += loc[j];
    }
    if (t == 255) bbase[2304] = pre;
}

__global__ __launch_bounds__(256) void bin_scatter(const int* __restrict__ ei,
                                                   int* __restrict__ bcursor,
                                                   int2* __restrict__ binned) {
    __shared__ int hist[256], gb[256], cur[256];
    int k = blockIdx.y, tid = threadIdx.x;
    const int* srcp = ei + (size_t)k * 2 * E_PER;
    const int* dstp = srcp + E_PER;
    unsigned Nt = (unsigned)d_NC[k % 3];
    int base = blockIdx.x * CH;
    int hi = min(base + CH, E_PER);
    hist[tid] = 0;
    __syncthreads();
    for (int i = base + tid; i < hi; i += 256) {
        unsigned b = ((unsigned)dstp[i] << 8) / Nt;
        atomicAdd(&hist[b], 1);
    }
    __syncthreads();
    gb[tid] = hist[tid] ? atomicAdd(&bcursor[k * 256 + tid], hist[tid]) : 0;
    cur[tid] = 0;
    __syncthreads();
    for (int i = base + tid; i < hi; i += 256) {
        int src = srcp[i], dst = dstp[i];
        unsigned b = ((unsigned)dst << 8) / Nt;
        int r = atomicAdd(&cur[b], 1);
        binned[(size_t)gb[b] + r] = make_int2(src, dst);
    }
}

__global__ __launch_bounds__(256) void fine_fill(const int2* __restrict__ binned,
                                                 const int* __restrict__ bbase,
                                                 int* __restrict__ rowstart,
                                                 int* __restrict__ ssrc) {
    __shared__ int rcnt[784];
    __shared__ int excl[784];
    __shared__ int scur[784];
    __shared__ int sb[256];
    int k = blockIdx.y, b = blockIdx.x, tid = threadIdx.x;
    int Nt = d_NC[k % 3];
    int segb = d_SEGB[k];
    int row_lo = (b * Nt + 255) >> 8;
    int row_hi = ((b + 1) * Nt + 255) >> 8;
    int nrows = row_hi - row_lo;
    int ebase = bbase[k * 256 + b];
    int eend  = bbase[k * 256 + b + 1];
    for (int i = tid; i < nrows; i += 256) rcnt[i] = 0;
    __syncthreads();
    for (int e = ebase + tid; e < eend; e += 256)
        atomicAdd(&rcnt[binned[e].y - row_lo], 1);
    __syncthreads();
    int stride = (nrows + 255) >> 8;
    int lo = tid * stride;
    int hi2 = min(lo + stride, nrows);
    int s = 0;
    for (int i = lo; i < hi2; ++i) s += rcnt[i];
    sb[tid] = s; __syncthreads();
    int v = s;
    for (int off = 1; off < 256; off <<= 1) {
        int u = (tid >= off) ? sb[tid - off] : 0;
        __syncthreads();
        sb[tid] += u;
        __syncthreads();
    }
    int pre = sb[tid] - v;
    for (int i = lo; i < hi2; ++i) {
        excl[i] = pre;
        scur[i] = pre;
        pre += rcnt[i];
    }
    __syncthreads();
    for (int i = tid; i < nrows; i += 256)
        rowstart[segb + row_lo + i] = ebase + excl[i];
    if (k == 8 && b == 255 && tid == 0) rowstart[TOT_ROWS] = eend;
    for (int e = ebase + tid; e < eend; e += 256) {
        int2 ed = binned[e];
        int r = atomicAdd(&scur[ed.y - row_lo], 1);
        ssrc[ebase + r] = ed.x;
    }
}

// ----------------------------------------------------- aggregate, all 9 k
__global__ __launch_bounds__(256) void aggregate_all(const f16* __restrict__ x16,
                                                     const int* __restrict__ rowstart,
                                                     const int* __restrict__ ssrc,
                                                     char* __restrict__ slabs,
                                                     const float* __restrict__ eps9) {
    __shared__ float part[4][130];
    int g = blockIdx.x;
    int k = 0;
    #pragma unroll
    for (int j = 1; j < 9; ++j) if (g >= d_AOFF[j]) k = j;
    int b = g - d_AOFF[k];
    int s = k / 3, t = k % 3;
    int N = d_NC[t];
    int wpr4 = (t == 1);
    const int* rs = rowstart + d_SEGB[k];
    const f16* xsrc = x16 + (size_t)d_XB[s] * D;
    const f16* xt   = x16 + (size_t)d_XB[t] * D;
    char* slab = slabs + (size_t)s * SLABSZ + (size_t)d_XB[t] * 256;
    float epsv = 1.0f + eps9[k];
    int lane = threadIdx.x & 63;
    int w    = threadIdx.x >> 6;
    int row, sub, wpr;
    if (wpr4) { row = b; sub = w; wpr = 4; }
    else      { row = (b << 2) + w; sub = 0; wpr = 1; }
    float r0 = 0.f, r1 = 0.f;
    if (row < N) {
        if (sub == 0) {
            f16x2 xv = *(const f16x2*)(xt + (size_t)row * D + lane * 2);
            r0 = epsv * (float)xv[0];
            r1 = epsv * (float)xv[1];
        }
        int e1 = rs[row + 1];
        int e  = rs[row] + sub;
        float a0=0,a1=0,b0=0,b1=0,c0=0,c1=0,d0=0,d1=0;
        for (; e + 3 * wpr < e1; e += 4 * wpr) {
            int s0 = ssrc[e], s1 = ssrc[e + wpr], s2 = ssrc[e + 2 * wpr], s3 = ssrc[e + 3 * wpr];
            f16x2 v0 = *(const f16x2*)(xsrc + (size_t)s0 * D + lane * 2);
            f16x2 v1 = *(const f16x2*)(xsrc + (size_t)s1 * D + lane * 2);
            f16x2 v2 = *(const f16x2*)(xsrc + (size_t)s2 * D + lane * 2);
            f16x2 v3 = *(const f16x2*)(xsrc + (size_t)s3 * D + lane * 2);
            a0 += (float)v0[0]; a1 += (float)v0[1];
            b0 += (float)v1[0]; b1 += (float)v1[1];
            c0 += (float)v2[0]; c1 += (float)v2[1];
            d0 += (float)v3[0]; d1 += (float)v3[1];
        }
        if (e + wpr < e1) {
            int s0 = ssrc[e], s1 = ssrc[e + wpr];
            f16x2 v0 = *(const f16x2*)(xsrc + (size_t)s0 * D + lane * 2);
            f16x2 v1 = *(const f16x2*)(xsrc + (size_t)s1 * D + lane * 2);
            a0 += (float)v0[0]; a1 += (float)v0[1];
            b0 += (float)v1[0]; b1 += (float)v1[1];
            e += 2 * wpr;
        }
        if (e < e1) {
            int s0 = ssrc[e];
            f16x2 v0 = *(const f16x2*)(xsrc + (size_t)s0 * D + lane * 2);
            a0 += (float)v0[0]; a1 += (float)v0[1];
        }
        r0 += (a0 + b0) + (c0 + d0);
        r1 += (a1 + b1) + (c1 + d1);
    }
    if (wpr4) {
        part[w][lane * 2] = r0; part[w][lane * 2 + 1] = r1;
        __syncthreads();
        if (w == 0 && row < N) {
            float s0 = part[0][lane*2] + part[1][lane*2] + part[2][lane*2] + part[3][lane*2];
            float s1 = part[0][lane*2+1] + part[1][lane*2+1] + part[2][lane*2+1] + part[3][lane*2+1];
            f16x2 h; h[0] = (f16)s0; h[1] = (f16)s1;
            *(f16x2*)(slab + (size_t)row * 256 + lane * 4) = h;
        }
    } else if (row < N) {
        f16x2 h; h[0] = (f16)r0; h[1] = (f16)r1;
        *(f16x2*)(slab + (size_t)row * 256 + lane * 4) = h;
    }
}

// -------------------------------------------------------------- layer-1 GEMM
// grid (1744, 3): x = global tile (t mapped), y = s.
__global__ __launch_bounds__(256) void gemm_l1(char* __restrict__ slabs,
                                               const f16* __restrict__ Wth,
                                               const float* __restrict__ bias,
                                               float* __restrict__ partials) {
    __shared__ alignas(16) char atile[128 * 256];
    __shared__ float wst[4][256];
    const int tid  = threadIdx.x;
    const int lane = tid & 63;
    const int w    = tid >> 6;
    const int s    = blockIdx.y;
    int t, tl;
    tile_map(blockIdx.x, t, tl);
    const int N = d_NC[t];
    const int row0 = tl * 128;
    char* slab = slabs + (size_t)s * SLABSZ + (size_t)d_XB[t] * 256;

    #pragma unroll
    for (int p = 0; p < 8; ++p) {
        int r  = p * 16 + (tid >> 4);
        int c8 = tid & 15;
        int row = row0 + r;
        if (row >= N) row = N - 1;   // clamp: garbage rows masked in epilogue
        const char* src = slab + (size_t)row * 256 + (unsigned)((c8 * 16) ^ ((r & 7) << 4));
        __builtin_amdgcn_global_load_lds(
            (const __attribute__((address_space(1))) void*)src,
            (__attribute__((address_space(3))) void*)(atile + p * 4096 + w * 1024),
            16, 0, 0);
    }
    __syncthreads();

    const f16* Wt = Wth + (size_t)s * 16384;
    f32x4 acc0[8], acc1[8];
    #pragma unroll
    for (int ct = 0; ct < 8; ++ct) {
        acc0[ct] = (f32x4){0.f, 0.f, 0.f, 0.f};
        acc1[ct] = (f32x4){0.f, 0.f, 0.f, 0.f};
    }
    const int arow0 = (w << 5) + (lane & 15);
    const int arow1 = arow0 + 16;
    const int kq = (lane >> 4) * 8;
    #pragma unroll
    for (int ks = 0; ks < 4; ++ks) {
        f16x8 af0 = *(const f16x8*)(atile + a_swz(arow0, (ks * 32 + kq) * 2));
        f16x8 af1 = *(const f16x8*)(atile + a_swz(arow1, (ks * 32 + kq) * 2));
        #pragma unroll
        for (int ct = 0; ct < 8; ++ct) {
            f16x8 bf = *(const f16x8*)(Wt + (size_t)(ct * 16 + (lane & 15)) * D + ks * 32 + kq);
            acc0[ct] = __builtin_amdgcn_mfma_f32_16x16x32_f16(af0, bf, acc0[ct], 0, 0, 0);
            acc1[ct] = __builtin_amdgcn_mfma_f32_16x16x32_f16(af1, bf, acc1[ct], 0, 0, 0);
        }
    }

    // epilogue: stats + z->LDS (wave-local rows: no barrier needed before)
    const int col_lo = lane & 15;
    const int lrb0 = (w << 5) + ((lane >> 4) << 2);
    #pragma unroll
    for (int ct = 0; ct < 8; ++ct) {
        int col = ct * 16 + col_lo;
        float bv = bias[s * D + col];
        float s_ = 0.f, q_ = 0.f;
        #pragma unroll
        for (int r = 0; r < 4; ++r) {
            int lrow = lrb0 + r;
            float val = acc0[ct][r] + bv;
            if (row0 + lrow < N) { s_ += val; q_ += val * val; }
            *(f16*)(atile + a_swz(lrow, col * 2)) = (f16)val;
        }
        #pragma unroll
        for (int r = 0; r < 4; ++r) {
            int lrow = lrb0 + 16 + r;
            float val = acc1[ct][r] + bv;
            if (row0 + lrow < N) { s_ += val; q_ += val * val; }
            *(f16*)(atile + a_swz(lrow, col * 2)) = (f16)val;
        }
        s_ += __shfl_xor(s_, 16); q_ += __shfl_xor(q_, 16);
        s_ += __shfl_xor(s_, 32); q_ += __shfl_xor(q_, 32);
        if (lane < 16) { wst[w][col] = s_; wst[w][128 + col] = q_; }
    }
    __syncthreads();

    // coalesced writeback (16B/lane)
    #pragma unroll
    for (int p = 0; p < 8; ++p) {
        int r  = p * 16 + (tid >> 4);
        int c8 = tid & 15;
        int row = row0 + r;
        if (row < N)
            *(f16x8*)(slab + (size_t)row * 256 + c8 * 16) = *(const f16x8*)(atile + a_swz(r, c8 * 16));
    }
    float pv = wst[0][tid] + wst[1][tid] + wst[2][tid] + wst[3][tid];
    partials[((size_t)blockIdx.x * 3 + s) * 256 + tid] = pv;
}

// -------------------------------------------------------------- layer-2 GEMM
__global__ __launch_bounds__(256) void gemm_l2(char* __restrict__ slabs,
                                               const f16* __restrict__ Wth2,
                                               const float* __restrict__ bias,
                                               const float* __restrict__ affa,
                                               const float* __restrict__ affc,
                                               float* __restrict__ partials) {
    __shared__ alignas(16) char atile[128 * 256];
    __shared__ float wst[4][256];
    const int tid  = threadIdx.x;
    const int lane = tid & 63;
    const int w    = tid >> 6;
    const int s    = blockIdx.y;
    int t, tl;
    tile_map(blockIdx.x, t, tl);
    const int N = d_NC[t];
    const int row0 = tl * 128;
    const int k = s * 3 + t;
    char* slab = slabs + (size_t)s * SLABSZ + (size_t)d_XB[t] * 256;
    const int c8 = tid & 15;

    // hoisted affine params for this thread's 8 columns
    f32x4 a0 = ((const f32x4*)(affa + k * 128))[c8 * 2];
    f32x4 a1 = ((const f32x4*)(affa + k * 128))[c8 * 2 + 1];
    f32x4 c0 = ((const f32x4*)(affc + k * 128))[c8 * 2];
    f32x4 c1 = ((const f32x4*)(affc + k * 128))[c8 * 2 + 1];

    // T14 split: issue all loads, then transform + LDS write
    f16x8 zv[8];
    #pragma unroll
    for (int p = 0; p < 8; ++p) {
        int r = p * 16 + (tid >> 4);
        int row = row0 + r;
        zv[p] = (row < N) ? ((const f16x8*)(slab + (size_t)row * 256))[c8]
                          : (f16x8){0, 0, 0, 0, 0, 0, 0, 0};
    }
    #pragma unroll
    for (int p = 0; p < 8; ++p) {
        int r = p * 16 + (tid >> 4);
        f16x8 hv;
        #pragma unroll
        for (int j = 0; j < 4; ++j) {
            float t0 = (float)zv[p][j] * a0[j] + c0[j];
            float t1 = (float)zv[p][4 + j] * a1[j] + c1[j];
            hv[j]     = (f16)(t0 > 0.f ? t0 : 0.f);
            hv[4 + j] = (f16)(t1 > 0.f ? t1 : 0.f);
        }
        *(f16x8*)(atile + a_swz(r, c8 * 16)) = hv;
    }
    __syncthreads();

    const f16* Wt = Wth2 + (size_t)s * 16384;
    f32x4 acc0[8], acc1[8];
    #pragma unroll
    for (int ct = 0; ct < 8; ++ct) {
        acc0[ct] = (f32x4){0.f, 0.f, 0.f, 0.f};
        acc1[ct] = (f32x4){0.f, 0.f, 0.f, 0.f};
    }
    const int arow0 = (w << 5) + (lane & 15);
    const int arow1 = arow0 + 16;
    const int kq = (lane >> 4) * 8;
    #pragma unroll
    for (int ks = 0; ks < 4; ++ks) {
        f16x8 af0 = *(const f16x8*)(atile + a_swz(arow0, (ks * 32 + kq) * 2));
        f16x8 af1 = *(const f16x8*)(atile + a_swz(arow1, (ks * 32 + kq) * 2));
        #pragma unroll
        for (int ct = 0; ct < 8; ++ct) {
            f16x8 bf = *(const f16x8*)(Wt + (size_t)(ct * 16 + (lane & 15)) * D + ks * 32 + kq);
            acc0[ct] = __builtin_amdgcn_mfma_f32_16x16x32_f16(af0, bf, acc0[ct], 0, 0, 0);
            acc1[ct] = __builtin_amdgcn_mfma_f32_16x16x32_f16(af1, bf, acc1[ct], 0, 0, 0);
        }
    }

    const int col_lo = lane & 15;
    const int lrb0 = (w << 5) + ((lane >> 4) << 2);
    #pragma unroll
    for (int ct = 0; ct < 8; ++ct) {
        int col = ct * 16 + col_lo;
        float bv = bias[s * D + col];
        float s_ = 0.f, q_ = 0.f;
        #pragma unroll
        for (int r = 0; r < 4; ++r) {
            int lrow = lrb0 + r;
            float val = acc0[ct][r] + bv;
            if (row0 + lrow < N) { s_ += val; q_ += val * val; }
            *(f16*)(atile + a_swz(lrow, col * 2)) = (f16)val;
        }
        #pragma unroll
        for (int r = 0; r < 4; ++r) {
            int lrow = lrb0 + 16 + r;
            float val = acc1[ct][r] + bv;
            if (row0 + lrow < N) { s_ += val; q_ += val * val; }
            *(f16*)(atile + a_swz(lrow, col * 2)) = (f16)val;
        }
        s_ += __shfl_xor(s_, 16); q_ += __shfl_xor(q_, 16);
        s_ += __shfl_xor(s_, 32); q_ += __shfl_xor(q_, 32);
        if (lane < 16) { wst[w][col] = s_; wst[w][128 + col] = q_; }
    }
    __syncthreads();

    #pragma unroll
    for (int p = 0; p < 8; ++p) {
        int r = p * 16 + (tid >> 4);
        int row = row0 + r;
        if (row < N)
            *(f16x8*)(slab + (size_t)row * 256 + c8 * 16) = *(const f16x8*)(atile + a_swz(r, c8 * 16));
    }
    float pv = wst[0][tid] + wst[1][tid] + wst[2][tid] + wst[3][tid];
    partials[((size_t)blockIdx.x * 3 + s) * 256 + tid] = pv;
}

// ------------------------------------------------- fused stats -> BN affine
// 9 blocks: blockIdx.x = k = s*3 + t. aff arrays are [9][128].
__global__ void bn_fuse(const float* __restrict__ partials,
                        const float* __restrict__ g, const float* __restrict__ be,
                        float* __restrict__ affa, float* __restrict__ affc) {
    __shared__ float red[256];
    int k = blockIdx.x, tid = threadIdx.x;
    int s = k / 3, t = k % 3;
    int lo = d_TLO[t], hi = d_THI[t];
    float v = 0.f;
    #pragma unroll 4
    for (int b = lo; b < hi; ++b)
        v += partials[((size_t)b * 3 + s) * 256 + tid];
    red[tid] = v;
    __syncthreads();
    if (tid < 128) {
        float sm = red[tid], q = red[128 + tid];
        float n = (float)d_NC[t];
        float mean = sm / n;
        float var  = q / n - mean * mean;
        float a = g[s * D + tid] * rsqrtf(var + 1e-5f);
        affa[k * 128 + tid] = a;
        affc[k * 128 + tid] = be[s * D + tid] - mean * a;
    }
}

// -------------------------------------------------- final accum, all rows
__global__ __launch_bounds__(256) void accum_all(const char* __restrict__ slabs,
                                                 const float* __restrict__ affa,
                                                 const float* __restrict__ affc,
                                                 float* __restrict__ outp) {
    const int total = 223000 * 16;
    for (int i = blockIdx.x * 256 + threadIdx.x; i < total; i += gridDim.x * 256) {
        int row = i >> 4;
        int c8  = i & 15;
        int t = (row < 200000) ? 0 : (row < 203000) ? 1 : 2;
        f32x4 o0 = {0.f, 0.f, 0.f, 0.f}, o1 = {0.f, 0.f, 0.f, 0.f};
        #pragma unroll
        for (int s = 0; s < 3; ++s) {
            int k = s * 3 + t;
            f16x8 z = ((const f16x8*)(slabs + (size_t)s * SLABSZ + (size_t)row * 256))[c8];
            f32x4 a0 = ((const f32x4*)(affa + k * 128))[c8 * 2];
            f32x4 a1 = ((const f32x4*)(affa + k * 128))[c8 * 2 + 1];
            f32x4 c0 = ((const f32x4*)(affc + k * 128))[c8 * 2];
            f32x4 c1 = ((const f32x4*)(affc + k * 128))[c8 * 2 + 1];
            #pragma unroll
            for (int j = 0; j < 4; ++j) {
                float t0 = (float)z[j] * a0[j] + c0[j];
                float t1 = (float)z[4 + j] * a1[j] + c1[j];
                o0[j] += t0 > 0.f ? t0 : 0.f;
                o1[j] += t1 > 0.f ? t1 : 0.f;
            }
        }
        ((f32x4*)(outp + (size_t)row * D))[c8 * 2]     = o0;
        ((f32x4*)(outp + (size_t)row * D))[c8 * 2 + 1] = o1;
    }
}

extern "C" void kernel_launch(void* const* d_in, const int* in_sizes, int n_in,
                              void* d_out, int out_size, void* d_ws, size_t ws_size,
                              hipStream_t stream) {
    const float* x0  = (const float*)d_in[0];
    const float* x1  = (const float*)d_in[1];
    const float* x2  = (const float*)d_in[2];
    const int*   ei  = (const int*)d_in[3];
    const float* W1  = (const float*)d_in[4];
    const float* b1  = (const float*)d_in[5];
    const float* g1  = (const float*)d_in[6];
    const float* be1 = (const float*)d_in[7];
    const float* W2  = (const float*)d_in[8];
    const float* b2  = (const float*)d_in[9];
    const float* g2  = (const float*)d_in[10];
    const float* be2 = (const float*)d_in[11];
    const float* eps9 = (const float*)d_in[12];
    float* outp = (float*)d_out;

    char* ws = (char*)d_ws;
    size_t off = 0;
    char* slabs = ws;                 off += 3 * SLABSZ;                   // 171.3 MB
    int2* binned = (int2*)slabs;      // 36 MB alias, consumed before slabs written
    f16* x16    = (f16*)(ws + off);   off += SLABSZ;                       // 57.1 MB
    int* ssrc   = (int*)(ws + off);   off += (size_t)9 * E_PER * 4;        // 18 MB
    int* rowstart = (int*)(ws + off); off += (size_t)(TOT_ROWS + 2) * 4;
    off = (off + 255) & ~(size_t)255;
    int* bcnt   = (int*)(ws + off);   off += 2308 * 4;
    int* bbase  = (int*)(ws + off);   off += 2308 * 4;
    int* bcursor= (int*)(ws + off);   off += 2308 * 4;
    off = (off + 255) & ~(size_t)255;
    float* partials = (float*)(ws + off); off += (size_t)1744 * 3 * 256 * 4;
    float* aff1a = (float*)(ws + off); off += 9 * 128 * 4;
    float* aff1c = (float*)(ws + off); off += 9 * 128 * 4;
    float* aff2a = (float*)(ws + off); off += 9 * 128 * 4;
    float* aff2c = (float*)(ws + off); off += 9 * 128 * 4;
    f16* Wth = (f16*)(ws + off); off += (size_t)2 * 3 * 128 * 128 * sizeof(f16);

    // ---- setup
    precast<<<384, 256, 0, stream>>>(W1, W2, Wth);
    cast16_all<<<2048, 256, 0, stream>>>(x0, x1, x2, x16);

    // ---- CSR build via LDS-binned counting sort (all 9 types)
    hipMemsetAsync(bcnt, 0, 2308 * 4, stream);
    int nchunk = (E_PER + CH - 1) / CH;   // 123
    bucket_count<<<dim3(nchunk, 9), 256, 0, stream>>>(ei, bcnt);
    bucket_scan<<<1, 256, 0, stream>>>(bcnt, bbase, bcursor);
    bin_scatter<<<dim3(nchunk, 9), 256, 0, stream>>>(ei, bcursor, binned);
    fine_fill<<<dim3(256, 9), 256, 0, stream>>>(binned, bbase, rowstart, ssrc);

    // ---- fully batched pipeline (all 9 (s,t) at once)
    aggregate_all<<<174000, 256, 0, stream>>>(x16, rowstart, ssrc, slabs, eps9);

    gemm_l1<<<dim3(1744, 3), 256, 0, stream>>>(slabs, Wth, b1, partials);
    bn_fuse<<<9, 256, 0, stream>>>(partials, g1, be1, aff1a, aff1c);

    gemm_l2<<<dim3(1744, 3), 256, 0, stream>>>(slabs, Wth + 3 * 16384, b2,
                                               aff1a, aff1c, partials);
    bn_fuse<<<9, 256, 0, stream>>>(partials, g2, be2, aff2a, aff2c);

    accum_all<<<4096, 256, 0, stream>>>(slabs, aff2a, aff2c, outp);
}

// Round 9
// 956.450 us; speedup vs baseline: 7.3816x; 1.0159x over previous
//
#include <hip/hip_runtime.h>
#include <hip/hip_fp16.h>

#define D 128
#define E_PER 500000
#define TOT_ROWS 669000
#define CH 4096
#define SLABSZ ((size_t)223000 * 256)

typedef _Float16 f16;
typedef _Float16 f16x8 __attribute__((ext_vector_type(8)));
typedef _Float16 f16x4 __attribute__((ext_vector_type(4)));
typedef _Float16 f16x2 __attribute__((ext_vector_type(2)));
typedef float f32x4 __attribute__((ext_vector_type(4)));

// Per-edge-type row-segment bases in the concatenated CSR arrays (k = s*3 + t).
__device__ const int d_SEGB[9] = {0, 200000, 203000, 223000, 423000, 426000,
                                  446000, 646000, 649000};
__device__ const int d_XB[3] = {0, 200000, 203000};
__device__ const int d_NC[3] = {200000, 3000, 20000};
// gemm tile ranges per t (128-row tiles): t0 1563, t1 24, t2 157
__device__ const int d_TLO[3] = {0, 1563, 1587};
__device__ const int d_THI[3] = {1563, 1587, 1744};
// aggregate block offsets per k (t0/t2: 4 rows/block; t1: 1 row/block 4-wave)
__device__ const int d_AOFF[10] = {0, 50000, 53000, 58000, 108000, 111000,
                                   116000, 166000, 169000, 174000};

// XOR swizzle for the A tile in LDS (row stride 256B f16).
__device__ __forceinline__ unsigned a_swz(int row, int byteoff) {
    return (unsigned)(row * 256 + byteoff) ^ (unsigned)((row & 7) << 4);
}

// map global gemm tile -> (t, local tile)
__device__ __forceinline__ void tile_map(int g, int& t, int& tl) {
    if (g < 1563)      { t = 0; tl = g; }
    else if (g < 1587) { t = 1; tl = g - 1563; }
    else               { t = 2; tl = g - 1587; }
}

// ---------------------------------------------------------------- precast W^T
__global__ void precast(const float* __restrict__ W1,
                        const float* __restrict__ W2,
                        f16* __restrict__ Wth) {
    int i = blockIdx.x * 256 + threadIdx.x;
    if (i >= 2 * 3 * 128 * 128) return;
    int layer = i / 49152;
    int rem = i - layer * 49152;
    int s = rem / 16384;
    int r2 = rem & 16383;
    int kk = r2 >> 7;
    int c  = r2 & 127;
    const float* W = layer ? W2 : W1;
    Wth[(((size_t)layer * 3 + s) * 128 + c) * 128 + kk] = (f16)W[((size_t)s * 128 + kk) * 128 + c];
}

// ------------------------------------------------------- all x -> f16 table
__global__ void cast16_all(const float* __restrict__ x0,
                           const float* __restrict__ x1,
                           const float* __restrict__ x2,
                           f16* __restrict__ y) {
    const int total = 223000 * 16;
    for (int i = blockIdx.x * 256 + threadIdx.x; i < total; i += gridDim.x * 256) {
        int row = i >> 4, c8 = i & 15;
        const float* src;
        if (row < 200000)      src = x0 + (size_t)row * D;
        else if (row < 203000) src = x1 + (size_t)(row - 200000) * D;
        else                   src = x2 + (size_t)(row - 203000) * D;
        f32x4 v0 = ((const f32x4*)src)[c8 * 2];
        f32x4 v1 = ((const f32x4*)src)[c8 * 2 + 1];
        f16x8 h;
        #pragma unroll
        for (int j = 0; j < 4; ++j) { h[j] = (f16)v0[j]; h[4 + j] = (f16)v1[j]; }
        ((f16x8*)(y + (size_t)row * D))[c8] = h;
    }
}

// ============================================================ CSR via 2-pass
__global__ __launch_bounds__(256) void bucket_count(const int* __restrict__ ei,
                                                    int* __restrict__ bcnt) {
    __shared__ int hist[256];
    int k = blockIdx.y, tid = threadIdx.x;
    const int* dstp = ei + (size_t)k * 2 * E_PER + E_PER;
    unsigned Nt = (unsigned)d_NC[k % 3];
    int base = blockIdx.x * CH;
    int hi = min(base + CH, E_PER);
    hist[tid] = 0;
    __syncthreads();
    for (int i = base + tid; i < hi; i += 256) {
        unsigned b = ((unsigned)dstp[i] << 8) / Nt;
        atomicAdd(&hist[b], 1);
    }
    __syncthreads();
    if (hist[tid]) atomicAdd(&bcnt[k * 256 + tid], hist[tid]);
}

__global__ void bucket_scan(const int* __restrict__ bcnt,
                            int* __restrict__ bbase, int* __restrict__ bcursor) {
    __shared__ int sb[256];
    int t = threadIdx.x;
    int loc[9];
    int s = 0;
    #pragma unroll
    for (int j = 0; j < 9; ++j) { loc[j] = bcnt[t * 9 + j]; s += loc[j]; }
    sb[t] = s; __syncthreads();
    int v = s;
    for (int off = 1; off < 256; off <<= 1) {
        int u = (t >= off) ? sb[t - off] : 0;
        __syncthreads();
        sb[t] += u;
        __syncthreads();
    }
    int pre = sb[t] - v;
    #pragma unroll
    for (int j = 0; j < 9; ++j) {
        bbase[t * 9 + j] = pre;
        bcursor[t * 9 + j] = pre;
        pre += loc[j];
    }
    if (t == 255) bbase[2304] = pre;
}

__global__ __launch_bounds__(256) void bin_scatter(const int* __restrict__ ei,
                                                   int* __restrict__ bcursor,
                                                   int2* __restrict__ binned) {
    __shared__ int hist[256], gb[256], cur[256];
    int k = blockIdx.y, tid = threadIdx.x;
    const int* srcp = ei + (size_t)k * 2 * E_PER;
    const int* dstp = srcp + E_PER;
    unsigned Nt = (unsigned)d_NC[k % 3];
    int base = blockIdx.x * CH;
    int hi = min(base + CH, E_PER);
    hist[tid] = 0;
    __syncthreads();
    for (int i = base + tid; i < hi; i += 256) {
        unsigned b = ((unsigned)dstp[i] << 8) / Nt;
        atomicAdd(&hist[b], 1);
    }
    __syncthreads();
    gb[tid] = hist[tid] ? atomicAdd(&bcursor[k * 256 + tid], hist[tid]) : 0;
    cur[tid] = 0;
    __syncthreads();
    for (int i = base + tid; i < hi; i += 256) {
        int src = srcp[i], dst = dstp[i];
        unsigned b = ((unsigned)dst << 8) / Nt;
        int r = atomicAdd(&cur[b], 1);
        binned[(size_t)gb[b] + r] = make_int2(src, dst);
    }
}

__global__ __launch_bounds__(256) void fine_fill(const int2* __restrict__ binned,
                                                 const int* __restrict__ bbase,
                                                 int* __restrict__ rowstart,
                                                 int* __restrict__ ssrc) {
    __shared__ int rcnt[784];
    __shared__ int excl[784];
    __shared__ int scur[784];
    __shared__ int sb[256];
    int k = blockIdx.y, b = blockIdx.x, tid = threadIdx.x;
    int Nt = d_NC[k % 3];
    int segb = d_SEGB[k];
    int row_lo = (b * Nt + 255) >> 8;
    int row_hi = ((b + 1) * Nt + 255) >> 8;
    int nrows = row_hi - row_lo;
    int ebase = bbase[k * 256 + b];
    int eend  = bbase[k * 256 + b + 1];
    for (int i = tid; i < nrows; i += 256) rcnt[i] = 0;
    __syncthreads();
    for (int e = ebase + tid; e < eend; e += 256)
        atomicAdd(&rcnt[binned[e].y - row_lo], 1);
    __syncthreads();
    int stride = (nrows + 255) >> 8;
    int lo = tid * stride;
    int hi2 = min(lo + stride, nrows);
    int s = 0;
    for (int i = lo; i < hi2; ++i) s += rcnt[i];
    sb[tid] = s; __syncthreads();
    int v = s;
    for (int off = 1; off < 256; off <<= 1) {
        int u = (tid >= off) ? sb[tid - off] : 0;
        __syncthreads();
        sb[tid] += u;
        __syncthreads();
    }
    int pre = sb[tid] - v;
    for (int i = lo; i < hi2; ++i) {
        excl[i] = pre;
        scur[i] = pre;
        pre += rcnt[i];
    }
    __syncthreads();
    for (int i = tid; i < nrows; i += 256)
        rowstart[segb + row_lo + i] = ebase + excl[i];
    if (k == 8 && b == 255 && tid == 0) rowstart[TOT_ROWS] = eend;
    for (int e = ebase + tid; e < eend; e += 256) {
        int2 ed = binned[e];
        int r = atomicAdd(&scur[ed.y - row_lo], 1);
        ssrc[ebase + r] = ed.x;
    }
}

// ----------------------------------------------------- aggregate, all 9 k
// Wave = 4 groups x 16 lanes. Lane: group = lane>>4 (edge slot), cs = lane&15
// (channels cs*8..cs*8+7, f16x8 = 16B). One wave-load gathers 4 source rows;
// 4-way unroll -> 16 edges in flight. Butterfly shfl_xor(16,32) reduces
// groups; lanes 0-15 add (1+eps)*x_t and store one coalesced 256B row.
__global__ __launch_bounds__(256) void aggregate_all(const f16* __restrict__ x16,
                                                     const int* __restrict__ rowstart,
                                                     const int* __restrict__ ssrc,
                                                     char* __restrict__ slabs,
                                                     const float* __restrict__ eps9) {
    __shared__ float part[4][128];
    int g = blockIdx.x;
    int k = 0;
    #pragma unroll
    for (int j = 1; j < 9; ++j) if (g >= d_AOFF[j]) k = j;
    int b = g - d_AOFF[k];
    int s = k / 3, t = k % 3;
    int N = d_NC[t];
    int onerow = (t == 1);
    const int* rs = rowstart + d_SEGB[k];
    const f16* xsrc = x16 + (size_t)d_XB[s] * D;
    const f16* xt   = x16 + (size_t)d_XB[t] * D;
    char* slab = slabs + (size_t)s * SLABSZ + (size_t)d_XB[t] * 256;
    float epsv = 1.0f + eps9[k];
    int tid  = threadIdx.x;
    int lane = tid & 63;
    int w    = tid >> 6;
    int grp  = lane >> 4;
    int cs   = lane & 15;
    int row, estart, estep;
    if (onerow) { row = b; estart = w * 4 + grp; estep = 16; }
    else        { row = (b << 2) + w; estart = grp; estep = 4; }

    float acc[8];
    #pragma unroll
    for (int j = 0; j < 8; ++j) acc[j] = 0.f;

    if (row < N) {
        int e1 = rs[row + 1];
        int e  = rs[row] + estart;
        for (; e + 3 * estep < e1; e += 4 * estep) {
            int s0 = ssrc[e], s1 = ssrc[e + estep], s2 = ssrc[e + 2 * estep], s3 = ssrc[e + 3 * estep];
            f16x8 v0 = ((const f16x8*)(xsrc + (size_t)s0 * D))[cs];
            f16x8 v1 = ((const f16x8*)(xsrc + (size_t)s1 * D))[cs];
            f16x8 v2 = ((const f16x8*)(xsrc + (size_t)s2 * D))[cs];
            f16x8 v3 = ((const f16x8*)(xsrc + (size_t)s3 * D))[cs];
            #pragma unroll
            for (int j = 0; j < 8; ++j)
                acc[j] += ((float)v0[j] + (float)v1[j]) + ((float)v2[j] + (float)v3[j]);
        }
        for (; e < e1; e += estep) {
            int s0 = ssrc[e];
            f16x8 v0 = ((const f16x8*)(xsrc + (size_t)s0 * D))[cs];
            #pragma unroll
            for (int j = 0; j < 8; ++j) acc[j] += (float)v0[j];
        }
    }
    // cross-group reduce (all lanes end with the group-sum for their cs)
    #pragma unroll
    for (int j = 0; j < 8; ++j) {
        acc[j] += __shfl_xor(acc[j], 16);
        acc[j] += __shfl_xor(acc[j], 32);
    }
    if (onerow) {
        if (lane < 16) {
            #pragma unroll
            for (int j = 0; j < 8; ++j) part[w][cs * 8 + j] = acc[j];
        }
        __syncthreads();
        if (w == 0 && lane < 16 && row < N) {
            f16x8 xv = ((const f16x8*)(xt + (size_t)row * D))[cs];
            f16x8 h;
            #pragma unroll
            for (int j = 0; j < 8; ++j) {
                float v = (part[0][cs*8+j] + part[1][cs*8+j]) + (part[2][cs*8+j] + part[3][cs*8+j]);
                h[j] = (f16)(v + epsv * (float)xv[j]);
            }
            ((f16x8*)(slab + (size_t)row * 256))[cs] = h;
        }
    } else if (row < N && lane < 16) {
        f16x8 xv = ((const f16x8*)(xt + (size_t)row * D))[cs];
        f16x8 h;
        #pragma unroll
        for (int j = 0; j < 8; ++j) h[j] = (f16)(acc[j] + epsv * (float)xv[j]);
        ((f16x8*)(slab + (size_t)row * 256))[cs] = h;
    }
}

// -------------------------------------------------------------- layer-1 GEMM
// grid (1744, 3): x = global tile (t mapped), y = s.
__global__ __launch_bounds__(256) void gemm_l1(char* __restrict__ slabs,
                                               const f16* __restrict__ Wth,
                                               const float* __restrict__ bias,
                                               float* __restrict__ partials) {
    __shared__ alignas(16) char atile[128 * 256];
    __shared__ float wst[4][256];
    const int tid  = threadIdx.x;
    const int lane = tid & 63;
    const int w    = tid >> 6;
    const int s    = blockIdx.y;
    int t, tl;
    tile_map(blockIdx.x, t, tl);
    const int N = d_NC[t];
    const int row0 = tl * 128;
    char* slab = slabs + (size_t)s * SLABSZ + (size_t)d_XB[t] * 256;

    #pragma unroll
    for (int p = 0; p < 8; ++p) {
        int r  = p * 16 + (tid >> 4);
        int c8 = tid & 15;
        int row = row0 + r;
        if (row >= N) row = N - 1;   // clamp: garbage rows masked in epilogue
        const char* src = slab + (size_t)row * 256 + (unsigned)((c8 * 16) ^ ((r & 7) << 4));
        __builtin_amdgcn_global_load_lds(
            (const __attribute__((address_space(1))) void*)src,
            (__attribute__((address_space(3))) void*)(atile + p * 4096 + w * 1024),
            16, 0, 0);
    }
    __syncthreads();

    const f16* Wt = Wth + (size_t)s * 16384;
    f32x4 acc0[8], acc1[8];
    #pragma unroll
    for (int ct = 0; ct < 8; ++ct) {
        acc0[ct] = (f32x4){0.f, 0.f, 0.f, 0.f};
        acc1[ct] = (f32x4){0.f, 0.f, 0.f, 0.f};
    }
    const int arow0 = (w << 5) + (lane & 15);
    const int arow1 = arow0 + 16;
    const int kq = (lane >> 4) * 8;
    #pragma unroll
    for (int ks = 0; ks < 4; ++ks) {
        f16x8 af0 = *(const f16x8*)(atile + a_swz(arow0, (ks * 32 + kq) * 2));
        f16x8 af1 = *(const f16x8*)(atile + a_swz(arow1, (ks * 32 + kq) * 2));
        #pragma unroll
        for (int ct = 0; ct < 8; ++ct) {
            f16x8 bf = *(const f16x8*)(Wt + (size_t)(ct * 16 + (lane & 15)) * D + ks * 32 + kq);
            acc0[ct] = __builtin_amdgcn_mfma_f32_16x16x32_f16(af0, bf, acc0[ct], 0, 0, 0);
            acc1[ct] = __builtin_amdgcn_mfma_f32_16x16x32_f16(af1, bf, acc1[ct], 0, 0, 0);
        }
    }

    // epilogue: stats + z->LDS (wave-local rows: no barrier needed before)
    const int col_lo = lane & 15;
    const int lrb0 = (w << 5) + ((lane >> 4) << 2);
    #pragma unroll
    for (int ct = 0; ct < 8; ++ct) {
        int col = ct * 16 + col_lo;
        float bv = bias[s * D + col];
        float s_ = 0.f, q_ = 0.f;
        #pragma unroll
        for (int r = 0; r < 4; ++r) {
            int lrow = lrb0 + r;
            float val = acc0[ct][r] + bv;
            if (row0 + lrow < N) { s_ += val; q_ += val * val; }
            *(f16*)(atile + a_swz(lrow, col * 2)) = (f16)val;
        }
        #pragma unroll
        for (int r = 0; r < 4; ++r) {
            int lrow = lrb0 + 16 + r;
            float val = acc1[ct][r] + bv;
            if (row0 + lrow < N) { s_ += val; q_ += val * val; }
            *(f16*)(atile + a_swz(lrow, col * 2)) = (f16)val;
        }
        s_ += __shfl_xor(s_, 16); q_ += __shfl_xor(q_, 16);
        s_ += __shfl_xor(s_, 32); q_ += __shfl_xor(q_, 32);
        if (lane < 16) { wst[w][col] = s_; wst[w][128 + col] = q_; }
    }
    __syncthreads();

    // coalesced writeback (16B/lane)
    #pragma unroll
    for (int p = 0; p < 8; ++p) {
        int r  = p * 16 + (tid >> 4);
        int c8 = tid & 15;
        int row = row0 + r;
        if (row < N)
            *(f16x8*)(slab + (size_t)row * 256 + c8 * 16) = *(const f16x8*)(atile + a_swz(r, c8 * 16));
    }
    float pv = wst[0][tid] + wst[1][tid] + wst[2][tid] + wst[3][tid];
    partials[((size_t)blockIdx.x * 3 + s) * 256 + tid] = pv;
}

// -------------------------------------------------------------- layer-2 GEMM
__global__ __launch_bounds__(256) void gemm_l2(char* __restrict__ slabs,
                                               const f16* __restrict__ Wth2,
                                               const float* __restrict__ bias,
                                               const float* __restrict__ affa,
                                               const float* __restrict__ affc,
                                               float* __restrict__ partials) {
    __shared__ alignas(16) char atile[128 * 256];
    __shared__ float wst[4][256];
    const int tid  = threadIdx.x;
    const int lane = tid & 63;
    const int w    = tid >> 6;
    const int s    = blockIdx.y;
    int t, tl;
    tile_map(blockIdx.x, t, tl);
    const int N = d_NC[t];
    const int row0 = tl * 128;
    const int k = s * 3 + t;
    char* slab = slabs + (size_t)s * SLABSZ + (size_t)d_XB[t] * 256;
    const int c8 = tid & 15;

    // hoisted affine params for this thread's 8 columns
    f32x4 a0 = ((const f32x4*)(affa + k * 128))[c8 * 2];
    f32x4 a1 = ((const f32x4*)(affa + k * 128))[c8 * 2 + 1];
    f32x4 c0 = ((const f32x4*)(affc + k * 128))[c8 * 2];
    f32x4 c1 = ((const f32x4*)(affc + k * 128))[c8 * 2 + 1];

    // T14 split: issue all loads, then transform + LDS write
    f16x8 zv[8];
    #pragma unroll
    for (int p = 0; p < 8; ++p) {
        int r = p * 16 + (tid >> 4);
        int row = row0 + r;
        zv[p] = (row < N) ? ((const f16x8*)(slab + (size_t)row * 256))[c8]
                          : (f16x8){0, 0, 0, 0, 0, 0, 0, 0};
    }
    #pragma unroll
    for (int p = 0; p < 8; ++p) {
        int r = p * 16 + (tid >> 4);
        f16x8 hv;
        #pragma unroll
        for (int j = 0; j < 4; ++j) {
            float t0 = (float)zv[p][j] * a0[j] + c0[j];
            float t1 = (float)zv[p][4 + j] * a1[j] + c1[j];
            hv[j]     = (f16)(t0 > 0.f ? t0 : 0.f);
            hv[4 + j] = (f16)(t1 > 0.f ? t1 : 0.f);
        }
        *(f16x8*)(atile + a_swz(r, c8 * 16)) = hv;
    }
    __syncthreads();

    const f16* Wt = Wth2 + (size_t)s * 16384;
    f32x4 acc0[8], acc1[8];
    #pragma unroll
    for (int ct = 0; ct < 8; ++ct) {
        acc0[ct] = (f32x4){0.f, 0.f, 0.f, 0.f};
        acc1[ct] = (f32x4){0.f, 0.f, 0.f, 0.f};
    }
    const int arow0 = (w << 5) + (lane & 15);
    const int arow1 = arow0 + 16;
    const int kq = (lane >> 4) * 8;
    #pragma unroll
    for (int ks = 0; ks < 4; ++ks) {
        f16x8 af0 = *(const f16x8*)(atile + a_swz(arow0, (ks * 32 + kq) * 2));
        f16x8 af1 = *(const f16x8*)(atile + a_swz(arow1, (ks * 32 + kq) * 2));
        #pragma unroll
        for (int ct = 0; ct < 8; ++ct) {
            f16x8 bf = *(const f16x8*)(Wt + (size_t)(ct * 16 + (lane & 15)) * D + ks * 32 + kq);
            acc0[ct] = __builtin_amdgcn_mfma_f32_16x16x32_f16(af0, bf, acc0[ct], 0, 0, 0);
            acc1[ct] = __builtin_amdgcn_mfma_f32_16x16x32_f16(af1, bf, acc1[ct], 0, 0, 0);
        }
    }

    const int col_lo = lane & 15;
    const int lrb0 = (w << 5) + ((lane >> 4) << 2);
    #pragma unroll
    for (int ct = 0; ct < 8; ++ct) {
        int col = ct * 16 + col_lo;
        float bv = bias[s * D + col];
        float s_ = 0.f, q_ = 0.f;
        #pragma unroll
        for (int r = 0; r < 4; ++r) {
            int lrow = lrb0 + r;
            float val = acc0[ct][r] + bv;
            if (row0 + lrow < N) { s_ += val; q_ += val * val; }
            *(f16*)(atile + a_swz(lrow, col * 2)) = (f16)val;
        }
        #pragma unroll
        for (int r = 0; r < 4; ++r) {
            int lrow = lrb0 + 16 + r;
            float val = acc1[ct][r] + bv;
            if (row0 + lrow < N) { s_ += val; q_ += val * val; }
            *(f16*)(atile + a_swz(lrow, col * 2)) = (f16)val;
        }
        s_ += __shfl_xor(s_, 16); q_ += __shfl_xor(q_, 16);
        s_ += __shfl_xor(s_, 32); q_ += __shfl_xor(q_, 32);
        if (lane < 16) { wst[w][col] = s_; wst[w][128 + col] = q_; }
    }
    __syncthreads();

    #pragma unroll
    for (int p = 0; p < 8; ++p) {
        int r = p * 16 + (tid >> 4);
        int row = row0 + r;
        if (row < N)
            *(f16x8*)(slab + (size_t)row * 256 + c8 * 16) = *(const f16x8*)(atile + a_swz(r, c8 * 16));
    }
    float pv = wst[0][tid] + wst[1][tid] + wst[2][tid] + wst[3][tid];
    partials[((size_t)blockIdx.x * 3 + s) * 256 + tid] = pv;
}

// ------------------------------------------------- fused stats -> BN affine
// 9 blocks: blockIdx.x = k = s*3 + t. aff arrays are [9][128].
__global__ void bn_fuse(const float* __restrict__ partials,
                        const float* __restrict__ g, const float* __restrict__ be,
                        float* __restrict__ affa, float* __restrict__ affc) {
    __shared__ float red[256];
    int k = blockIdx.x, tid = threadIdx.x;
    int s = k / 3, t = k % 3;
    int lo = d_TLO[t], hi = d_THI[t];
    float v = 0.f;
    #pragma unroll 4
    for (int b = lo; b < hi; ++b)
        v += partials[((size_t)b * 3 + s) * 256 + tid];
    red[tid] = v;
    __syncthreads();
    if (tid < 128) {
        float sm = red[tid], q = red[128 + tid];
        float n = (float)d_NC[t];
        float mean = sm / n;
        float var  = q / n - mean * mean;
        float a = g[s * D + tid] * rsqrtf(var + 1e-5f);
        affa[k * 128 + tid] = a;
        affc[k * 128 + tid] = be[s * D + tid] - mean * a;
    }
}

// -------------------------------------------------- final accum, all rows
__global__ __launch_bounds__(256) void accum_all(const char* __restrict__ slabs,
                                                 const float* __restrict__ affa,
                                                 const float* __restrict__ affc,
                                                 float* __restrict__ outp) {
    const int total = 223000 * 16;
    for (int i = blockIdx.x * 256 + threadIdx.x; i < total; i += gridDim.x * 256) {
        int row = i >> 4;
        int c8  = i & 15;
        int t = (row < 200000) ? 0 : (row < 203000) ? 1 : 2;
        f32x4 o0 = {0.f, 0.f, 0.f, 0.f}, o1 = {0.f, 0.f, 0.f, 0.f};
        #pragma unroll
        for (int s = 0; s < 3; ++s) {
            int k = s * 3 + t;
            f16x8 z = ((const f16x8*)(slabs + (size_t)s * SLABSZ + (size_t)row * 256))[c8];
            f32x4 a0 = ((const f32x4*)(affa + k * 128))[c8 * 2];
            f32x4 a1 = ((const f32x4*)(affa + k * 128))[c8 * 2 + 1];
            f32x4 c0 = ((const f32x4*)(affc + k * 128))[c8 * 2];
            f32x4 c1 = ((const f32x4*)(affc + k * 128))[c8 * 2 + 1];
            #pragma unroll
            for (int j = 0; j < 4; ++j) {
                float t0 = (float)z[j] * a0[j] + c0[j];
                float t1 = (float)z[4 + j] * a1[j] + c1[j];
                o0[j] += t0 > 0.f ? t0 : 0.f;
                o1[j] += t1 > 0.f ? t1 : 0.f;
            }
        }
        ((f32x4*)(outp + (size_t)row * D))[c8 * 2]     = o0;
        ((f32x4*)(outp + (size_t)row * D))[c8 * 2 + 1] = o1;
    }
}

extern "C" void kernel_launch(void* const* d_in, const int* in_sizes, int n_in,
                              void* d_out, int out_size, void* d_ws, size_t ws_size,
                              hipStream_t stream) {
    const float* x0  = (const float*)d_in[0];
    const float* x1  = (const float*)d_in[1];
    const float* x2  = (const float*)d_in[2];
    const int*   ei  = (const int*)d_in[3];
    const float* W1  = (const float*)d_in[4];
    const float* b1  = (const float*)d_in[5];
    const float* g1  = (const float*)d_in[6];
    const float* be1 = (const float*)d_in[7];
    const float* W2  = (const float*)d_in[8];
    const float* b2  = (const float*)d_in[9];
    const float* g2  = (const float*)d_in[10];
    const float* be2 = (const float*)d_in[11];
    const float* eps9 = (const float*)d_in[12];
    float* outp = (float*)d_out;

    char* ws = (char*)d_ws;
    size_t off = 0;
    char* slabs = ws;                 off += 3 * SLABSZ;                   // 171.3 MB
    int2* binned = (int2*)slabs;      // 36 MB alias, consumed before slabs written
    f16* x16    = (f16*)(ws + off);   off += SLABSZ;                       // 57.1 MB
    int* ssrc   = (int*)(ws + off);   off += (size_t)9 * E_PER * 4;        // 18 MB
    int* rowstart = (int*)(ws + off); off += (size_t)(TOT_ROWS + 2) * 4;
    off = (off + 255) & ~(size_t)255;
    int* bcnt   = (int*)(ws + off);   off += 2308 * 4;
    int* bbase  = (int*)(ws + off);   off += 2308 * 4;
    int* bcursor= (int*)(ws + off);   off += 2308 * 4;
    off = (off + 255) & ~(size_t)255;
    float* partials = (float*)(ws + off); off += (size_t)1744 * 3 * 256 * 4;
    float* aff1a = (float*)(ws + off); off += 9 * 128 * 4;
    float* aff1c = (float*)(ws + off); off += 9 * 128 * 4;
    float* aff2a = (float*)(ws + off); off += 9 * 128 * 4;
    float* aff2c = (float*)(ws + off); off += 9 * 128 * 4;
    f16* Wth = (f16*)(ws + off); off += (size_t)2 * 3 * 128 * 128 * sizeof(f16);

    // ---- setup
    precast<<<384, 256, 0, stream>>>(W1, W2, Wth);
    cast16_all<<<2048, 256, 0, stream>>>(x0, x1, x2, x16);

    // ---- CSR build via LDS-binned counting sort (all 9 types)
    hipMemsetAsync(bcnt, 0, 2308 * 4, stream);
    int nchunk = (E_PER + CH - 1) / CH;   // 123
    bucket_count<<<dim3(nchunk, 9), 256, 0, stream>>>(ei, bcnt);
    bucket_scan<<<1, 256, 0, stream>>>(bcnt, bbase, bcursor);
    bin_scatter<<<dim3(nchunk, 9), 256, 0, stream>>>(ei, bcursor, binned);
    fine_fill<<<dim3(256, 9), 256, 0, stream>>>(binned, bbase, rowstart, ssrc);

    // ---- fully batched pipeline (all 9 (s,t) at once)
    aggregate_all<<<174000, 256, 0, stream>>>(x16, rowstart, ssrc, slabs, eps9);

    gemm_l1<<<dim3(1744, 3), 256, 0, stream>>>(slabs, Wth, b1, partials);
    bn_fuse<<<9, 256, 0, stream>>>(partials, g1, be1, aff1a, aff1c);

    gemm_l2<<<dim3(1744, 3), 256, 0, stream>>>(slabs, Wth + 3 * 16384, b2,
                                               aff1a, aff1c, partials);
    bn_fuse<<<9, 256, 0, stream>>>(partials, g2, be2, aff2a, aff2c);

    accum_all<<<4096, 256, 0, stream>>>(slabs, aff2a, aff2c, outp);
}

// Round 10
// 856.750 us; speedup vs baseline: 8.2406x; 1.1164x over previous
//
#include <hip/hip_runtime.h>
#include <hip/hip_fp16.h>

#define D 128
#define E_PER 500000
#define TOT_ROWS 669000
#define CH 4096
#define SLABSZ ((size_t)223000 * 256)

typedef _Float16 f16;
typedef _Float16 f16x8 __attribute__((ext_vector_type(8)));
typedef _Float16 f16x4 __attribute__((ext_vector_type(4)));
typedef _Float16 f16x2 __attribute__((ext_vector_type(2)));
typedef float f32x4 __attribute__((ext_vector_type(4)));

// Per-edge-type row-segment bases in the concatenated CSR arrays (k = s*3 + t).
__device__ const int d_SEGB[9] = {0, 200000, 203000, 223000, 423000, 426000,
                                  446000, 646000, 649000};
__device__ const int d_XB[3] = {0, 200000, 203000};
__device__ const int d_NC[3] = {200000, 3000, 20000};
// gemm tile ranges per t (128-row tiles): t0 1563, t1 24, t2 157
__device__ const int d_TLO[3] = {0, 1563, 1587};
__device__ const int d_THI[3] = {1563, 1587, 1744};
// aggregate block offsets per k: t0/t2 = 16 rows/block (group-per-row);
// t1 = 1 row/block (16 edge slots)
__device__ const int d_AOFF[10] = {0, 12500, 15500, 16750, 29250, 32250,
                                   33500, 46000, 49000, 50250};

// XOR swizzle for the A tile in LDS (row stride 256B f16).
__device__ __forceinline__ unsigned a_swz(int row, int byteoff) {
    return (unsigned)(row * 256 + byteoff) ^ (unsigned)((row & 7) << 4);
}

// map global gemm tile -> (t, local tile)
__device__ __forceinline__ void tile_map(int g, int& t, int& tl) {
    if (g < 1563)      { t = 0; tl = g; }
    else if (g < 1587) { t = 1; tl = g - 1563; }
    else               { t = 2; tl = g - 1587; }
}

// ---------------------------------------------------------------- precast W^T
__global__ void precast(const float* __restrict__ W1,
                        const float* __restrict__ W2,
                        f16* __restrict__ Wth) {
    int i = blockIdx.x * 256 + threadIdx.x;
    if (i >= 2 * 3 * 128 * 128) return;
    int layer = i / 49152;
    int rem = i - layer * 49152;
    int s = rem / 16384;
    int r2 = rem & 16383;
    int kk = r2 >> 7;
    int c  = r2 & 127;
    const float* W = layer ? W2 : W1;
    Wth[(((size_t)layer * 3 + s) * 128 + c) * 128 + kk] = (f16)W[((size_t)s * 128 + kk) * 128 + c];
}

// ------------------------------------------------------- all x -> f16 table
__global__ void cast16_all(const float* __restrict__ x0,
                           const float* __restrict__ x1,
                           const float* __restrict__ x2,
                           f16* __restrict__ y) {
    const int total = 223000 * 16;
    for (int i = blockIdx.x * 256 + threadIdx.x; i < total; i += gridDim.x * 256) {
        int row = i >> 4, c8 = i & 15;
        const float* src;
        if (row < 200000)      src = x0 + (size_t)row * D;
        else if (row < 203000) src = x1 + (size_t)(row - 200000) * D;
        else                   src = x2 + (size_t)(row - 203000) * D;
        f32x4 v0 = ((const f32x4*)src)[c8 * 2];
        f32x4 v1 = ((const f32x4*)src)[c8 * 2 + 1];
        f16x8 h;
        #pragma unroll
        for (int j = 0; j < 4; ++j) { h[j] = (f16)v0[j]; h[4 + j] = (f16)v1[j]; }
        ((f16x8*)(y + (size_t)row * D))[c8] = h;
    }
}

// ============================================================ CSR via 2-pass
__global__ __launch_bounds__(256) void bucket_count(const int* __restrict__ ei,
                                                    int* __restrict__ bcnt) {
    __shared__ int hist[256];
    int k = blockIdx.y, tid = threadIdx.x;
    const int* dstp = ei + (size_t)k * 2 * E_PER + E_PER;
    unsigned Nt = (unsigned)d_NC[k % 3];
    int base = blockIdx.x * CH;
    int hi = min(base + CH, E_PER);
    hist[tid] = 0;
    __syncthreads();
    for (int i = base + tid; i < hi; i += 256) {
        unsigned b = ((unsigned)dstp[i] << 8) / Nt;
        atomicAdd(&hist[b], 1);
    }
    __syncthreads();
    if (hist[tid]) atomicAdd(&bcnt[k * 256 + tid], hist[tid]);
}

__global__ void bucket_scan(const int* __restrict__ bcnt,
                            int* __restrict__ bbase, int* __restrict__ bcursor) {
    __shared__ int sb[256];
    int t = threadIdx.x;
    int loc[9];
    int s = 0;
    #pragma unroll
    for (int j = 0; j < 9; ++j) { loc[j] = bcnt[t * 9 + j]; s += loc[j]; }
    sb[t] = s; __syncthreads();
    int v = s;
    for (int off = 1; off < 256; off <<= 1) {
        int u = (t >= off) ? sb[t - off] : 0;
        __syncthreads();
        sb[t] += u;
        __syncthreads();
    }
    int pre = sb[t] - v;
    #pragma unroll
    for (int j = 0; j < 9; ++j) {
        bbase[t * 9 + j] = pre;
        bcursor[t * 9 + j] = pre;
        pre += loc[j];
    }
    if (t == 255) bbase[2304] = pre;
}

__global__ __launch_bounds__(256) void bin_scatter(const int* __restrict__ ei,
                                                   int* __restrict__ bcursor,
                                                   int2* __restrict__ binned) {
    __shared__ int hist[256], gb[256], cur[256];
    int k = blockIdx.y, tid = threadIdx.x;
    const int* srcp = ei + (size_t)k * 2 * E_PER;
    const int* dstp = srcp + E_PER;
    unsigned Nt = (unsigned)d_NC[k % 3];
    int base = blockIdx.x * CH;
    int hi = min(base + CH, E_PER);
    hist[tid] = 0;
    __syncthreads();
    for (int i = base + tid; i < hi; i += 256) {
        unsigned b = ((unsigned)dstp[i] << 8) / Nt;
        atomicAdd(&hist[b], 1);
    }
    __syncthreads();
    gb[tid] = hist[tid] ? atomicAdd(&bcursor[k * 256 + tid], hist[tid]) : 0;
    cur[tid] = 0;
    __syncthreads();
    for (int i = base + tid; i < hi; i += 256) {
        int src = srcp[i], dst = dstp[i];
        unsigned b = ((unsigned)dst << 8) / Nt;
        int r = atomicAdd(&cur[b], 1);
        binned[(size_t)gb[b] + r] = make_int2(src, dst);
    }
}

__global__ __launch_bounds__(256) void fine_fill(const int2* __restrict__ binned,
                                                 const int* __restrict__ bbase,
                                                 int* __restrict__ rowstart,
                                                 int* __restrict__ ssrc) {
    __shared__ int rcnt[784];
    __shared__ int excl[784];
    __shared__ int scur[784];
    __shared__ int sb[256];
    int k = blockIdx.y, b = blockIdx.x, tid = threadIdx.x;
    int Nt = d_NC[k % 3];
    int segb = d_SEGB[k];
    int row_lo = (b * Nt + 255) >> 8;
    int row_hi = ((b + 1) * Nt + 255) >> 8;
    int nrows = row_hi - row_lo;
    int ebase = bbase[k * 256 + b];
    int eend  = bbase[k * 256 + b + 1];
    for (int i = tid; i < nrows; i += 256) rcnt[i] = 0;
    __syncthreads();
    for (int e = ebase + tid; e < eend; e += 256)
        atomicAdd(&rcnt[binned[e].y - row_lo], 1);
    __syncthreads();
    int stride = (nrows + 255) >> 8;
    int lo = tid * stride;
    int hi2 = min(lo + stride, nrows);
    int s = 0;
    for (int i = lo; i < hi2; ++i) s += rcnt[i];
    sb[tid] = s; __syncthreads();
    int v = s;
    for (int off = 1; off < 256; off <<= 1) {
        int u = (tid >= off) ? sb[tid - off] : 0;
        __syncthreads();
        sb[tid] += u;
        __syncthreads();
    }
    int pre = sb[tid] - v;
    for (int i = lo; i < hi2; ++i) {
        excl[i] = pre;
        scur[i] = pre;
        pre += rcnt[i];
    }
    __syncthreads();
    for (int i = tid; i < nrows; i += 256)
        rowstart[segb + row_lo + i] = ebase + excl[i];
    if (k == 8 && b == 255 && tid == 0) rowstart[TOT_ROWS] = eend;
    for (int e = ebase + tid; e < eend; e += 256) {
        int2 ed = binned[e];
        int r = atomicAdd(&scur[ed.y - row_lo], 1);
        ssrc[ebase + r] = ed.x;
    }
}

// ----------------------------------------------------- aggregate, all 9 k
// t=0/t=2 (low degree): group-per-row. 16-lane group covers all 128 channels
// (f16x8/lane); each group owns one dst row: acc = (1+eps)*x_t, then serial
// gather of its edge list with 4-wide ILP, one coalesced 256B store.
// No shfl, no LDS. 16 rows/block.
// t=1 (deg~500): 16 edge slots (4 waves x 4 groups), butterfly + LDS combine.
__global__ __launch_bounds__(256) void aggregate_all(const f16* __restrict__ x16,
                                                     const int* __restrict__ rowstart,
                                                     const int* __restrict__ ssrc,
                                                     char* __restrict__ slabs,
                                                     const float* __restrict__ eps9) {
    __shared__ float part[4][128];
    int g = blockIdx.x;
    int k = 0;
    #pragma unroll
    for (int j = 1; j < 9; ++j) if (g >= d_AOFF[j]) k = j;
    int b = g - d_AOFF[k];
    int s = k / 3, t = k % 3;
    int N = d_NC[t];
    const int* rs = rowstart + d_SEGB[k];
    const f16* xsrc = x16 + (size_t)d_XB[s] * D;
    const f16* xt   = x16 + (size_t)d_XB[t] * D;
    char* slab = slabs + (size_t)s * SLABSZ + (size_t)d_XB[t] * 256;
    float epsv = 1.0f + eps9[k];
    int tid  = threadIdx.x;
    int lane = tid & 63;
    int w    = tid >> 6;
    int grp  = lane >> 4;
    int cs   = lane & 15;

    if (t != 1) {
        // ---- group-per-row (low degree)
        int row = (b << 4) + (tid >> 4);
        if (row >= N) return;          // exact grids; no barrier in this path
        int e0 = rs[row], e1 = rs[row + 1];
        f16x8 xv = ((const f16x8*)(xt + (size_t)row * D))[cs];
        float acc[8];
        #pragma unroll
        for (int j = 0; j < 8; ++j) acc[j] = epsv * (float)xv[j];
        int e = e0;
        for (; e + 3 < e1; e += 4) {
            int s0 = ssrc[e], s1 = ssrc[e + 1], s2 = ssrc[e + 2], s3 = ssrc[e + 3];
            f16x8 v0 = ((const f16x8*)(xsrc + (size_t)s0 * D))[cs];
            f16x8 v1 = ((const f16x8*)(xsrc + (size_t)s1 * D))[cs];
            f16x8 v2 = ((const f16x8*)(xsrc + (size_t)s2 * D))[cs];
            f16x8 v3 = ((const f16x8*)(xsrc + (size_t)s3 * D))[cs];
            #pragma unroll
            for (int j = 0; j < 8; ++j)
                acc[j] += ((float)v0[j] + (float)v1[j]) + ((float)v2[j] + (float)v3[j]);
        }
        if (e + 1 < e1) {
            int s0 = ssrc[e], s1 = ssrc[e + 1];
            f16x8 v0 = ((const f16x8*)(xsrc + (size_t)s0 * D))[cs];
            f16x8 v1 = ((const f16x8*)(xsrc + (size_t)s1 * D))[cs];
            #pragma unroll
            for (int j = 0; j < 8; ++j) acc[j] += (float)v0[j] + (float)v1[j];
            e += 2;
        }
        if (e < e1) {
            int s0 = ssrc[e];
            f16x8 v0 = ((const f16x8*)(xsrc + (size_t)s0 * D))[cs];
            #pragma unroll
            for (int j = 0; j < 8; ++j) acc[j] += (float)v0[j];
        }
        f16x8 h;
        #pragma unroll
        for (int j = 0; j < 8; ++j) h[j] = (f16)acc[j];
        ((f16x8*)(slab + (size_t)row * 256))[cs] = h;
    } else {
        // ---- high degree: 16 edge slots, butterfly + LDS combine
        int row = b;
        int estart = w * 4 + grp, estep = 16;
        float acc[8];
        #pragma unroll
        for (int j = 0; j < 8; ++j) acc[j] = 0.f;
        int e1 = rs[row + 1];
        int e  = rs[row] + estart;
        for (; e + 3 * estep < e1; e += 4 * estep) {
            int s0 = ssrc[e], s1 = ssrc[e + estep], s2 = ssrc[e + 2 * estep], s3 = ssrc[e + 3 * estep];
            f16x8 v0 = ((const f16x8*)(xsrc + (size_t)s0 * D))[cs];
            f16x8 v1 = ((const f16x8*)(xsrc + (size_t)s1 * D))[cs];
            f16x8 v2 = ((const f16x8*)(xsrc + (size_t)s2 * D))[cs];
            f16x8 v3 = ((const f16x8*)(xsrc + (size_t)s3 * D))[cs];
            #pragma unroll
            for (int j = 0; j < 8; ++j)
                acc[j] += ((float)v0[j] + (float)v1[j]) + ((float)v2[j] + (float)v3[j]);
        }
        for (; e < e1; e += estep) {
            int s0 = ssrc[e];
            f16x8 v0 = ((const f16x8*)(xsrc + (size_t)s0 * D))[cs];
            #pragma unroll
            for (int j = 0; j < 8; ++j) acc[j] += (float)v0[j];
        }
        #pragma unroll
        for (int j = 0; j < 8; ++j) {
            acc[j] += __shfl_xor(acc[j], 16);
            acc[j] += __shfl_xor(acc[j], 32);
        }
        if (lane < 16) {
            #pragma unroll
            for (int j = 0; j < 8; ++j) part[w][cs * 8 + j] = acc[j];
        }
        __syncthreads();
        if (w == 0 && lane < 16) {
            f16x8 xv = ((const f16x8*)(xt + (size_t)row * D))[cs];
            f16x8 h;
            #pragma unroll
            for (int j = 0; j < 8; ++j) {
                float v = (part[0][cs*8+j] + part[1][cs*8+j]) + (part[2][cs*8+j] + part[3][cs*8+j]);
                h[j] = (f16)(v + epsv * (float)xv[j]);
            }
            ((f16x8*)(slab + (size_t)row * 256))[cs] = h;
        }
    }
}

// -------------------------------------------------------------- layer-1 GEMM
// grid (1744, 3): x = global tile (t mapped), y = s.
__global__ __launch_bounds__(256) void gemm_l1(char* __restrict__ slabs,
                                               const f16* __restrict__ Wth,
                                               const float* __restrict__ bias,
                                               float* __restrict__ partials) {
    __shared__ alignas(16) char atile[128 * 256];
    __shared__ float wst[4][256];
    const int tid  = threadIdx.x;
    const int lane = tid & 63;
    const int w    = tid >> 6;
    const int s    = blockIdx.y;
    int t, tl;
    tile_map(blockIdx.x, t, tl);
    const int N = d_NC[t];
    const int row0 = tl * 128;
    char* slab = slabs + (size_t)s * SLABSZ + (size_t)d_XB[t] * 256;

    #pragma unroll
    for (int p = 0; p < 8; ++p) {
        int r  = p * 16 + (tid >> 4);
        int c8 = tid & 15;
        int row = row0 + r;
        if (row >= N) row = N - 1;   // clamp: garbage rows masked in epilogue
        const char* src = slab + (size_t)row * 256 + (unsigned)((c8 * 16) ^ ((r & 7) << 4));
        __builtin_amdgcn_global_load_lds(
            (const __attribute__((address_space(1))) void*)src,
            (__attribute__((address_space(3))) void*)(atile + p * 4096 + w * 1024),
            16, 0, 0);
    }
    __syncthreads();

    const f16* Wt = Wth + (size_t)s * 16384;
    f32x4 acc0[8], acc1[8];
    #pragma unroll
    for (int ct = 0; ct < 8; ++ct) {
        acc0[ct] = (f32x4){0.f, 0.f, 0.f, 0.f};
        acc1[ct] = (f32x4){0.f, 0.f, 0.f, 0.f};
    }
    const int arow0 = (w << 5) + (lane & 15);
    const int arow1 = arow0 + 16;
    const int kq = (lane >> 4) * 8;
    #pragma unroll
    for (int ks = 0; ks < 4; ++ks) {
        f16x8 af0 = *(const f16x8*)(atile + a_swz(arow0, (ks * 32 + kq) * 2));
        f16x8 af1 = *(const f16x8*)(atile + a_swz(arow1, (ks * 32 + kq) * 2));
        #pragma unroll
        for (int ct = 0; ct < 8; ++ct) {
            f16x8 bf = *(const f16x8*)(Wt + (size_t)(ct * 16 + (lane & 15)) * D + ks * 32 + kq);
            acc0[ct] = __builtin_amdgcn_mfma_f32_16x16x32_f16(af0, bf, acc0[ct], 0, 0, 0);
            acc1[ct] = __builtin_amdgcn_mfma_f32_16x16x32_f16(af1, bf, acc1[ct], 0, 0, 0);
        }
    }

    // epilogue: stats + z->LDS (wave-local rows: no barrier needed before)
    const int col_lo = lane & 15;
    const int lrb0 = (w << 5) + ((lane >> 4) << 2);
    #pragma unroll
    for (int ct = 0; ct < 8; ++ct) {
        int col = ct * 16 + col_lo;
        float bv = bias[s * D + col];
        float s_ = 0.f, q_ = 0.f;
        #pragma unroll
        for (int r = 0; r < 4; ++r) {
            int lrow = lrb0 + r;
            float val = acc0[ct][r] + bv;
            if (row0 + lrow < N) { s_ += val; q_ += val * val; }
            *(f16*)(atile + a_swz(lrow, col * 2)) = (f16)val;
        }
        #pragma unroll
        for (int r = 0; r < 4; ++r) {
            int lrow = lrb0 + 16 + r;
            float val = acc1[ct][r] + bv;
            if (row0 + lrow < N) { s_ += val; q_ += val * val; }
            *(f16*)(atile + a_swz(lrow, col * 2)) = (f16)val;
        }
        s_ += __shfl_xor(s_, 16); q_ += __shfl_xor(q_, 16);
        s_ += __shfl_xor(s_, 32); q_ += __shfl_xor(q_, 32);
        if (lane < 16) { wst[w][col] = s_; wst[w][128 + col] = q_; }
    }
    __syncthreads();

    // coalesced writeback (16B/lane)
    #pragma unroll
    for (int p = 0; p < 8; ++p) {
        int r  = p * 16 + (tid >> 4);
        int c8 = tid & 15;
        int row = row0 + r;
        if (row < N)
            *(f16x8*)(slab + (size_t)row * 256 + c8 * 16) = *(const f16x8*)(atile + a_swz(r, c8 * 16));
    }
    float pv = wst[0][tid] + wst[1][tid] + wst[2][tid] + wst[3][tid];
    partials[((size_t)blockIdx.x * 3 + s) * 256 + tid] = pv;
}

// -------------------------------------------------------------- layer-2 GEMM
__global__ __launch_bounds__(256) void gemm_l2(char* __restrict__ slabs,
                                               const f16* __restrict__ Wth2,
                                               const float* __restrict__ bias,
                                               const float* __restrict__ affa,
                                               const float* __restrict__ affc,
                                               float* __restrict__ partials) {
    __shared__ alignas(16) char atile[128 * 256];
    __shared__ float wst[4][256];
    const int tid  = threadIdx.x;
    const int lane = tid & 63;
    const int w    = tid >> 6;
    const int s    = blockIdx.y;
    int t, tl;
    tile_map(blockIdx.x, t, tl);
    const int N = d_NC[t];
    const int row0 = tl * 128;
    const int k = s * 3 + t;
    char* slab = slabs + (size_t)s * SLABSZ + (size_t)d_XB[t] * 256;
    const int c8 = tid & 15;

    // hoisted affine params for this thread's 8 columns
    f32x4 a0 = ((const f32x4*)(affa + k * 128))[c8 * 2];
    f32x4 a1 = ((const f32x4*)(affa + k * 128))[c8 * 2 + 1];
    f32x4 c0 = ((const f32x4*)(affc + k * 128))[c8 * 2];
    f32x4 c1 = ((const f32x4*)(affc + k * 128))[c8 * 2 + 1];

    // T14 split: issue all loads, then transform + LDS write
    f16x8 zv[8];
    #pragma unroll
    for (int p = 0; p < 8; ++p) {
        int r = p * 16 + (tid >> 4);
        int row = row0 + r;
        zv[p] = (row < N) ? ((const f16x8*)(slab + (size_t)row * 256))[c8]
                          : (f16x8){0, 0, 0, 0, 0, 0, 0, 0};
    }
    #pragma unroll
    for (int p = 0; p < 8; ++p) {
        int r = p * 16 + (tid >> 4);
        f16x8 hv;
        #pragma unroll
        for (int j = 0; j < 4; ++j) {
            float t0 = (float)zv[p][j] * a0[j] + c0[j];
            float t1 = (float)zv[p][4 + j] * a1[j] + c1[j];
            hv[j]     = (f16)(t0 > 0.f ? t0 : 0.f);
            hv[4 + j] = (f16)(t1 > 0.f ? t1 : 0.f);
        }
        *(f16x8*)(atile + a_swz(r, c8 * 16)) = hv;
    }
    __syncthreads();

    const f16* Wt = Wth2 + (size_t)s * 16384;
    f32x4 acc0[8], acc1[8];
    #pragma unroll
    for (int ct = 0; ct < 8; ++ct) {
        acc0[ct] = (f32x4){0.f, 0.f, 0.f, 0.f};
        acc1[ct] = (f32x4){0.f, 0.f, 0.f, 0.f};
    }
    const int arow0 = (w << 5) + (lane & 15);
    const int arow1 = arow0 + 16;
    const int kq = (lane >> 4) * 8;
    #pragma unroll
    for (int ks = 0; ks < 4; ++ks) {
        f16x8 af0 = *(const f16x8*)(atile + a_swz(arow0, (ks * 32 + kq) * 2));
        f16x8 af1 = *(const f16x8*)(atile + a_swz(arow1, (ks * 32 + kq) * 2));
        #pragma unroll
        for (int ct = 0; ct < 8; ++ct) {
            f16x8 bf = *(const f16x8*)(Wt + (size_t)(ct * 16 + (lane & 15)) * D + ks * 32 + kq);
            acc0[ct] = __builtin_amdgcn_mfma_f32_16x16x32_f16(af0, bf, acc0[ct], 0, 0, 0);
            acc1[ct] = __builtin_amdgcn_mfma_f32_16x16x32_f16(af1, bf, acc1[ct], 0, 0, 0);
        }
    }

    const int col_lo = lane & 15;
    const int lrb0 = (w << 5) + ((lane >> 4) << 2);
    #pragma unroll
    for (int ct = 0; ct < 8; ++ct) {
        int col = ct * 16 + col_lo;
        float bv = bias[s * D + col];
        float s_ = 0.f, q_ = 0.f;
        #pragma unroll
        for (int r = 0; r < 4; ++r) {
            int lrow = lrb0 + r;
            float val = acc0[ct][r] + bv;
            if (row0 + lrow < N) { s_ += val; q_ += val * val; }
            *(f16*)(atile + a_swz(lrow, col * 2)) = (f16)val;
        }
        #pragma unroll
        for (int r = 0; r < 4; ++r) {
            int lrow = lrb0 + 16 + r;
            float val = acc1[ct][r] + bv;
            if (row0 + lrow < N) { s_ += val; q_ += val * val; }
            *(f16*)(atile + a_swz(lrow, col * 2)) = (f16)val;
        }
        s_ += __shfl_xor(s_, 16); q_ += __shfl_xor(q_, 16);
        s_ += __shfl_xor(s_, 32); q_ += __shfl_xor(q_, 32);
        if (lane < 16) { wst[w][col] = s_; wst[w][128 + col] = q_; }
    }
    __syncthreads();

    #pragma unroll
    for (int p = 0; p < 8; ++p) {
        int r = p * 16 + (tid >> 4);
        int row = row0 + r;
        if (row < N)
            *(f16x8*)(slab + (size_t)row * 256 + c8 * 16) = *(const f16x8*)(atile + a_swz(r, c8 * 16));
    }
    float pv = wst[0][tid] + wst[1][tid] + wst[2][tid] + wst[3][tid];
    partials[((size_t)blockIdx.x * 3 + s) * 256 + tid] = pv;
}

// ------------------------------------------------- fused stats -> BN affine
// 9 blocks: blockIdx.x = k = s*3 + t. aff arrays are [9][128].
__global__ void bn_fuse(const float* __restrict__ partials,
                        const float* __restrict__ g, const float* __restrict__ be,
                        float* __restrict__ affa, float* __restrict__ affc) {
    __shared__ float red[256];
    int k = blockIdx.x, tid = threadIdx.x;
    int s = k / 3, t = k % 3;
    int lo = d_TLO[t], hi = d_THI[t];
    float v = 0.f;
    #pragma unroll 4
    for (int b = lo; b < hi; ++b)
        v += partials[((size_t)b * 3 + s) * 256 + tid];
    red[tid] = v;
    __syncthreads();
    if (tid < 128) {
        float sm = red[tid], q = red[128 + tid];
        float n = (float)d_NC[t];
        float mean = sm / n;
        float var  = q / n - mean * mean;
        float a = g[s * D + tid] * rsqrtf(var + 1e-5f);
        affa[k * 128 + tid] = a;
        affc[k * 128 + tid] = be[s * D + tid] - mean * a;
    }
}

// -------------------------------------------------- final accum, all rows
__global__ __launch_bounds__(256) void accum_all(const char* __restrict__ slabs,
                                                 const float* __restrict__ affa,
                                                 const float* __restrict__ affc,
                                                 float* __restrict__ outp) {
    const int total = 223000 * 16;
    for (int i = blockIdx.x * 256 + threadIdx.x; i < total; i += gridDim.x * 256) {
        int row = i >> 4;
        int c8  = i & 15;
        int t = (row < 200000) ? 0 : (row < 203000) ? 1 : 2;
        f32x4 o0 = {0.f, 0.f, 0.f, 0.f}, o1 = {0.f, 0.f, 0.f, 0.f};
        #pragma unroll
        for (int s = 0; s < 3; ++s) {
            int k = s * 3 + t;
            f16x8 z = ((const f16x8*)(slabs + (size_t)s * SLABSZ + (size_t)row * 256))[c8];
            f32x4 a0 = ((const f32x4*)(affa + k * 128))[c8 * 2];
            f32x4 a1 = ((const f32x4*)(affa + k * 128))[c8 * 2 + 1];
            f32x4 c0 = ((const f32x4*)(affc + k * 128))[c8 * 2];
            f32x4 c1 = ((const f32x4*)(affc + k * 128))[c8 * 2 + 1];
            #pragma unroll
            for (int j = 0; j < 4; ++j) {
                float t0 = (float)z[j] * a0[j] + c0[j];
                float t1 = (float)z[4 + j] * a1[j] + c1[j];
                o0[j] += t0 > 0.f ? t0 : 0.f;
                o1[j] += t1 > 0.f ? t1 : 0.f;
            }
        }
        ((f32x4*)(outp + (size_t)row * D))[c8 * 2]     = o0;
        ((f32x4*)(outp + (size_t)row * D))[c8 * 2 + 1] = o1;
    }
}

extern "C" void kernel_launch(void* const* d_in, const int* in_sizes, int n_in,
                              void* d_out, int out_size, void* d_ws, size_t ws_size,
                              hipStream_t stream) {
    const float* x0  = (const float*)d_in[0];
    const float* x1  = (const float*)d_in[1];
    const float* x2  = (const float*)d_in[2];
    const int*   ei  = (const int*)d_in[3];
    const float* W1  = (const float*)d_in[4];
    const float* b1  = (const float*)d_in[5];
    const float* g1  = (const float*)d_in[6];
    const float* be1 = (const float*)d_in[7];
    const float* W2  = (const float*)d_in[8];
    const float* b2  = (const float*)d_in[9];
    const float* g2  = (const float*)d_in[10];
    const float* be2 = (const float*)d_in[11];
    const float* eps9 = (const float*)d_in[12];
    float* outp = (float*)d_out;

    char* ws = (char*)d_ws;
    size_t off = 0;
    char* slabs = ws;                 off += 3 * SLABSZ;                   // 171.3 MB
    int2* binned = (int2*)slabs;      // 36 MB alias, consumed before slabs written
    f16* x16    = (f16*)(ws + off);   off += SLABSZ;                       // 57.1 MB
    int* ssrc   = (int*)(ws + off);   off += (size_t)9 * E_PER * 4;        // 18 MB
    int* rowstart = (int*)(ws + off); off += (size_t)(TOT_ROWS + 2) * 4;
    off = (off + 255) & ~(size_t)255;
    int* bcnt   = (int*)(ws + off);   off += 2308 * 4;
    int* bbase  = (int*)(ws + off);   off += 2308 * 4;
    int* bcursor= (int*)(ws + off);   off += 2308 * 4;
    off = (off + 255) & ~(size_t)255;
    float* partials = (float*)(ws + off); off += (size_t)1744 * 3 * 256 * 4;
    float* aff1a = (float*)(ws + off); off += 9 * 128 * 4;
    float* aff1c = (float*)(ws + off); off += 9 * 128 * 4;
    float* aff2a = (float*)(ws + off); off += 9 * 128 * 4;
    float* aff2c = (float*)(ws + off); off += 9 * 128 * 4;
    f16* Wth = (f16*)(ws + off); off += (size_t)2 * 3 * 128 * 128 * sizeof(f16);

    // ---- setup
    precast<<<384, 256, 0, stream>>>(W1, W2, Wth);
    cast16_all<<<2048, 256, 0, stream>>>(x0, x1, x2, x16);

    // ---- CSR build via LDS-binned counting sort (all 9 types)
    hipMemsetAsync(bcnt, 0, 2308 * 4, stream);
    int nchunk = (E_PER + CH - 1) / CH;   // 123
    bucket_count<<<dim3(nchunk, 9), 256, 0, stream>>>(ei, bcnt);
    bucket_scan<<<1, 256, 0, stream>>>(bcnt, bbase, bcursor);
    bin_scatter<<<dim3(nchunk, 9), 256, 0, stream>>>(ei, bcursor, binned);
    fine_fill<<<dim3(256, 9), 256, 0, stream>>>(binned, bbase, rowstart, ssrc);

    // ---- fully batched pipeline (all 9 (s,t) at once)
    aggregate_all<<<50250, 256, 0, stream>>>(x16, rowstart, ssrc, slabs, eps9);

    gemm_l1<<<dim3(1744, 3), 256, 0, stream>>>(slabs, Wth, b1, partials);
    bn_fuse<<<9, 256, 0, stream>>>(partials, g1, be1, aff1a, aff1c);

    gemm_l2<<<dim3(1744, 3), 256, 0, stream>>>(slabs, Wth + 3 * 16384, b2,
                                               aff1a, aff1c, partials);
    bn_fuse<<<9, 256, 0, stream>>>(partials, g2, be2, aff2a, aff2c);

    accum_all<<<4096, 256, 0, stream>>>(slabs, aff2a, aff2c, outp);
}

// Round 11
// 785.968 us; speedup vs baseline: 8.9827x; 1.0901x over previous
//
#include <hip/hip_runtime.h>
#include <hip/hip_fp16.h>

#define D 128
#define E_PER 500000
#define TOT_ROWS 669000
#define CH 4096
#define NR64 64
#define SLABSZ ((size_t)223000 * 256)

typedef _Float16 f16;
typedef _Float16 f16x8 __attribute__((ext_vector_type(8)));
typedef _Float16 f16x4 __attribute__((ext_vector_type(4)));
typedef _Float16 f16x2 __attribute__((ext_vector_type(2)));
typedef float f32x4 __attribute__((ext_vector_type(4)));

// Per-edge-type row-segment bases in the concatenated CSR arrays (k = s*3 + t).
__device__ const int d_SEGB[9] = {0, 200000, 203000, 223000, 423000, 426000,
                                  446000, 646000, 649000};
__device__ const int d_XB[3] = {0, 200000, 203000};
__device__ const int d_NC[3] = {200000, 3000, 20000};
// gemm tile ranges per t (64-row tiles): t0 3125, t1 47, t2 313
__device__ const int d_T64LO[3] = {0, 3125, 3172};
__device__ const int d_T64HI[3] = {3125, 3172, 3485};

// XOR swizzle for the A tile in LDS (row stride 256B f16).
__device__ __forceinline__ unsigned a_swz(int row, int byteoff) {
    return (unsigned)(row * 256 + byteoff) ^ (unsigned)((row & 7) << 4);
}

// map global gemm tile (64-row) -> (t, local tile)
__device__ __forceinline__ void tile_map64(int g, int& t, int& tl) {
    if (g < 3125)      { t = 0; tl = g; }
    else if (g < 3172) { t = 1; tl = g - 3125; }
    else               { t = 2; tl = g - 3172; }
}

// ---------------------------------------------------------------- precast W^T
__global__ void precast(const float* __restrict__ W1,
                        const float* __restrict__ W2,
                        f16* __restrict__ Wth) {
    int i = blockIdx.x * 256 + threadIdx.x;
    if (i >= 2 * 3 * 128 * 128) return;
    int layer = i / 49152;
    int rem = i - layer * 49152;
    int s = rem / 16384;
    int r2 = rem & 16383;
    int kk = r2 >> 7;
    int c  = r2 & 127;
    const float* W = layer ? W2 : W1;
    Wth[(((size_t)layer * 3 + s) * 128 + c) * 128 + kk] = (f16)W[((size_t)s * 128 + kk) * 128 + c];
}

// ------------------------------------------------------- all x -> f16 table
__global__ void cast16_all(const float* __restrict__ x0,
                           const float* __restrict__ x1,
                           const float* __restrict__ x2,
                           f16* __restrict__ y) {
    const int total = 223000 * 16;
    for (int i = blockIdx.x * 256 + threadIdx.x; i < total; i += gridDim.x * 256) {
        int row = i >> 4, c8 = i & 15;
        const float* src;
        if (row < 200000)      src = x0 + (size_t)row * D;
        else if (row < 203000) src = x1 + (size_t)(row - 200000) * D;
        else                   src = x2 + (size_t)(row - 203000) * D;
        f32x4 v0 = ((const f32x4*)src)[c8 * 2];
        f32x4 v1 = ((const f32x4*)src)[c8 * 2 + 1];
        f16x8 h;
        #pragma unroll
        for (int j = 0; j < 4; ++j) { h[j] = (f16)v0[j]; h[4 + j] = (f16)v1[j]; }
        ((f16x8*)(y + (size_t)row * D))[c8] = h;
    }
}

// ============================================================ CSR via 2-pass
__global__ __launch_bounds__(256) void bucket_count(const int* __restrict__ ei,
                                                    int* __restrict__ bcnt) {
    __shared__ int hist[256];
    int k = blockIdx.y, tid = threadIdx.x;
    const int* dstp = ei + (size_t)k * 2 * E_PER + E_PER;
    unsigned Nt = (unsigned)d_NC[k % 3];
    int base = blockIdx.x * CH;
    int hi = min(base + CH, E_PER);
    hist[tid] = 0;
    __syncthreads();
    for (int i = base + tid; i < hi; i += 256) {
        unsigned b = ((unsigned)dstp[i] << 8) / Nt;
        atomicAdd(&hist[b], 1);
    }
    __syncthreads();
    if (hist[tid]) atomicAdd(&bcnt[k * 256 + tid], hist[tid]);
}

__global__ void bucket_scan(const int* __restrict__ bcnt,
                            int* __restrict__ bbase, int* __restrict__ bcursor) {
    __shared__ int sb[256];
    int t = threadIdx.x;
    int loc[9];
    int s = 0;
    #pragma unroll
    for (int j = 0; j < 9; ++j) { loc[j] = bcnt[t * 9 + j]; s += loc[j]; }
    sb[t] = s; __syncthreads();
    int v = s;
    for (int off = 1; off < 256; off <<= 1) {
        int u = (t >= off) ? sb[t - off] : 0;
        __syncthreads();
        sb[t] += u;
        __syncthreads();
    }
    int pre = sb[t] - v;
    #pragma unroll
    for (int j = 0; j < 9; ++j) {
        bbase[t * 9 + j] = pre;
        bcursor[t * 9 + j] = pre;
        pre += loc[j];
    }
    if (t == 255) bbase[2304] = pre;
}

__global__ __launch_bounds__(256) void bin_scatter(const int* __restrict__ ei,
                                                   int* __restrict__ bcursor,
                                                   int2* __restrict__ binned) {
    __shared__ int hist[256], gb[256], cur[256];
    int k = blockIdx.y, tid = threadIdx.x;
    const int* srcp = ei + (size_t)k * 2 * E_PER;
    const int* dstp = srcp + E_PER;
    unsigned Nt = (unsigned)d_NC[k % 3];
    int base = blockIdx.x * CH;
    int hi = min(base + CH, E_PER);
    hist[tid] = 0;
    __syncthreads();
    for (int i = base + tid; i < hi; i += 256) {
        unsigned b = ((unsigned)dstp[i] << 8) / Nt;
        atomicAdd(&hist[b], 1);
    }
    __syncthreads();
    gb[tid] = hist[tid] ? atomicAdd(&bcursor[k * 256 + tid], hist[tid]) : 0;
    cur[tid] = 0;
    __syncthreads();
    for (int i = base + tid; i < hi; i += 256) {
        int src = srcp[i], dst = dstp[i];
        unsigned b = ((unsigned)dst << 8) / Nt;
        int r = atomicAdd(&cur[b], 1);
        binned[(size_t)gb[b] + r] = make_int2(src, dst);
    }
}

__global__ __launch_bounds__(256) void fine_fill(const int2* __restrict__ binned,
                                                 const int* __restrict__ bbase,
                                                 int* __restrict__ rowstart,
                                                 int* __restrict__ ssrc) {
    __shared__ int rcnt[784];
    __shared__ int excl[784];
    __shared__ int scur[784];
    __shared__ int sb[256];
    int k = blockIdx.y, b = blockIdx.x, tid = threadIdx.x;
    int Nt = d_NC[k % 3];
    int segb = d_SEGB[k];
    int row_lo = (b * Nt + 255) >> 8;
    int row_hi = ((b + 1) * Nt + 255) >> 8;
    int nrows = row_hi - row_lo;
    int ebase = bbase[k * 256 + b];
    int eend  = bbase[k * 256 + b + 1];
    for (int i = tid; i < nrows; i += 256) rcnt[i] = 0;
    __syncthreads();
    for (int e = ebase + tid; e < eend; e += 256)
        atomicAdd(&rcnt[binned[e].y - row_lo], 1);
    __syncthreads();
    int stride = (nrows + 255) >> 8;
    int lo = tid * stride;
    int hi2 = min(lo + stride, nrows);
    int s = 0;
    for (int i = lo; i < hi2; ++i) s += rcnt[i];
    sb[tid] = s; __syncthreads();
    int v = s;
    for (int off = 1; off < 256; off <<= 1) {
        int u = (tid >= off) ? sb[tid - off] : 0;
        __syncthreads();
        sb[tid] += u;
        __syncthreads();
    }
    int pre = sb[tid] - v;
    for (int i = lo; i < hi2; ++i) {
        excl[i] = pre;
        scur[i] = pre;
        pre += rcnt[i];
    }
    __syncthreads();
    for (int i = tid; i < nrows; i += 256)
        rowstart[segb + row_lo + i] = ebase + excl[i];
    if (k == 8 && b == 255 && tid == 0) rowstart[TOT_ROWS] = eend;
    for (int e = ebase + tid; e < eend; e += 256) {
        int2 ed = binned[e];
        int r = atomicAdd(&scur[ed.y - row_lo], 1);
        ssrc[ebase + r] = ed.x;
    }
}

// --------------------------------------------- aggregate for t=1 (deg~500)
// grid (3000, 3): 16 edge slots (4 waves x 4 groups), butterfly + LDS combine.
__global__ __launch_bounds__(256) void aggregate_t1(const f16* __restrict__ x16,
                                                    const int* __restrict__ rowstart,
                                                    const int* __restrict__ ssrc,
                                                    char* __restrict__ slabs,
                                                    const float* __restrict__ eps9) {
    __shared__ float part[4][128];
    int row = blockIdx.x;
    int s = blockIdx.y;
    int k = s * 3 + 1;
    const int* rs = rowstart + d_SEGB[k];
    const f16* xsrc = x16 + (size_t)d_XB[s] * D;
    const f16* xt   = x16 + (size_t)d_XB[1] * D;
    char* slab = slabs + (size_t)s * SLABSZ + (size_t)d_XB[1] * 256;
    float epsv = 1.0f + eps9[k];
    int tid  = threadIdx.x;
    int lane = tid & 63;
    int w    = tid >> 6;
    int grp  = lane >> 4;
    int cs   = lane & 15;
    int estart = w * 4 + grp, estep = 16;
    float acc[8];
    #pragma unroll
    for (int j = 0; j < 8; ++j) acc[j] = 0.f;
    int e1 = rs[row + 1];
    int e  = rs[row] + estart;
    for (; e + 3 * estep < e1; e += 4 * estep) {
        int s0 = ssrc[e], s1 = ssrc[e + estep], s2 = ssrc[e + 2 * estep], s3 = ssrc[e + 3 * estep];
        f16x8 v0 = ((const f16x8*)(xsrc + (size_t)s0 * D))[cs];
        f16x8 v1 = ((const f16x8*)(xsrc + (size_t)s1 * D))[cs];
        f16x8 v2 = ((const f16x8*)(xsrc + (size_t)s2 * D))[cs];
        f16x8 v3 = ((const f16x8*)(xsrc + (size_t)s3 * D))[cs];
        #pragma unroll
        for (int j = 0; j < 8; ++j)
            acc[j] += ((float)v0[j] + (float)v1[j]) + ((float)v2[j] + (float)v3[j]);
    }
    for (; e < e1; e += estep) {
        int s0 = ssrc[e];
        f16x8 v0 = ((const f16x8*)(xsrc + (size_t)s0 * D))[cs];
        #pragma unroll
        for (int j = 0; j < 8; ++j) acc[j] += (float)v0[j];
    }
    #pragma unroll
    for (int j = 0; j < 8; ++j) {
        acc[j] += __shfl_xor(acc[j], 16);
        acc[j] += __shfl_xor(acc[j], 32);
    }
    if (lane < 16) {
        #pragma unroll
        for (int j = 0; j < 8; ++j) part[w][cs * 8 + j] = acc[j];
    }
    __syncthreads();
    if (w == 0 && lane < 16) {
        f16x8 xv = ((const f16x8*)(xt + (size_t)row * D))[cs];
        f16x8 h;
        #pragma unroll
        for (int j = 0; j < 8; ++j) {
            float v = (part[0][cs*8+j] + part[1][cs*8+j]) + (part[2][cs*8+j] + part[3][cs*8+j]);
            h[j] = (f16)(v + epsv * (float)xv[j]);
        }
        ((f16x8*)(slab + (size_t)row * 256))[cs] = h;
    }
}

// --------------------------------- layer-1 GEMM with FUSED gather (t=0,2)
// grid (3485, 3). 64-row tiles. t!=1: phase 1 gathers (1+eps)*x_t + sum x_s
// per row straight into the swizzled LDS A-tile (group-per-row, ILP-4, no
// slab round-trip). t==1: stage from slab via global_load_lds (pre-swizzled
// source). Phase 2: MFMA + bias + stats + z1 writeback (in slab).
__global__ __launch_bounds__(256) void gemm_l1f(char* __restrict__ slabs,
                                                const f16* __restrict__ x16,
                                                const int* __restrict__ rowstart,
                                                const int* __restrict__ ssrc,
                                                const f16* __restrict__ Wth,
                                                const float* __restrict__ b1,
                                                const float* __restrict__ eps9,
                                                float* __restrict__ partials) {
    __shared__ alignas(16) char atile[64 * 256];
    __shared__ float wst[4][256];
    const int tid  = threadIdx.x;
    const int lane = tid & 63;
    const int w    = tid >> 6;
    const int s    = blockIdx.y;
    int t, tl;
    tile_map64(blockIdx.x, t, tl);
    const int N = d_NC[t];
    const int row0 = tl * 64;
    const int k = s * 3 + t;
    char* slab = slabs + (size_t)s * SLABSZ + (size_t)d_XB[t] * 256;

    if (t != 1) {
        const f16* xsrc = x16 + (size_t)d_XB[s] * D;
        const f16* xt   = x16 + (size_t)d_XB[t] * D;
        const int* rs = rowstart + d_SEGB[k];
        float epsv = 1.0f + eps9[k];
        int grp = tid >> 4, cs = tid & 15;
        for (int i = 0; i < 4; ++i) {
            int r = i * 16 + grp;
            int row = row0 + r;
            f16x8 h = {0, 0, 0, 0, 0, 0, 0, 0};
            if (row < N) {
                f16x8 xv = ((const f16x8*)(xt + (size_t)row * D))[cs];
                float acc[8];
                #pragma unroll
                for (int j = 0; j < 8; ++j) acc[j] = epsv * (float)xv[j];
                int e = rs[row], e1 = rs[row + 1];
                for (; e + 3 < e1; e += 4) {
                    int s0 = ssrc[e], s1 = ssrc[e + 1], s2 = ssrc[e + 2], s3 = ssrc[e + 3];
                    f16x8 v0 = ((const f16x8*)(xsrc + (size_t)s0 * D))[cs];
                    f16x8 v1 = ((const f16x8*)(xsrc + (size_t)s1 * D))[cs];
                    f16x8 v2 = ((const f16x8*)(xsrc + (size_t)s2 * D))[cs];
                    f16x8 v3 = ((const f16x8*)(xsrc + (size_t)s3 * D))[cs];
                    #pragma unroll
                    for (int j = 0; j < 8; ++j)
                        acc[j] += ((float)v0[j] + (float)v1[j]) + ((float)v2[j] + (float)v3[j]);
                }
                if (e + 1 < e1) {
                    int s0 = ssrc[e], s1 = ssrc[e + 1];
                    f16x8 v0 = ((const f16x8*)(xsrc + (size_t)s0 * D))[cs];
                    f16x8 v1 = ((const f16x8*)(xsrc + (size_t)s1 * D))[cs];
                    #pragma unroll
                    for (int j = 0; j < 8; ++j) acc[j] += (float)v0[j] + (float)v1[j];
                    e += 2;
                }
                if (e < e1) {
                    int s0 = ssrc[e];
                    f16x8 v0 = ((const f16x8*)(xsrc + (size_t)s0 * D))[cs];
                    #pragma unroll
                    for (int j = 0; j < 8; ++j) acc[j] += (float)v0[j];
                }
                #pragma unroll
                for (int j = 0; j < 8; ++j) h[j] = (f16)acc[j];
            }
            *(f16x8*)(atile + a_swz(r, cs * 16)) = h;
        }
    } else {
        #pragma unroll
        for (int p = 0; p < 4; ++p) {
            int r  = p * 16 + (tid >> 4);
            int c8 = tid & 15;
            int row = row0 + r;
            if (row >= N) row = N - 1;   // clamp: garbage masked in epilogue
            const char* src = slab + (size_t)row * 256 + (unsigned)((c8 * 16) ^ ((r & 7) << 4));
            __builtin_amdgcn_global_load_lds(
                (const __attribute__((address_space(1))) void*)src,
                (__attribute__((address_space(3))) void*)(atile + p * 4096 + w * 1024),
                16, 0, 0);
        }
    }
    __syncthreads();

    const f16* Wt = Wth + (size_t)s * 16384;
    f32x4 acc0[8];
    #pragma unroll
    for (int ct = 0; ct < 8; ++ct) acc0[ct] = (f32x4){0.f, 0.f, 0.f, 0.f};
    const int arow = (w << 4) + (lane & 15);
    const int kq = (lane >> 4) * 8;
    #pragma unroll
    for (int ks = 0; ks < 4; ++ks) {
        f16x8 af = *(const f16x8*)(atile + a_swz(arow, (ks * 32 + kq) * 2));
        #pragma unroll
        for (int ct = 0; ct < 8; ++ct) {
            f16x8 bf = *(const f16x8*)(Wt + (size_t)(ct * 16 + (lane & 15)) * D + ks * 32 + kq);
            acc0[ct] = __builtin_amdgcn_mfma_f32_16x16x32_f16(af, bf, acc0[ct], 0, 0, 0);
        }
    }

    const int col_lo = lane & 15;
    const int lrb0 = (w << 4) + ((lane >> 4) << 2);
    #pragma unroll
    for (int ct = 0; ct < 8; ++ct) {
        int col = ct * 16 + col_lo;
        float bv = b1[s * D + col];
        float s_ = 0.f, q_ = 0.f;
        #pragma unroll
        for (int r = 0; r < 4; ++r) {
            int lrow = lrb0 + r;
            float val = acc0[ct][r] + bv;
            if (row0 + lrow < N) { s_ += val; q_ += val * val; }
            *(f16*)(atile + a_swz(lrow, col * 2)) = (f16)val;
        }
        s_ += __shfl_xor(s_, 16); q_ += __shfl_xor(q_, 16);
        s_ += __shfl_xor(s_, 32); q_ += __shfl_xor(q_, 32);
        if (lane < 16) { wst[w][col] = s_; wst[w][128 + col] = q_; }
    }
    __syncthreads();

    #pragma unroll
    for (int p = 0; p < 4; ++p) {
        int r  = p * 16 + (tid >> 4);
        int c8 = tid & 15;
        int row = row0 + r;
        if (row < N)
            *(f16x8*)(slab + (size_t)row * 256 + c8 * 16) = *(const f16x8*)(atile + a_swz(r, c8 * 16));
    }
    float pv = wst[0][tid] + wst[1][tid] + wst[2][tid] + wst[3][tid];
    partials[((size_t)blockIdx.x * 3 + s) * 256 + tid] = pv;
}

// -------------------------------------------------------------- layer-2 GEMM
// grid (3485, 3). 64-row tiles, reg-staged affine+relu transform.
__global__ __launch_bounds__(256) void gemm_l2(char* __restrict__ slabs,
                                               const f16* __restrict__ Wth2,
                                               const float* __restrict__ bias,
                                               const float* __restrict__ affa,
                                               const float* __restrict__ affc,
                                               float* __restrict__ partials) {
    __shared__ alignas(16) char atile[64 * 256];
    __shared__ float wst[4][256];
    const int tid  = threadIdx.x;
    const int lane = tid & 63;
    const int w    = tid >> 6;
    const int s    = blockIdx.y;
    int t, tl;
    tile_map64(blockIdx.x, t, tl);
    const int N = d_NC[t];
    const int row0 = tl * 64;
    const int k = s * 3 + t;
    char* slab = slabs + (size_t)s * SLABSZ + (size_t)d_XB[t] * 256;
    const int c8 = tid & 15;

    f32x4 a0 = ((const f32x4*)(affa + k * 128))[c8 * 2];
    f32x4 a1 = ((const f32x4*)(affa + k * 128))[c8 * 2 + 1];
    f32x4 c0 = ((const f32x4*)(affc + k * 128))[c8 * 2];
    f32x4 c1 = ((const f32x4*)(affc + k * 128))[c8 * 2 + 1];

    f16x8 zv[4];
    #pragma unroll
    for (int p = 0; p < 4; ++p) {
        int r = p * 16 + (tid >> 4);
        int row = row0 + r;
        zv[p] = (row < N) ? ((const f16x8*)(slab + (size_t)row * 256))[c8]
                          : (f16x8){0, 0, 0, 0, 0, 0, 0, 0};
    }
    #pragma unroll
    for (int p = 0; p < 4; ++p) {
        int r = p * 16 + (tid >> 4);
        f16x8 hv;
        #pragma unroll
        for (int j = 0; j < 4; ++j) {
            float t0 = (float)zv[p][j] * a0[j] + c0[j];
            float t1 = (float)zv[p][4 + j] * a1[j] + c1[j];
            hv[j]     = (f16)(t0 > 0.f ? t0 : 0.f);
            hv[4 + j] = (f16)(t1 > 0.f ? t1 : 0.f);
        }
        *(f16x8*)(atile + a_swz(r, c8 * 16)) = hv;
    }
    __syncthreads();

    const f16* Wt = Wth2 + (size_t)s * 16384;
    f32x4 acc0[8];
    #pragma unroll
    for (int ct = 0; ct < 8; ++ct) acc0[ct] = (f32x4){0.f, 0.f, 0.f, 0.f};
    const int arow = (w << 4) + (lane & 15);
    const int kq = (lane >> 4) * 8;
    #pragma unroll
    for (int ks = 0; ks < 4; ++ks) {
        f16x8 af = *(const f16x8*)(atile + a_swz(arow, (ks * 32 + kq) * 2));
        #pragma unroll
        for (int ct = 0; ct < 8; ++ct) {
            f16x8 bf = *(const f16x8*)(Wt + (size_t)(ct * 16 + (lane & 15)) * D + ks * 32 + kq);
            acc0[ct] = __builtin_amdgcn_mfma_f32_16x16x32_f16(af, bf, acc0[ct], 0, 0, 0);
        }
    }

    const int col_lo = lane & 15;
    const int lrb0 = (w << 4) + ((lane >> 4) << 2);
    #pragma unroll
    for (int ct = 0; ct < 8; ++ct) {
        int col = ct * 16 + col_lo;
        float bv = bias[s * D + col];
        float s_ = 0.f, q_ = 0.f;
        #pragma unroll
        for (int r = 0; r < 4; ++r) {
            int lrow = lrb0 + r;
            float val = acc0[ct][r] + bv;
            if (row0 + lrow < N) { s_ += val; q_ += val * val; }
            *(f16*)(atile + a_swz(lrow, col * 2)) = (f16)val;
        }
        s_ += __shfl_xor(s_, 16); q_ += __shfl_xor(q_, 16);
        s_ += __shfl_xor(s_, 32); q_ += __shfl_xor(q_, 32);
        if (lane < 16) { wst[w][col] = s_; wst[w][128 + col] = q_; }
    }
    __syncthreads();

    #pragma unroll
    for (int p = 0; p < 4; ++p) {
        int r = p * 16 + (tid >> 4);
        int row = row0 + r;
        if (row < N)
            *(f16x8*)(slab + (size_t)row * 256 + c8 * 16) = *(const f16x8*)(atile + a_swz(r, c8 * 16));
    }
    float pv = wst[0][tid] + wst[1][tid] + wst[2][tid] + wst[3][tid];
    partials[((size_t)blockIdx.x * 3 + s) * 256 + tid] = pv;
}

// ----------------------------------------------------------- stats reduction
__global__ void bn_reduce(const float* __restrict__ partials,
                          float* __restrict__ partial2) {
    int k = blockIdx.y, tid = threadIdx.x;
    int s = k / 3, t = k % 3;
    int lo = d_T64LO[t], hi = d_T64HI[t];
    float v = 0.f;
    for (int b = lo + blockIdx.x; b < hi; b += NR64)
        v += partials[((size_t)b * 3 + s) * 256 + tid];
    partial2[((size_t)k * NR64 + blockIdx.x) * 256 + tid] = v;
}

__global__ void bn_params(const float* __restrict__ partial2,
                          const float* __restrict__ g, const float* __restrict__ be,
                          float* __restrict__ affa, float* __restrict__ affc) {
    __shared__ float red[256];
    int k = blockIdx.x, tid = threadIdx.x;
    int s = k / 3, t = k % 3;
    float v = 0.f;
    #pragma unroll 4
    for (int b = 0; b < NR64; ++b)
        v += partial2[((size_t)k * NR64 + b) * 256 + tid];
    red[tid] = v;
    __syncthreads();
    if (tid < 128) {
        float sm = red[tid], q = red[128 + tid];
        float n = (float)d_NC[t];
        float mean = sm / n;
        float var  = q / n - mean * mean;
        float a = g[s * D + tid] * rsqrtf(var + 1e-5f);
        affa[k * 128 + tid] = a;
        affc[k * 128 + tid] = be[s * D + tid] - mean * a;
    }
}

// -------------------------------------------------- final accum, all rows
__global__ __launch_bounds__(256) void accum_all(const char* __restrict__ slabs,
                                                 const float* __restrict__ affa,
                                                 const float* __restrict__ affc,
                                                 float* __restrict__ outp) {
    const int total = 223000 * 16;
    for (int i = blockIdx.x * 256 + threadIdx.x; i < total; i += gridDim.x * 256) {
        int row = i >> 4;
        int c8  = i & 15;
        int t = (row < 200000) ? 0 : (row < 203000) ? 1 : 2;
        f32x4 o0 = {0.f, 0.f, 0.f, 0.f}, o1 = {0.f, 0.f, 0.f, 0.f};
        #pragma unroll
        for (int s = 0; s < 3; ++s) {
            int k = s * 3 + t;
            f16x8 z = ((const f16x8*)(slabs + (size_t)s * SLABSZ + (size_t)row * 256))[c8];
            f32x4 a0 = ((const f32x4*)(affa + k * 128))[c8 * 2];
            f32x4 a1 = ((const f32x4*)(affa + k * 128))[c8 * 2 + 1];
            f32x4 c0 = ((const f32x4*)(affc + k * 128))[c8 * 2];
            f32x4 c1 = ((const f32x4*)(affc + k * 128))[c8 * 2 + 1];
            #pragma unroll
            for (int j = 0; j < 4; ++j) {
                float t0 = (float)z[j] * a0[j] + c0[j];
                float t1 = (float)z[4 + j] * a1[j] + c1[j];
                o0[j] += t0 > 0.f ? t0 : 0.f;
                o1[j] += t1 > 0.f ? t1 : 0.f;
            }
        }
        ((f32x4*)(outp + (size_t)row * D))[c8 * 2]     = o0;
        ((f32x4*)(outp + (size_t)row * D))[c8 * 2 + 1] = o1;
    }
}

extern "C" void kernel_launch(void* const* d_in, const int* in_sizes, int n_in,
                              void* d_out, int out_size, void* d_ws, size_t ws_size,
                              hipStream_t stream) {
    const float* x0  = (const float*)d_in[0];
    const float* x1  = (const float*)d_in[1];
    const float* x2  = (const float*)d_in[2];
    const int*   ei  = (const int*)d_in[3];
    const float* W1  = (const float*)d_in[4];
    const float* b1  = (const float*)d_in[5];
    const float* g1  = (const float*)d_in[6];
    const float* be1 = (const float*)d_in[7];
    const float* W2  = (const float*)d_in[8];
    const float* b2  = (const float*)d_in[9];
    const float* g2  = (const float*)d_in[10];
    const float* be2 = (const float*)d_in[11];
    const float* eps9 = (const float*)d_in[12];
    float* outp = (float*)d_out;

    char* ws = (char*)d_ws;
    size_t off = 0;
    char* slabs = ws;                 off += 3 * SLABSZ;                   // 171.3 MB
    int2* binned = (int2*)slabs;      // 36 MB alias, consumed before slabs written
    f16* x16    = (f16*)(ws + off);   off += SLABSZ;                       // 57.1 MB
    int* ssrc   = (int*)(ws + off);   off += (size_t)9 * E_PER * 4;        // 18 MB
    int* rowstart = (int*)(ws + off); off += (size_t)(TOT_ROWS + 2) * 4;
    off = (off + 255) & ~(size_t)255;
    int* bcnt   = (int*)(ws + off);   off += 2308 * 4;
    int* bbase  = (int*)(ws + off);   off += 2308 * 4;
    int* bcursor= (int*)(ws + off);   off += 2308 * 4;
    off = (off + 255) & ~(size_t)255;
    float* partials = (float*)(ws + off); off += (size_t)3485 * 3 * 256 * 4;
    float* partial2 = (float*)(ws + off); off += (size_t)9 * NR64 * 256 * 4;
    float* aff1a = (float*)(ws + off); off += 9 * 128 * 4;
    float* aff1c = (float*)(ws + off); off += 9 * 128 * 4;
    float* aff2a = (float*)(ws + off); off += 9 * 128 * 4;
    float* aff2c = (float*)(ws + off); off += 9 * 128 * 4;
    f16* Wth = (f16*)(ws + off); off += (size_t)2 * 3 * 128 * 128 * sizeof(f16);

    // ---- setup
    precast<<<384, 256, 0, stream>>>(W1, W2, Wth);
    cast16_all<<<2048, 256, 0, stream>>>(x0, x1, x2, x16);

    // ---- CSR build via LDS-binned counting sort (all 9 types)
    hipMemsetAsync(bcnt, 0, 2308 * 4, stream);
    int nchunk = (E_PER + CH - 1) / CH;   // 123
    bucket_count<<<dim3(nchunk, 9), 256, 0, stream>>>(ei, bcnt);
    bucket_scan<<<1, 256, 0, stream>>>(bcnt, bbase, bcursor);
    bin_scatter<<<dim3(nchunk, 9), 256, 0, stream>>>(ei, bcursor, binned);
    fine_fill<<<dim3(256, 9), 256, 0, stream>>>(binned, bbase, rowstart, ssrc);

    // ---- t=1 aggregate (high degree) into slab; t=0/2 fused into gemm_l1f
    aggregate_t1<<<dim3(3000, 3), 256, 0, stream>>>(x16, rowstart, ssrc, slabs, eps9);

    gemm_l1f<<<dim3(3485, 3), 256, 0, stream>>>(slabs, x16, rowstart, ssrc,
                                                Wth, b1, eps9, partials);
    bn_reduce<<<dim3(NR64, 9), 256, 0, stream>>>(partials, partial2);
    bn_params<<<9, 256, 0, stream>>>(partial2, g1, be1, aff1a, aff1c);

    gemm_l2<<<dim3(3485, 3), 256, 0, stream>>>(slabs, Wth + 3 * 16384, b2,
                                               aff1a, aff1c, partials);
    bn_reduce<<<dim3(NR64, 9), 256, 0, stream>>>(partials, partial2);
    bn_params<<<9, 256, 0, stream>>>(partial2, g2, be2, aff2a, aff2c);

    accum_all<<<4096, 256, 0, stream>>>(slabs, aff2a, aff2c, outp);
}